// Round 3
// baseline (1015.923 us; speedup 1.0000x reference)
//
#include <hip/hip_runtime.h>
#include <hip/hip_bf16.h>
#include <math.h>

#define NTOK 2048      // N
#define DDIM 512       // D
#define FDIM 2048      // F
#define KNN_K 16
#define ROWS 4096      // B*N

__device__ __forceinline__ float b2f(__hip_bfloat16 h) { return __bfloat162float(h); }

// flagged load from an external input buffer: mode 1 = f32, 0 = bf16
__device__ __forceinline__ float ldin(const void* p, size_t i, int f32m) {
    return f32m ? ((const float*)p)[i] : b2f(((const __hip_bfloat16*)p)[i]);
}
__device__ __forceinline__ float ld_scalar(const void* p, int f32m) {
    return f32m ? *(const float*)p : b2f(*(const __hip_bfloat16*)p);
}

__device__ __forceinline__ float wred1(float a) {
    #pragma unroll
    for (int off = 32; off; off >>= 1) a += __shfl_down(a, off);
    return __shfl(a, 0);
}
__device__ __forceinline__ void wred2(float& a, float& b) {
    #pragma unroll
    for (int off = 32; off; off >>= 1) { a += __shfl_down(a, off); b += __shfl_down(b, off); }
    a = __shfl(a, 0); b = __shfl(b, 0);
}

__device__ __forceinline__ float gelu_f(float x) {
    float x3 = x * x * x;
    return 0.5f * x * (1.f + tanhf(0.7978845608028654f * (x + 0.044715f * x3)));
}

// ---------------- dtype detector: is d_in[0] f32 or bf16? ----------------
// Reads first 1024 16-bit halves as bf16; counts wild exponents. x ~ N(0,1):
// bf16 buffer -> ~0 wild; f32 buffer -> ~40%+ wild (low mantissa halves).
__global__ void detect_kernel(const void* __restrict__ x, int* __restrict__ flag) {
    const unsigned short* u = (const unsigned short*)x;
    int tid = threadIdx.x;
    int bad = 0;
    #pragma unroll
    for (int t = 0; t < 16; ++t) {
        unsigned short h = u[tid * 16 + t];
        int e = (h >> 7) & 0xFF;
        if (e == 0xFF) bad++;                         // NaN/Inf
        else if (e >= 0x8E) bad++;                    // |v| >= 2^15
        else if (e != 0 && e <= 0x66) bad++;          // 0 < |v| <= ~2^-25
    }
    #pragma unroll
    for (int off = 32; off; off >>= 1) bad += __shfl_down(bad, off);
    if (tid == 0) *flag = (bad > 100) ? 1 : 0;
}

// ---------------- LayerNorm (one block per row of 512) ----------------
// EXT: input is an external buffer (use flag); else internal f32.
template<bool EXT>
__global__ void ln_kernel(const void* __restrict__ xin,
                          const void* __restrict__ s,
                          const void* __restrict__ b,
                          float* __restrict__ y, const int* __restrict__ fl) {
    const int m = *fl;
    const int row = blockIdx.x, tid = threadIdx.x;
    float v0, v1;
    if (EXT) {
        v0 = ldin(xin, (size_t)row * DDIM + tid, m);
        v1 = ldin(xin, (size_t)row * DDIM + tid + 256, m);
    } else {
        const float* xp = (const float*)xin + (size_t)row * DDIM;
        v0 = xp[tid]; v1 = xp[tid + 256];
    }
    float sum = v0 + v1, sq = v0 * v0 + v1 * v1;
    const int lane = tid & 63, wv = tid >> 6;
    #pragma unroll
    for (int off = 32; off; off >>= 1) { sum += __shfl_down(sum, off); sq += __shfl_down(sq, off); }
    __shared__ float ls[8];
    if (lane == 0) { ls[wv] = sum; ls[4 + wv] = sq; }
    __syncthreads();
    float ts = ls[0] + ls[1] + ls[2] + ls[3];
    float tq = ls[4] + ls[5] + ls[6] + ls[7];
    float mean = ts * (1.f / DDIM);
    float var = tq * (1.f / DDIM) - mean * mean;
    float rstd = rsqrtf(var + 1e-6f);
    y[(size_t)row * DDIM + tid]       = ldin(s, tid, m) * (v0 - mean) * rstd + ldin(b, tid, m);
    y[(size_t)row * DDIM + tid + 256] = ldin(s, tid + 256, m) * (v1 - mean) * rstd + ldin(b, tid + 256, m);
}

// ---------------- p2 = sum(pos^2) per row ----------------
__global__ void p2_kernel(const void* __restrict__ pos, float* __restrict__ p2,
                          const int* __restrict__ fl) {
    const int m = *fl;
    const int row = blockIdx.x, tid = threadIdx.x;
    float v0 = ldin(pos, (size_t)row * DDIM + tid, m);
    float v1 = ldin(pos, (size_t)row * DDIM + tid + 256, m);
    float s = v0 * v0 + v1 * v1;
    const int lane = tid & 63, wv = tid >> 6;
    #pragma unroll
    for (int off = 32; off; off >>= 1) s += __shfl_down(s, off);
    __shared__ float ls[4];
    if (lane == 0) ls[wv] = s;
    __syncthreads();
    if (tid == 0) p2[row] = ls[0] + ls[1] + ls[2] + ls[3];
}

// ---------------- generic 64x64 tiled GEMM: C = A @ W + bias ----------------
// EPI: 0 = +bias ; 1 = +bias+res ; 2 = gelu(+bias)
// AKIND: 0 internal f32, 1 internal bf16
// RESKIND: 0 none, 1 external (flagged), 2 internal f32
// OUTKIND: 0 internal f32, 1 internal bf16, 2 external (flagged)
template<int EPI, int AKIND, int RESKIND, int OUTKIND>
__global__ void gemm64(const void* __restrict__ A, const void* __restrict__ W,
                       const void* __restrict__ bias, const void* __restrict__ res,
                       void* __restrict__ C, int M, int N, int K,
                       const int* __restrict__ fl) {
    const int fm = *fl;
    __shared__ float As[16][68];
    __shared__ float Bs[16][68];
    const int tid = threadIdx.x, tx = tid & 15, ty = tid >> 4;
    const int m0 = blockIdx.y * 64, n0 = blockIdx.x * 64;
    float acc[4][4] = {};
    for (int k0 = 0; k0 < K; k0 += 16) {
        #pragma unroll
        for (int t = 0; t < 4; ++t) {
            int li = tid + t * 256;
            int mm = li >> 4, kk = li & 15;
            size_t ai = (size_t)(m0 + mm) * K + k0 + kk;
            As[kk][mm] = (AKIND == 0) ? ((const float*)A)[ai]
                                      : b2f(((const __hip_bfloat16*)A)[ai]);
        }
        #pragma unroll
        for (int t = 0; t < 4; ++t) {
            int li = tid + t * 256;
            int kk = li >> 6, n = li & 63;
            Bs[kk][n] = ldin(W, (size_t)(k0 + kk) * N + n0 + n, fm);
        }
        __syncthreads();
        #pragma unroll
        for (int kk = 0; kk < 16; ++kk) {
            float av[4], bv[4];
            #pragma unroll
            for (int i = 0; i < 4; ++i) av[i] = As[kk][ty * 4 + i];
            #pragma unroll
            for (int j = 0; j < 4; ++j) bv[j] = Bs[kk][tx * 4 + j];
            #pragma unroll
            for (int i = 0; i < 4; ++i)
                #pragma unroll
                for (int j = 0; j < 4; ++j) acc[i][j] = fmaf(av[i], bv[j], acc[i][j]);
        }
        __syncthreads();
    }
    #pragma unroll
    for (int i = 0; i < 4; ++i) {
        const int mm = m0 + ty * 4 + i;
        #pragma unroll
        for (int j = 0; j < 4; ++j) {
            const int n = n0 + tx * 4 + j;
            float val = acc[i][j] + ldin(bias, n, fm);
            if (EPI == 1) {
                if (RESKIND == 1) val += ldin(res, (size_t)mm * N + n, fm);
                else if (RESKIND == 2) val += ((const float*)res)[(size_t)mm * N + n];
            } else if (EPI == 2) {
                val = gelu_f(val);
            }
            size_t ci = (size_t)mm * N + n;
            if (OUTKIND == 0) ((float*)C)[ci] = val;
            else if (OUTKIND == 1) ((__hip_bfloat16*)C)[ci] = __float2bfloat16(val);
            else {
                if (fm) ((float*)C)[ci] = val;
                else ((__hip_bfloat16*)C)[ci] = __float2bfloat16(val);
            }
        }
    }
}

// ---------------- distance "arg" matrix for one batch: P @ P^T + hyperbolic epilogue ----------------
__global__ void dist_kernel(const void* __restrict__ pos, const float* __restrict__ p2,
                            const void* __restrict__ cp, float* __restrict__ out, int bb,
                            const int* __restrict__ fl) {
    const int fm = *fl;
    const size_t pbase = (size_t)bb * NTOK * DDIM;
    const float* p2b = p2 + bb * NTOK;
    const float c = ld_scalar(cp, fm);
    __shared__ float As[16][68];
    __shared__ float Bs[16][68];
    const int tid = threadIdx.x, tx = tid & 15, ty = tid >> 4;
    const int i0 = blockIdx.y * 64, j0 = blockIdx.x * 64;
    float acc[4][4] = {};
    for (int k0 = 0; k0 < DDIM; k0 += 16) {
        #pragma unroll
        for (int t = 0; t < 4; ++t) {
            int li = tid + t * 256;
            int mm = li >> 4, kk = li & 15;
            As[kk][mm] = ldin(pos, pbase + (size_t)(i0 + mm) * DDIM + k0 + kk, fm);
            Bs[kk][mm] = ldin(pos, pbase + (size_t)(j0 + mm) * DDIM + k0 + kk, fm);
        }
        __syncthreads();
        #pragma unroll
        for (int kk = 0; kk < 16; ++kk) {
            float av[4], bv[4];
            #pragma unroll
            for (int i = 0; i < 4; ++i) av[i] = As[kk][ty * 4 + i];
            #pragma unroll
            for (int j = 0; j < 4; ++j) bv[j] = Bs[kk][tx * 4 + j];
            #pragma unroll
            for (int i = 0; i < 4; ++i)
                #pragma unroll
                for (int j = 0; j < 4; ++j) acc[i][j] = fmaf(av[i], bv[j], acc[i][j]);
        }
        __syncthreads();
    }
    #pragma unroll
    for (int i = 0; i < 4; ++i) {
        const int ii = i0 + ty * 4 + i;
        const float p2i = p2b[ii];
        #pragma unroll
        for (int j = 0; j < 4; ++j) {
            const int jj = j0 + tx * 4 + j;
            const float p2j = p2b[jj];
            float diff = fmaxf(p2i + p2j - 2.f * acc[i][j], 0.f);
            float den = fmaxf((1.f - c * p2i) * (1.f - c * p2j), 1e-8f);
            out[(size_t)ii * NTOK + jj] = 1.f + 2.f * c * diff / den;
        }
    }
}

// ---------------- top-16 smallest per row (lowest-index tie-break), one batch ----------------
__global__ void topk_kernel(const float* __restrict__ argb, int* __restrict__ idxb, int bb) {
    const int r = blockIdx.x;
    const float* arow = argb + (size_t)r * NTOK;
    int* orow = idxb + ((size_t)bb * NTOK + r) * KNN_K;
    __shared__ float vals[NTOK];
    __shared__ float rv[256];
    __shared__ int   ri[256];
    for (int t = threadIdx.x; t < NTOK; t += 256) vals[t] = arow[t];
    __syncthreads();
    for (int sel = 0; sel < KNN_K; ++sel) {
        float best = 3.4e38f; int bi = -1;
        for (int t = threadIdx.x; t < NTOK; t += 256) {
            float vv = vals[t];
            if (vv < best) { best = vv; bi = t; }
        }
        rv[threadIdx.x] = best; ri[threadIdx.x] = bi;
        __syncthreads();
        for (int s = 128; s > 0; s >>= 1) {
            if (threadIdx.x < s) {
                float ov = rv[threadIdx.x + s]; int oi = ri[threadIdx.x + s];
                if (ov < rv[threadIdx.x] ||
                    (ov == rv[threadIdx.x] && oi >= 0 && (ri[threadIdx.x] < 0 || oi < ri[threadIdx.x]))) {
                    rv[threadIdx.x] = ov; ri[threadIdx.x] = oi;
                }
            }
            __syncthreads();
        }
        if (threadIdx.x == 0) { int w = ri[0] < 0 ? 0 : ri[0]; orow[sel] = w; vals[w] = 3.4e38f; }
        __syncthreads();
    }
}

// ---------------- fused gather + mobius/logmap + LN(geo) + scores + softmax + attn ----------------
__global__ void attn_kernel(const void* __restrict__ pos,
                            const float* __restrict__ qB, const float* __restrict__ kB,
                            const float* __restrict__ vB, const int* __restrict__ idxb,
                            const void* __restrict__ cp,
                            const void* __restrict__ geo_s, const void* __restrict__ geo_b,
                            const void* __restrict__ a_sc, const void* __restrict__ f_sc,
                            float* __restrict__ attnO, const int* __restrict__ fl) {
    const int fm = *fl;
    const int row = blockIdx.x;          // b*N + n
    const int bb = row >> 11;            // N = 2048
    const int tid = threadIdx.x, lane = tid & 63, wv = tid >> 6;
    __shared__ float qp_s[DDIM], q_s[DDIM], gs_s[DDIM], gb_s[DDIM];
    __shared__ float sc_s[KNN_K];
    __shared__ int nid_s[KNN_K];
    const float c = ld_scalar(cp, fm);
    for (int i = tid; i < DDIM; i += 256) {
        qp_s[i] = ldin(pos, (size_t)row * DDIM + i, fm);
        q_s[i]  = qB[(size_t)row * DDIM + i];
        gs_s[i] = ldin(geo_s, i, fm);
        gb_s[i] = ldin(geo_b, i, fm);
    }
    if (tid < KNN_K) nid_s[tid] = idxb[row * KNN_K + tid];
    __syncthreads();
    float qpl[8];
    float x2p = 0.f;
    #pragma unroll
    for (int t = 0; t < 8; ++t) { float e = qp_s[lane + 64 * t]; qpl[t] = e; x2p += e * e; }
    const float x2 = wred1(x2p);
    const float sc_c = sqrtf(fmaxf(c, 0.f));
    for (int it = 0; it < 4; ++it) {
        const int kk = it * 4 + wv;
        const int j = nid_s[kk];
        const size_t nro = (size_t)(bb * NTOK + j) * DDIM;
        float kpl[8];
        float xy = 0.f, y2 = 0.f;
        #pragma unroll
        for (int t = 0; t < 8; ++t) {
            float e = ldin(pos, nro + lane + 64 * t, fm);
            kpl[t] = e; xy += qpl[t] * e; y2 += e * e;
        }
        wred2(xy, y2);
        const float xym = -xy;
        const float Af = 1.f + 2.f * c * xym + c * y2;
        const float Bf = 1.f - c * x2;
        float den = 1.f + 2.f * c * xym + c * c * x2 * y2;
        den = fmaxf(den, 1e-8f);
        const float rden = 1.f / den;
        float mal[8]; float n2 = 0.f;
        #pragma unroll
        for (int t = 0; t < 8; ++t) {
            float m = (Af * (-qpl[t]) + Bf * kpl[t]) * rden;
            mal[t] = m; n2 += m * m;
        }
        n2 = wred1(n2);
        const float ynorm = fmaxf(sqrtf(n2), 1e-8f);
        const float t_over = sc_c * ynorm;
        const float targ = fminf(t_over, 1.f - 1e-7f);
        const float scale = (targ > 0.f) ? (atanhf(targ) / t_over) : 1.f;
        float sum = 0.f, sq = 0.f; float gl[8];
        #pragma unroll
        for (int t = 0; t < 8; ++t) { float g = scale * mal[t]; gl[t] = g; sum += g; sq += g * g; }
        wred2(sum, sq);
        const float mean = sum * (1.f / DDIM);
        const float var = sq * (1.f / DDIM) - mean * mean;
        const float rstd = rsqrtf(fmaxf(var, 0.f) + 1e-6f);
        float align = 0.f, feat = 0.f;
        #pragma unroll
        for (int t = 0; t < 8; ++t) {
            const int d = lane + 64 * t;
            float gn = gs_s[d] * (gl[t] - mean) * rstd + gb_s[d];
            float kv = kB[nro + d];
            align += q_s[d] * gn;
            feat  += q_s[d] * kv;
        }
        wred2(align, feat);
        if (lane == 0) sc_s[kk] = ld_scalar(f_sc, fm) * feat + ld_scalar(a_sc, fm) * align;
    }
    __syncthreads();
    float wgt[KNN_K];
    float mx = -1e30f;
    #pragma unroll
    for (int t = 0; t < KNN_K; ++t) mx = fmaxf(mx, sc_s[t]);
    float ssum = 0.f;
    #pragma unroll
    for (int t = 0; t < KNN_K; ++t) { float e = expf(sc_s[t] - mx); wgt[t] = e; ssum += e; }
    const float rs = 1.f / ssum;
    for (int d = tid; d < DDIM; d += 256) {
        float acc = 0.f;
        #pragma unroll
        for (int t = 0; t < KNN_K; ++t)
            acc += wgt[t] * vB[(size_t)(bb * NTOK + nid_s[t]) * DDIM + d];
        attnO[(size_t)row * DDIM + d] = acc * rs;
    }
}

extern "C" void kernel_launch(void* const* d_in, const int* in_sizes, int n_in,
                              void* d_out, int out_size, void* d_ws, size_t ws_size,
                              hipStream_t stream) {
    const void* x    = d_in[0];
    const void* posb = d_in[1];
    const void* cb   = d_in[2];
    const void* Wq   = d_in[3];
    const void* bq   = d_in[4];
    const void* Wk   = d_in[5];
    const void* bk   = d_in[6];
    const void* Wv   = d_in[7];
    const void* bv   = d_in[8];
    const void* Wo   = d_in[9];
    const void* bo   = d_in[10];
    const void* W1   = d_in[11];
    const void* b1   = d_in[12];
    const void* W2   = d_in[13];
    const void* b2   = d_in[14];
    const void* ln1s = d_in[15];
    const void* ln1b = d_in[16];
    const void* ln2s = d_in[17];
    const void* ln2b = d_in[18];
    const void* geos = d_in[19];
    const void* geob = d_in[20];
    const void* asc  = d_in[21];
    const void* fsc  = d_in[22];

    const size_t RD = (size_t)ROWS * DDIM;            // 2,097,152
    int*   flag = (int*)d_ws;
    float* base = (float*)d_ws + 16;
    float* xn   = base;                               // region1: xn, later attn out
    float* qb_  = xn + RD;                            // region2: q, later h (LN2 out)
    float* kb_  = qb_ + RD;                           // region3: k, later x1
    float* vb_  = kb_ + RD;                           // region4: v
    float* p2   = vb_ + RD;                           // 4096
    int*   idxb = (int*)(p2 + 4096);                  // ROWS*16 ints
    float* big  = (float*)(idxb + (size_t)ROWS * KNN_K);  // argb (NTOK^2 f32) / hh (bf16)
    float* argb = big;
    __hip_bfloat16* hh = (__hip_bfloat16*)big;
    float* attnb = xn;
    float* x1    = kb_;
    float* hbuf  = qb_;

    // 0. dtype detection (f32 vs bf16 inputs)
    detect_kernel<<<1, 64, 0, stream>>>(x, flag);
    // 1. LN1
    ln_kernel<true><<<ROWS, 256, 0, stream>>>(x, ln1s, ln1b, xn, flag);
    // 2. q,k,v
    gemm64<0, 0, 0, 0><<<dim3(8, 64), 256, 0, stream>>>(xn, Wq, bq, nullptr, qb_, ROWS, DDIM, DDIM, flag);
    gemm64<0, 0, 0, 0><<<dim3(8, 64), 256, 0, stream>>>(xn, Wk, bk, nullptr, kb_, ROWS, DDIM, DDIM, flag);
    gemm64<0, 0, 0, 0><<<dim3(8, 64), 256, 0, stream>>>(xn, Wv, bv, nullptr, vb_, ROWS, DDIM, DDIM, flag);
    // 3. distances + top-16, per batch (argb reused)
    p2_kernel<<<ROWS, 256, 0, stream>>>(posb, p2, flag);
    dist_kernel<<<dim3(32, 32), 256, 0, stream>>>(posb, p2, cb, argb, 0, flag);
    topk_kernel<<<NTOK, 256, 0, stream>>>(argb, idxb, 0);
    dist_kernel<<<dim3(32, 32), 256, 0, stream>>>(posb, p2, cb, argb, 1, flag);
    topk_kernel<<<NTOK, 256, 0, stream>>>(argb, idxb, 1);
    // 5. fused geometric attention
    attn_kernel<<<ROWS, 256, 0, stream>>>(posb, qb_, kb_, vb_, idxb, cb, geos, geob, asc, fsc, attnb, flag);
    // 6. x1 = x + attn @ Wo + bo
    gemm64<1, 0, 1, 0><<<dim3(8, 64), 256, 0, stream>>>(attnb, Wo, bo, x, x1, ROWS, DDIM, DDIM, flag);
    // 7. LN2
    ln_kernel<false><<<ROWS, 256, 0, stream>>>(x1, ln2s, ln2b, hbuf, flag);
    // 8. hh = gelu(h @ W1 + b1)   (bf16 internal, overlays dead argb)
    gemm64<2, 0, 0, 1><<<dim3(32, 64), 256, 0, stream>>>(hbuf, W1, b1, nullptr, hh, ROWS, FDIM, DDIM, flag);
    // 9. out = x1 + hh @ W2 + b2  (output dtype per flag)
    gemm64<1, 1, 2, 2><<<dim3(8, 64), 256, 0, stream>>>(hh, W2, b2, x1, d_out, ROWS, DDIM, FDIM, flag);

    (void)in_sizes; (void)n_in; (void)out_size; (void)ws_size;
}

// Round 4
// 474.559 us; speedup vs baseline: 2.1408x; 2.1408x over previous
//
#include <hip/hip_runtime.h>
#include <hip/hip_bf16.h>
#include <math.h>

#define NTOK 2048      // N
#define DDIM 512       // D
#define FDIM 2048      // F
#define KNN_K 16
#define ROWS 4096      // B*N

typedef __hip_bfloat16 hb;
typedef short s8v __attribute__((ext_vector_type(8)));
typedef float f4v __attribute__((ext_vector_type(4)));

__device__ __forceinline__ float b2f(hb h) { return __bfloat162float(h); }

// flagged load from an external input buffer: mode 1 = f32, 0 = bf16
__device__ __forceinline__ float ldin(const void* p, size_t i, int f32m) {
    return f32m ? ((const float*)p)[i] : b2f(((const hb*)p)[i]);
}
__device__ __forceinline__ float ld_scalar(const void* p, int f32m) {
    return f32m ? *(const float*)p : b2f(*(const hb*)p);
}

__device__ __forceinline__ float wred1(float a) {
    #pragma unroll
    for (int off = 32; off; off >>= 1) a += __shfl_down(a, off);
    return __shfl(a, 0);
}
__device__ __forceinline__ void wred2(float& a, float& b) {
    #pragma unroll
    for (int off = 32; off; off >>= 1) { a += __shfl_down(a, off); b += __shfl_down(b, off); }
    a = __shfl(a, 0); b = __shfl(b, 0);
}

__device__ __forceinline__ float gelu_f(float x) {
    float x3 = x * x * x;
    return 0.5f * x * (1.f + tanhf(0.7978845608028654f * (x + 0.044715f * x3)));
}

// ---------------- dtype detector ----------------
__global__ void detect_kernel(const void* __restrict__ x, int* __restrict__ flag) {
    const unsigned short* u = (const unsigned short*)x;
    int tid = threadIdx.x;
    int bad = 0;
    #pragma unroll
    for (int t = 0; t < 16; ++t) {
        unsigned short h = u[tid * 16 + t];
        int e = (h >> 7) & 0xFF;
        if (e == 0xFF) bad++;
        else if (e >= 0x8E) bad++;
        else if (e != 0 && e <= 0x66) bad++;
    }
    #pragma unroll
    for (int off = 32; off; off >>= 1) bad += __shfl_down(bad, off);
    if (tid == 0) *flag = (bad > 100) ? 1 : 0;
}

// ---------------- transpose external [K][N] -> bf16 [N][K] ----------------
__global__ void transpose_bf16(const void* __restrict__ src, hb* __restrict__ dst,
                               int K, int N, const int* __restrict__ fl) {
    const int fm = *fl;
    __shared__ float t[32][33];
    const int k0 = blockIdx.y * 32, n0 = blockIdx.x * 32;
    const int tx = threadIdx.x & 31, ty = threadIdx.x >> 5;   // 32 x 8
    #pragma unroll
    for (int r = 0; r < 32; r += 8)
        t[ty + r][tx] = ldin(src, (size_t)(k0 + ty + r) * N + n0 + tx, fm);
    __syncthreads();
    #pragma unroll
    for (int r = 0; r < 32; r += 8)
        dst[(size_t)(n0 + ty + r) * K + k0 + tx] = __float2bfloat16(t[tx][ty + r]);
}

// ---------------- positions hi/lo split ----------------
__global__ void possplit_kernel(const void* __restrict__ pos, hb* __restrict__ ph,
                                hb* __restrict__ pl, const int* __restrict__ fl) {
    const int fm = *fl;
    size_t i = (size_t)blockIdx.x * 256 + threadIdx.x;
    float v = ldin(pos, i, fm);
    hb h = __float2bfloat16(v);
    ph[i] = h;
    pl[i] = __float2bfloat16(v - b2f(h));
}

// ---------------- LayerNorm: out bf16 ----------------
template<bool EXT>
__global__ void ln_kernel(const void* __restrict__ xin,
                          const void* __restrict__ s, const void* __restrict__ b,
                          hb* __restrict__ y, const int* __restrict__ fl) {
    const int m = *fl;
    const int row = blockIdx.x, tid = threadIdx.x;
    float v0, v1;
    if (EXT) {
        v0 = ldin(xin, (size_t)row * DDIM + tid, m);
        v1 = ldin(xin, (size_t)row * DDIM + tid + 256, m);
    } else {
        const float* xp = (const float*)xin + (size_t)row * DDIM;
        v0 = xp[tid]; v1 = xp[tid + 256];
    }
    float sum = v0 + v1, sq = v0 * v0 + v1 * v1;
    const int lane = tid & 63, wv = tid >> 6;
    #pragma unroll
    for (int off = 32; off; off >>= 1) { sum += __shfl_down(sum, off); sq += __shfl_down(sq, off); }
    __shared__ float ls[8];
    if (lane == 0) { ls[wv] = sum; ls[4 + wv] = sq; }
    __syncthreads();
    float ts = ls[0] + ls[1] + ls[2] + ls[3];
    float tq = ls[4] + ls[5] + ls[6] + ls[7];
    float mean = ts * (1.f / DDIM);
    float var = tq * (1.f / DDIM) - mean * mean;
    float rstd = rsqrtf(var + 1e-6f);
    y[(size_t)row * DDIM + tid]       = __float2bfloat16(ldin(s, tid, m) * (v0 - mean) * rstd + ldin(b, tid, m));
    y[(size_t)row * DDIM + tid + 256] = __float2bfloat16(ldin(s, tid + 256, m) * (v1 - mean) * rstd + ldin(b, tid + 256, m));
}

// ---------------- p2 = sum(pos^2) per row ----------------
__global__ void p2_kernel(const void* __restrict__ pos, float* __restrict__ p2,
                          const int* __restrict__ fl) {
    const int m = *fl;
    const int row = blockIdx.x, tid = threadIdx.x;
    float v0 = ldin(pos, (size_t)row * DDIM + tid, m);
    float v1 = ldin(pos, (size_t)row * DDIM + tid + 256, m);
    float s = v0 * v0 + v1 * v1;
    const int lane = tid & 63, wv = tid >> 6;
    #pragma unroll
    for (int off = 32; off; off >>= 1) s += __shfl_down(s, off);
    __shared__ float ls[4];
    if (lane == 0) ls[wv] = s;
    __syncthreads();
    if (tid == 0) p2[row] = ls[0] + ls[1] + ls[2] + ls[3];
}

// ================ MFMA GEMM: C[M][N] = A[M][K](bf16) @ Bt[N][K]^T + epilogue ================
// 128x128 tile, 4 waves in 2x2, each wave 64x64 (4x4 frags of 16x16x32).
// EPI: 0 = qkv (+bias from 3 ptrs by n>>9, out bf16)
//      1 = Wo  (+bias + external-res, out f32)
//      2 = W1  (gelu(+bias), out bf16)
//      3 = W2  (+bias + internal f32 res, out flagged to d_out)
template<int EPI>
__global__ __launch_bounds__(256, 2)
void gemm_bt(const hb* __restrict__ A, const hb* __restrict__ Bt,
             const void* __restrict__ bp0, const void* __restrict__ bp1, const void* __restrict__ bp2,
             const void* __restrict__ res, void* __restrict__ C,
             int N, int K, int lda, int ldb, int ldc,
             const int* __restrict__ fl) {
    const int fm = *fl;
    __shared__ short As[128 * 40];
    __shared__ short Bs[128 * 40];
    const int tid = threadIdx.x, lane = tid & 63, wave = tid >> 6;
    const int wy = wave >> 1, wx = wave & 1;
    const int m0 = blockIdx.y * 128, n0 = blockIdx.x * 128;
    const int srow = tid >> 2, schk = (tid & 3) * 8;
    const int lm = lane & 15, lk = (lane >> 4) * 8;
    f4v acc[4][4];
    #pragma unroll
    for (int i = 0; i < 4; ++i)
        #pragma unroll
        for (int j = 0; j < 4; ++j) acc[i][j] = (f4v){0.f, 0.f, 0.f, 0.f};

    for (int k0 = 0; k0 < K; k0 += 32) {
        const s8v a0 = *(const s8v*)(A + (size_t)(m0 + srow) * lda + k0 + schk);
        const s8v a1 = *(const s8v*)(A + (size_t)(m0 + 64 + srow) * lda + k0 + schk);
        const s8v b0 = *(const s8v*)(Bt + (size_t)(n0 + srow) * ldb + k0 + schk);
        const s8v b1 = *(const s8v*)(Bt + (size_t)(n0 + 64 + srow) * ldb + k0 + schk);
        __syncthreads();
        *(s8v*)(As + srow * 40 + schk) = a0;
        *(s8v*)(As + (64 + srow) * 40 + schk) = a1;
        *(s8v*)(Bs + srow * 40 + schk) = b0;
        *(s8v*)(Bs + (64 + srow) * 40 + schk) = b1;
        __syncthreads();
        s8v af[4], bf[4];
        #pragma unroll
        for (int f = 0; f < 4; ++f) {
            af[f] = *(const s8v*)(As + (wy * 64 + f * 16 + lm) * 40 + lk);
            bf[f] = *(const s8v*)(Bs + (wx * 64 + f * 16 + lm) * 40 + lk);
        }
        #pragma unroll
        for (int fi = 0; fi < 4; ++fi)
            #pragma unroll
            for (int fj = 0; fj < 4; ++fj)
                acc[fi][fj] = __builtin_amdgcn_mfma_f32_16x16x32_bf16(af[fi], bf[fj], acc[fi][fj], 0, 0, 0);
    }

    const int embase = m0 + wy * 64 + (lane >> 4) * 4;
    const int enbase = n0 + wx * 64 + lm;
    #pragma unroll
    for (int fi = 0; fi < 4; ++fi) {
        #pragma unroll
        for (int fj = 0; fj < 4; ++fj) {
            const int n = enbase + fj * 16;
            #pragma unroll
            for (int r = 0; r < 4; ++r) {
                const int m = embase + fi * 16 + r;
                float val = acc[fi][fj][r];
                size_t ci = (size_t)m * ldc + n;
                if (EPI == 0) {
                    const void* bp = (n < 512) ? bp0 : ((n < 1024) ? bp1 : bp2);
                    val += ldin(bp, n & 511, fm);
                    ((hb*)C)[ci] = __float2bfloat16(val);
                } else if (EPI == 1) {
                    val += ldin(bp0, n, fm) + ldin(res, (size_t)m * 512 + n, fm);
                    ((float*)C)[ci] = val;
                } else if (EPI == 2) {
                    val = gelu_f(val + ldin(bp0, n, fm));
                    ((hb*)C)[ci] = __float2bfloat16(val);
                } else {
                    val += ldin(bp0, n, fm) + ((const float*)res)[(size_t)m * 512 + n];
                    if (fm) ((float*)C)[ci] = val;
                    else ((hb*)C)[ci] = __float2bfloat16(val);
                }
            }
        }
    }
}

// ================ dist MFMA: per-batch arg = 1 + 2c*diff/den via split hi/lo ================
__global__ __launch_bounds__(256, 2)
void dist_mfma(const hb* __restrict__ ph, const hb* __restrict__ pl,
               const float* __restrict__ p2, const void* __restrict__ cp,
               float* __restrict__ out, int bb, const int* __restrict__ fl) {
    const int fm = *fl;
    const float c = ld_scalar(cp, fm);
    const float* p2b = p2 + bb * NTOK;
    const size_t rb = (size_t)bb * NTOK;
    __shared__ short As[128 * 40];
    __shared__ short Bs[128 * 40];
    const int tid = threadIdx.x, lane = tid & 63, wave = tid >> 6;
    const int wy = wave >> 1, wx = wave & 1;
    const int i0 = blockIdx.y * 128, j0 = blockIdx.x * 128;
    const int srow = tid >> 2, schk = (tid & 3) * 8;
    const int lm = lane & 15, lk = (lane >> 4) * 8;
    f4v acc[4][4];
    #pragma unroll
    for (int i = 0; i < 4; ++i)
        #pragma unroll
        for (int j = 0; j < 4; ++j) acc[i][j] = (f4v){0.f, 0.f, 0.f, 0.f};

    const hb* Ap[3] = {ph, ph, pl};
    const hb* Bp[3] = {ph, pl, ph};
    for (int p = 0; p < 3; ++p) {
        const hb* Asrc = Ap[p]; const hb* Bsrc = Bp[p];
        for (int k0 = 0; k0 < DDIM; k0 += 32) {
            const s8v a0 = *(const s8v*)(Asrc + (rb + i0 + srow) * DDIM + k0 + schk);
            const s8v a1 = *(const s8v*)(Asrc + (rb + i0 + 64 + srow) * DDIM + k0 + schk);
            const s8v b0 = *(const s8v*)(Bsrc + (rb + j0 + srow) * DDIM + k0 + schk);
            const s8v b1 = *(const s8v*)(Bsrc + (rb + j0 + 64 + srow) * DDIM + k0 + schk);
            __syncthreads();
            *(s8v*)(As + srow * 40 + schk) = a0;
            *(s8v*)(As + (64 + srow) * 40 + schk) = a1;
            *(s8v*)(Bs + srow * 40 + schk) = b0;
            *(s8v*)(Bs + (64 + srow) * 40 + schk) = b1;
            __syncthreads();
            s8v af[4], bf[4];
            #pragma unroll
            for (int f = 0; f < 4; ++f) {
                af[f] = *(const s8v*)(As + (wy * 64 + f * 16 + lm) * 40 + lk);
                bf[f] = *(const s8v*)(Bs + (wx * 64 + f * 16 + lm) * 40 + lk);
            }
            #pragma unroll
            for (int fi = 0; fi < 4; ++fi)
                #pragma unroll
                for (int fj = 0; fj < 4; ++fj)
                    acc[fi][fj] = __builtin_amdgcn_mfma_f32_16x16x32_bf16(af[fi], bf[fj], acc[fi][fj], 0, 0, 0);
        }
    }

    const int eibase = i0 + wy * 64 + (lane >> 4) * 4;
    const int ejbase = j0 + wx * 64 + lm;
    #pragma unroll
    for (int fi = 0; fi < 4; ++fi) {
        #pragma unroll
        for (int fj = 0; fj < 4; ++fj) {
            const int jj = ejbase + fj * 16;
            const float p2j = p2b[jj];
            #pragma unroll
            for (int r = 0; r < 4; ++r) {
                const int ii = eibase + fi * 16 + r;
                const float p2i = p2b[ii];
                float diff = fmaxf(p2i + p2j - 2.f * acc[fi][fj][r], 0.f);
                float den = fmaxf((1.f - c * p2i) * (1.f - c * p2j), 1e-8f);
                out[(size_t)ii * NTOK + jj] = 1.f + 2.f * c * diff / den;
            }
        }
    }
}

// ---------------- top-16 smallest per row ----------------
__global__ void topk_kernel(const float* __restrict__ argb, int* __restrict__ idxb, int bb) {
    const int r = blockIdx.x;
    const float* arow = argb + (size_t)r * NTOK;
    int* orow = idxb + ((size_t)bb * NTOK + r) * KNN_K;
    __shared__ float vals[NTOK];
    __shared__ float rv[256];
    __shared__ int   ri[256];
    for (int t = threadIdx.x; t < NTOK; t += 256) vals[t] = arow[t];
    __syncthreads();
    for (int sel = 0; sel < KNN_K; ++sel) {
        float best = 3.4e38f; int bi = -1;
        for (int t = threadIdx.x; t < NTOK; t += 256) {
            float vv = vals[t];
            if (vv < best) { best = vv; bi = t; }
        }
        rv[threadIdx.x] = best; ri[threadIdx.x] = bi;
        __syncthreads();
        for (int s = 128; s > 0; s >>= 1) {
            if (threadIdx.x < s) {
                float ov = rv[threadIdx.x + s]; int oi = ri[threadIdx.x + s];
                if (ov < rv[threadIdx.x] ||
                    (ov == rv[threadIdx.x] && oi >= 0 && (ri[threadIdx.x] < 0 || oi < ri[threadIdx.x]))) {
                    rv[threadIdx.x] = ov; ri[threadIdx.x] = oi;
                }
            }
            __syncthreads();
        }
        if (threadIdx.x == 0) { int w = ri[0] < 0 ? 0 : ri[0]; orow[sel] = w; vals[w] = 3.4e38f; }
        __syncthreads();
    }
}

// ---------------- fused gather + mobius/logmap + LN(geo) + scores + softmax + attn ----------------
__global__ void attn_kernel(const void* __restrict__ pos,
                            const hb* __restrict__ qkvB, const int* __restrict__ idxb,
                            const void* __restrict__ cp,
                            const void* __restrict__ geo_s, const void* __restrict__ geo_b,
                            const void* __restrict__ a_sc, const void* __restrict__ f_sc,
                            hb* __restrict__ attnO, const int* __restrict__ fl) {
    const int fm = *fl;
    const int row = blockIdx.x;
    const int bb = row >> 11;
    const int tid = threadIdx.x, lane = tid & 63, wv = tid >> 6;
    __shared__ float qp_s[DDIM], q_s[DDIM], gs_s[DDIM], gb_s[DDIM];
    __shared__ float sc_s[KNN_K];
    __shared__ int nid_s[KNN_K];
    const float c = ld_scalar(cp, fm);
    for (int i = tid; i < DDIM; i += 256) {
        qp_s[i] = ldin(pos, (size_t)row * DDIM + i, fm);
        q_s[i]  = b2f(qkvB[(size_t)row * 1536 + i]);
        gs_s[i] = ldin(geo_s, i, fm);
        gb_s[i] = ldin(geo_b, i, fm);
    }
    if (tid < KNN_K) nid_s[tid] = idxb[row * KNN_K + tid];
    __syncthreads();
    float qpl[8];
    float x2p = 0.f;
    #pragma unroll
    for (int t = 0; t < 8; ++t) { float e = qp_s[lane + 64 * t]; qpl[t] = e; x2p += e * e; }
    const float x2 = wred1(x2p);
    const float sc_c = sqrtf(fmaxf(c, 0.f));
    for (int it = 0; it < 4; ++it) {
        const int kk = it * 4 + wv;
        const int j = nid_s[kk];
        const size_t nro = (size_t)(bb * NTOK + j) * DDIM;
        const size_t nro3 = (size_t)(bb * NTOK + j) * 1536;
        float kpl[8];
        float xy = 0.f, y2 = 0.f;
        #pragma unroll
        for (int t = 0; t < 8; ++t) {
            float e = ldin(pos, nro + lane + 64 * t, fm);
            kpl[t] = e; xy += qpl[t] * e; y2 += e * e;
        }
        wred2(xy, y2);
        const float xym = -xy;
        const float Af = 1.f + 2.f * c * xym + c * y2;
        const float Bf = 1.f - c * x2;
        float den = 1.f + 2.f * c * xym + c * c * x2 * y2;
        den = fmaxf(den, 1e-8f);
        const float rden = 1.f / den;
        float mal[8]; float n2 = 0.f;
        #pragma unroll
        for (int t = 0; t < 8; ++t) {
            float m = (Af * (-qpl[t]) + Bf * kpl[t]) * rden;
            mal[t] = m; n2 += m * m;
        }
        n2 = wred1(n2);
        const float ynorm = fmaxf(sqrtf(n2), 1e-8f);
        const float t_over = sc_c * ynorm;
        const float targ = fminf(t_over, 1.f - 1e-7f);
        const float scale = (targ > 0.f) ? (atanhf(targ) / t_over) : 1.f;
        float sum = 0.f, sq = 0.f; float gl[8];
        #pragma unroll
        for (int t = 0; t < 8; ++t) { float g = scale * mal[t]; gl[t] = g; sum += g; sq += g * g; }
        wred2(sum, sq);
        const float mean = sum * (1.f / DDIM);
        const float var = sq * (1.f / DDIM) - mean * mean;
        const float rstd = rsqrtf(fmaxf(var, 0.f) + 1e-6f);
        float align = 0.f, feat = 0.f;
        #pragma unroll
        for (int t = 0; t < 8; ++t) {
            const int d = lane + 64 * t;
            float gn = gs_s[d] * (gl[t] - mean) * rstd + gb_s[d];
            float kv = b2f(qkvB[nro3 + 512 + d]);
            align += q_s[d] * gn;
            feat  += q_s[d] * kv;
        }
        wred2(align, feat);
        if (lane == 0) sc_s[kk] = ld_scalar(f_sc, fm) * feat + ld_scalar(a_sc, fm) * align;
    }
    __syncthreads();
    float wgt[KNN_K];
    float mx = -1e30f;
    #pragma unroll
    for (int t = 0; t < KNN_K; ++t) mx = fmaxf(mx, sc_s[t]);
    float ssum = 0.f;
    #pragma unroll
    for (int t = 0; t < KNN_K; ++t) { float e = expf(sc_s[t] - mx); wgt[t] = e; ssum += e; }
    const float rs = 1.f / ssum;
    for (int d = tid; d < DDIM; d += 256) {
        float acc = 0.f;
        #pragma unroll
        for (int t = 0; t < KNN_K; ++t)
            acc += wgt[t] * b2f(qkvB[(size_t)(bb * NTOK + nid_s[t]) * 1536 + 1024 + d]);
        attnO[(size_t)row * DDIM + d] = __float2bfloat16(acc * rs);
    }
}

extern "C" void kernel_launch(void* const* d_in, const int* in_sizes, int n_in,
                              void* d_out, int out_size, void* d_ws, size_t ws_size,
                              hipStream_t stream) {
    const void* x    = d_in[0];
    const void* posb = d_in[1];
    const void* cb   = d_in[2];
    const void* Wq   = d_in[3];
    const void* bq   = d_in[4];
    const void* Wk   = d_in[5];
    const void* bk   = d_in[6];
    const void* Wv   = d_in[7];
    const void* bv   = d_in[8];
    const void* Wo   = d_in[9];
    const void* bo   = d_in[10];
    const void* W1   = d_in[11];
    const void* b1   = d_in[12];
    const void* W2   = d_in[13];
    const void* b2   = d_in[14];
    const void* ln1s = d_in[15];
    const void* ln1b = d_in[16];
    const void* ln2s = d_in[17];
    const void* ln2b = d_in[18];
    const void* geos = d_in[19];
    const void* geob = d_in[20];
    const void* asc  = d_in[21];
    const void* fsc  = d_in[22];

    float* wsf = (float*)d_ws;
    int* flag = (int*)wsf;
    size_t off = 16;
    hb* xnB   = (hb*)(wsf + off); off += 1048576;   // 4096x512 bf16; later hbuf (LN2 out)
    hb* qkvB  = (hb*)(wsf + off); off += 3145728;   // 4096x1536 bf16
    float* p2 = wsf + off;        off += 4096;
    int* idxb = (int*)(wsf + off); off += 65536;
    float* x1 = wsf + off;        off += 2097152;   // f32 4096x512
    float* argb = wsf + off;                         // NTOK^2 f32 (per batch)
    hb* hh    = (hb*)argb;        off += 4194304;   // later 4096x2048 bf16
    hb* ph    = (hb*)(wsf + off); off += 1048576;   // later attnO
    hb* pl    = (hb*)(wsf + off); off += 1048576;   // later W1T+W2T
    hb* WqkvT = (hb*)(wsf + off); off += 393216;    // 1536x512 bf16
    hb* WoT   = (hb*)(wsf + off); off += 131072;    // 512x512 bf16
    hb* attnO = ph;
    hb* W1T   = pl;                                  // 2048x512 bf16
    hb* W2T   = pl + 1048576;                        // 512x2048 bf16
    hb* hbuf  = xnB;

    // 0. dtype detection
    detect_kernel<<<1, 64, 0, stream>>>(x, flag);
    // weight transposes (N x K bf16)
    transpose_bf16<<<dim3(16, 16), 256, 0, stream>>>(Wq, WqkvT,              512, 512, flag);
    transpose_bf16<<<dim3(16, 16), 256, 0, stream>>>(Wk, WqkvT + 512 * 512,  512, 512, flag);
    transpose_bf16<<<dim3(16, 16), 256, 0, stream>>>(Wv, WqkvT + 1024 * 512, 512, 512, flag);
    transpose_bf16<<<dim3(16, 16), 256, 0, stream>>>(Wo, WoT,                512, 512, flag);
    // positions split
    possplit_kernel<<<ROWS * DDIM / 256, 256, 0, stream>>>(posb, ph, pl, flag);
    // 1. LN1 -> bf16
    ln_kernel<true><<<ROWS, 256, 0, stream>>>(x, ln1s, ln1b, xnB, flag);
    // 2. fused qkv GEMM: [4096x512] @ [512x1536] -> bf16 [4096x1536]
    gemm_bt<0><<<dim3(12, 32), 256, 0, stream>>>(xnB, WqkvT, bq, bk, bv, nullptr, qkvB,
                                                 1536, 512, 512, 512, 1536, flag);
    // 3. distances + top-16 per batch
    p2_kernel<<<ROWS, 256, 0, stream>>>(posb, p2, flag);
    dist_mfma<<<dim3(16, 16), 256, 0, stream>>>(ph, pl, p2, cb, argb, 0, flag);
    topk_kernel<<<NTOK, 256, 0, stream>>>(argb, idxb, 0);
    dist_mfma<<<dim3(16, 16), 256, 0, stream>>>(ph, pl, p2, cb, argb, 1, flag);
    topk_kernel<<<NTOK, 256, 0, stream>>>(argb, idxb, 1);
    // FFN weight transposes (into pl region, dead after dist)
    transpose_bf16<<<dim3(64, 16), 256, 0, stream>>>(W1, W1T, 512, 2048, flag);
    transpose_bf16<<<dim3(16, 64), 256, 0, stream>>>(W2, W2T, 2048, 512, flag);
    // 5. fused geometric attention -> bf16 (overlays ph)
    attn_kernel<<<ROWS, 256, 0, stream>>>(posb, qkvB, idxb, cb, geos, geob, asc, fsc, attnO, flag);
    // 6. x1 = x + attn @ Wo + bo  (f32)
    gemm_bt<1><<<dim3(4, 32), 256, 0, stream>>>(attnO, WoT, bo, nullptr, nullptr, x, x1,
                                                512, 512, 512, 512, 512, flag);
    // 7. LN2 -> bf16
    ln_kernel<false><<<ROWS, 256, 0, stream>>>(x1, ln2s, ln2b, hbuf, flag);
    // 8. hh = gelu(h @ W1 + b1) -> bf16
    gemm_bt<2><<<dim3(16, 32), 256, 0, stream>>>(hbuf, W1T, b1, nullptr, nullptr, nullptr, hh,
                                                 2048, 512, 512, 512, 2048, flag);
    // 9. out = x1 + hh @ W2 + b2
    gemm_bt<3><<<dim3(4, 32), 256, 0, stream>>>(hh, W2T, b2, nullptr, nullptr, x1, d_out,
                                                512, 2048, 2048, 2048, 512, flag);

    (void)in_sizes; (void)n_in; (void)out_size; (void)ws_size;
}

// Round 5
// 457.653 us; speedup vs baseline: 2.2199x; 1.0369x over previous
//
#include <hip/hip_runtime.h>
#include <hip/hip_bf16.h>
#include <math.h>

#define NTOK 2048      // N
#define DDIM 512       // D
#define FDIM 2048      // F
#define KNN_K 16
#define ROWS 4096      // B*N

typedef __hip_bfloat16 hb;
typedef unsigned long long ull;
typedef short s8v __attribute__((ext_vector_type(8)));
typedef float f4v __attribute__((ext_vector_type(4)));

__device__ __forceinline__ float b2f(hb h) { return __bfloat162float(h); }

// flagged load from an external input buffer: mode 1 = f32, 0 = bf16
__device__ __forceinline__ float ldin(const void* p, size_t i, int f32m) {
    return f32m ? ((const float*)p)[i] : b2f(((const hb*)p)[i]);
}
__device__ __forceinline__ float ld_scalar(const void* p, int f32m) {
    return f32m ? *(const float*)p : b2f(*(const hb*)p);
}

__device__ __forceinline__ ull shfl_down_u64(ull x, int off) {
    unsigned lo = (unsigned)x, hi = (unsigned)(x >> 32);
    lo = __shfl_down(lo, off); hi = __shfl_down(hi, off);
    return ((ull)hi << 32) | lo;
}

__device__ __forceinline__ float gelu_f(float x) {
    float x3 = x * x * x;
    return 0.5f * x * (1.f + tanhf(0.7978845608028654f * (x + 0.044715f * x3)));
}

// ---------------- dtype detector ----------------
__global__ void detect_kernel(const void* __restrict__ x, int* __restrict__ flag) {
    const unsigned short* u = (const unsigned short*)x;
    int tid = threadIdx.x;
    int bad = 0;
    #pragma unroll
    for (int t = 0; t < 16; ++t) {
        unsigned short h = u[tid * 16 + t];
        int e = (h >> 7) & 0xFF;
        if (e == 0xFF) bad++;
        else if (e >= 0x8E) bad++;
        else if (e != 0 && e <= 0x66) bad++;
    }
    #pragma unroll
    for (int off = 32; off; off >>= 1) bad += __shfl_down(bad, off);
    if (tid == 0) *flag = (bad > 100) ? 1 : 0;
}

// ---------------- transpose external [K][N] -> bf16 [N][K] ----------------
__global__ void transpose_bf16(const void* __restrict__ src, hb* __restrict__ dst,
                               int K, int N, const int* __restrict__ fl) {
    const int fm = *fl;
    __shared__ float t[32][33];
    const int k0 = blockIdx.y * 32, n0 = blockIdx.x * 32;
    const int tx = threadIdx.x & 31, ty = threadIdx.x >> 5;   // 32 x 8
    #pragma unroll
    for (int r = 0; r < 32; r += 8)
        t[ty + r][tx] = ldin(src, (size_t)(k0 + ty + r) * N + n0 + tx, fm);
    __syncthreads();
    #pragma unroll
    for (int r = 0; r < 32; r += 8)
        dst[(size_t)(n0 + ty + r) * K + k0 + tx] = __float2bfloat16(t[tx][ty + r]);
}

// ---------------- positions hi/lo split + p2 (fused, one block per row) ----------------
__global__ void possplit_p2(const void* __restrict__ pos, hb* __restrict__ ph,
                            hb* __restrict__ pl, float* __restrict__ p2,
                            const int* __restrict__ fl) {
    const int fm = *fl;
    const int row = blockIdx.x, tid = threadIdx.x;
    float s = 0.f;
    #pragma unroll
    for (int t = 0; t < 2; ++t) {
        size_t i = (size_t)row * DDIM + tid + 256 * t;
        float v = ldin(pos, i, fm);
        hb h = __float2bfloat16(v);
        ph[i] = h;
        pl[i] = __float2bfloat16(v - b2f(h));
        s += v * v;
    }
    const int lane = tid & 63, wv = tid >> 6;
    #pragma unroll
    for (int off = 32; off; off >>= 1) s += __shfl_down(s, off);
    __shared__ float ls[4];
    if (lane == 0) ls[wv] = s;
    __syncthreads();
    if (tid == 0) p2[row] = ls[0] + ls[1] + ls[2] + ls[3];
}

// ---------------- LayerNorm: out bf16 ----------------
template<bool EXT>
__global__ void ln_kernel(const void* __restrict__ xin,
                          const void* __restrict__ s, const void* __restrict__ b,
                          hb* __restrict__ y, const int* __restrict__ fl) {
    const int m = *fl;
    const int row = blockIdx.x, tid = threadIdx.x;
    float v0, v1;
    if (EXT) {
        v0 = ldin(xin, (size_t)row * DDIM + tid, m);
        v1 = ldin(xin, (size_t)row * DDIM + tid + 256, m);
    } else {
        const float* xp = (const float*)xin + (size_t)row * DDIM;
        v0 = xp[tid]; v1 = xp[tid + 256];
    }
    float sum = v0 + v1, sq = v0 * v0 + v1 * v1;
    const int lane = tid & 63, wv = tid >> 6;
    #pragma unroll
    for (int off = 32; off; off >>= 1) { sum += __shfl_down(sum, off); sq += __shfl_down(sq, off); }
    __shared__ float ls[8];
    if (lane == 0) { ls[wv] = sum; ls[4 + wv] = sq; }
    __syncthreads();
    float ts = ls[0] + ls[1] + ls[2] + ls[3];
    float tq = ls[4] + ls[5] + ls[6] + ls[7];
    float mean = ts * (1.f / DDIM);
    float var = tq * (1.f / DDIM) - mean * mean;
    float rstd = rsqrtf(var + 1e-6f);
    y[(size_t)row * DDIM + tid]       = __float2bfloat16(ldin(s, tid, m) * (v0 - mean) * rstd + ldin(b, tid, m));
    y[(size_t)row * DDIM + tid + 256] = __float2bfloat16(ldin(s, tid + 256, m) * (v1 - mean) * rstd + ldin(b, tid + 256, m));
}

// ================ MFMA GEMM: C[M][N] = A[M][K](bf16) @ Bt[N][K]^T + epilogue ================
// EPI: 0 = qkv (+bias from 3 ptrs by n>>9, out bf16)
//      1 = Wo  (+bias + external-res, out f32)
//      2 = W1  (gelu(+bias), out bf16)
//      3 = W2  (+bias + internal f32 res, out flagged to d_out)
template<int EPI>
__global__ __launch_bounds__(256, 2)
void gemm_bt(const hb* __restrict__ A, const hb* __restrict__ Bt,
             const void* __restrict__ bp0, const void* __restrict__ bp1, const void* __restrict__ bp2,
             const void* __restrict__ res, void* __restrict__ C,
             int N, int K, int lda, int ldb, int ldc,
             const int* __restrict__ fl) {
    const int fm = *fl;
    __shared__ short As[128 * 40];
    __shared__ short Bs[128 * 40];
    const int tid = threadIdx.x, lane = tid & 63, wave = tid >> 6;
    const int wy = wave >> 1, wx = wave & 1;
    const int m0 = blockIdx.y * 128, n0 = blockIdx.x * 128;
    const int srow = tid >> 2, schk = (tid & 3) * 8;
    const int lm = lane & 15, lk = (lane >> 4) * 8;
    f4v acc[4][4];
    #pragma unroll
    for (int i = 0; i < 4; ++i)
        #pragma unroll
        for (int j = 0; j < 4; ++j) acc[i][j] = (f4v){0.f, 0.f, 0.f, 0.f};

    for (int k0 = 0; k0 < K; k0 += 32) {
        const s8v a0 = *(const s8v*)(A + (size_t)(m0 + srow) * lda + k0 + schk);
        const s8v a1 = *(const s8v*)(A + (size_t)(m0 + 64 + srow) * lda + k0 + schk);
        const s8v b0 = *(const s8v*)(Bt + (size_t)(n0 + srow) * ldb + k0 + schk);
        const s8v b1 = *(const s8v*)(Bt + (size_t)(n0 + 64 + srow) * ldb + k0 + schk);
        __syncthreads();
        *(s8v*)(As + srow * 40 + schk) = a0;
        *(s8v*)(As + (64 + srow) * 40 + schk) = a1;
        *(s8v*)(Bs + srow * 40 + schk) = b0;
        *(s8v*)(Bs + (64 + srow) * 40 + schk) = b1;
        __syncthreads();
        s8v af[4], bf[4];
        #pragma unroll
        for (int f = 0; f < 4; ++f) {
            af[f] = *(const s8v*)(As + (wy * 64 + f * 16 + lm) * 40 + lk);
            bf[f] = *(const s8v*)(Bs + (wx * 64 + f * 16 + lm) * 40 + lk);
        }
        #pragma unroll
        for (int fi = 0; fi < 4; ++fi)
            #pragma unroll
            for (int fj = 0; fj < 4; ++fj)
                acc[fi][fj] = __builtin_amdgcn_mfma_f32_16x16x32_bf16(af[fi], bf[fj], acc[fi][fj], 0, 0, 0);
    }

    const int embase = m0 + wy * 64 + (lane >> 4) * 4;
    const int enbase = n0 + wx * 64 + lm;
    #pragma unroll
    for (int fi = 0; fi < 4; ++fi) {
        #pragma unroll
        for (int fj = 0; fj < 4; ++fj) {
            const int n = enbase + fj * 16;
            #pragma unroll
            for (int r = 0; r < 4; ++r) {
                const int m = embase + fi * 16 + r;
                float val = acc[fi][fj][r];
                size_t ci = (size_t)m * ldc + n;
                if (EPI == 0) {
                    const void* bp = (n < 512) ? bp0 : ((n < 1024) ? bp1 : bp2);
                    val += ldin(bp, n & 511, fm);
                    ((hb*)C)[ci] = __float2bfloat16(val);
                } else if (EPI == 1) {
                    val += ldin(bp0, n, fm) + ldin(res, (size_t)m * 512 + n, fm);
                    ((float*)C)[ci] = val;
                } else if (EPI == 2) {
                    val = gelu_f(val + ldin(bp0, n, fm));
                    ((hb*)C)[ci] = __float2bfloat16(val);
                } else {
                    val += ldin(bp0, n, fm) + ((const float*)res)[(size_t)m * 512 + n];
                    if (fm) ((float*)C)[ci] = val;
                    else ((hb*)C)[ci] = __float2bfloat16(val);
                }
            }
        }
    }
}

// ================ dist MFMA: per-batch arg = 1 + 2c*diff/den via split hi/lo ================
__global__ __launch_bounds__(256, 2)
void dist_mfma(const hb* __restrict__ ph, const hb* __restrict__ pl,
               const float* __restrict__ p2, const void* __restrict__ cp,
               float* __restrict__ out, int bb, const int* __restrict__ fl) {
    const int fm = *fl;
    const float c = ld_scalar(cp, fm);
    const float* p2b = p2 + bb * NTOK;
    const size_t rb = (size_t)bb * NTOK;
    __shared__ short As[128 * 40];
    __shared__ short Bs[128 * 40];
    const int tid = threadIdx.x, lane = tid & 63, wave = tid >> 6;
    const int wy = wave >> 1, wx = wave & 1;
    const int i0 = blockIdx.y * 128, j0 = blockIdx.x * 128;
    const int srow = tid >> 2, schk = (tid & 3) * 8;
    const int lm = lane & 15, lk = (lane >> 4) * 8;
    f4v acc[4][4];
    #pragma unroll
    for (int i = 0; i < 4; ++i)
        #pragma unroll
        for (int j = 0; j < 4; ++j) acc[i][j] = (f4v){0.f, 0.f, 0.f, 0.f};

    const hb* Ap[3] = {ph, ph, pl};
    const hb* Bp[3] = {ph, pl, ph};
    for (int p = 0; p < 3; ++p) {
        const hb* Asrc = Ap[p]; const hb* Bsrc = Bp[p];
        for (int k0 = 0; k0 < DDIM; k0 += 32) {
            const s8v a0 = *(const s8v*)(Asrc + (rb + i0 + srow) * DDIM + k0 + schk);
            const s8v a1 = *(const s8v*)(Asrc + (rb + i0 + 64 + srow) * DDIM + k0 + schk);
            const s8v b0 = *(const s8v*)(Bsrc + (rb + j0 + srow) * DDIM + k0 + schk);
            const s8v b1 = *(const s8v*)(Bsrc + (rb + j0 + 64 + srow) * DDIM + k0 + schk);
            __syncthreads();
            *(s8v*)(As + srow * 40 + schk) = a0;
            *(s8v*)(As + (64 + srow) * 40 + schk) = a1;
            *(s8v*)(Bs + srow * 40 + schk) = b0;
            *(s8v*)(Bs + (64 + srow) * 40 + schk) = b1;
            __syncthreads();
            s8v af[4], bf[4];
            #pragma unroll
            for (int f = 0; f < 4; ++f) {
                af[f] = *(const s8v*)(As + (wy * 64 + f * 16 + lm) * 40 + lk);
                bf[f] = *(const s8v*)(Bs + (wx * 64 + f * 16 + lm) * 40 + lk);
            }
            #pragma unroll
            for (int fi = 0; fi < 4; ++fi)
                #pragma unroll
                for (int fj = 0; fj < 4; ++fj)
                    acc[fi][fj] = __builtin_amdgcn_mfma_f32_16x16x32_bf16(af[fi], bf[fj], acc[fi][fj], 0, 0, 0);
        }
    }

    const int eibase = i0 + wy * 64 + (lane >> 4) * 4;
    const int ejbase = j0 + wx * 64 + lm;
    #pragma unroll
    for (int fi = 0; fi < 4; ++fi) {
        #pragma unroll
        for (int fj = 0; fj < 4; ++fj) {
            const int jj = ejbase + fj * 16;
            const float p2j = p2b[jj];
            #pragma unroll
            for (int r = 0; r < 4; ++r) {
                const int ii = eibase + fi * 16 + r;
                const float p2i = p2b[ii];
                float diff = fmaxf(p2i + p2j - 2.f * acc[fi][fj][r], 0.f);
                float den = fmaxf((1.f - c * p2i) * (1.f - c * p2j), 1e-8f);
                out[(size_t)ii * NTOK + jj] = 1.f + 2.f * c * diff / den;
            }
        }
    }
}

// ---------------- top-16 smallest per row: register-resident, packed u64 keys ----------------
// arg >= 1.0 > 0 so float bit pattern is order-preserving; key = (bits<<32)|idx
// => min key = (min val, then min idx) — matches lax.top_k tie-break.
__global__ void topk_kernel(const float* __restrict__ argb, int* __restrict__ idxb, int bb) {
    const int r = blockIdx.x;
    const float* arow = argb + (size_t)r * NTOK;
    int* orow = idxb + ((size_t)bb * NTOK + r) * KNN_K;
    const int tid = threadIdx.x, lane = tid & 63, wv = tid >> 6;
    ull k8[8];
    #pragma unroll
    for (int i = 0; i < 8; ++i) {
        int idx = i * 256 + tid;
        unsigned int bbits = __float_as_uint(arow[idx]);
        k8[i] = ((ull)bbits << 32) | (unsigned int)idx;
    }
    __shared__ ull lw[4];
    for (int sel = 0; sel < KNN_K; ++sel) {
        ull m = k8[0];
        #pragma unroll
        for (int i = 1; i < 8; ++i) m = (k8[i] < m) ? k8[i] : m;
        #pragma unroll
        for (int off = 32; off; off >>= 1) {
            ull o = shfl_down_u64(m, off);
            m = (o < m) ? o : m;
        }
        if (lane == 0) lw[wv] = m;
        __syncthreads();
        ull m01 = (lw[0] < lw[1]) ? lw[0] : lw[1];
        ull m23 = (lw[2] < lw[3]) ? lw[2] : lw[3];
        ull m4 = (m01 < m23) ? m01 : m23;
        int widx = (int)(unsigned int)m4;
        if (tid == 0) orow[sel] = widx;
        if ((widx & 255) == tid) k8[widx >> 8] = ~0ull;
        __syncthreads();
    }
}

// ---------------- fused attention: algebraic form (one elementwise pass per neighbor) ----------------
__global__ void attn_kernel(const void* __restrict__ pos,
                            const hb* __restrict__ qkvB, const int* __restrict__ idxb,
                            const void* __restrict__ cp,
                            const void* __restrict__ geo_s, const void* __restrict__ geo_b,
                            const void* __restrict__ a_sc, const void* __restrict__ f_sc,
                            hb* __restrict__ attnO, const int* __restrict__ fl) {
    const int fm = *fl;
    const int row = blockIdx.x;
    const int bb = row >> 11;
    const int tid = threadIdx.x, lane = tid & 63, wv = tid >> 6;
    __shared__ float sc_s[KNN_K];
    __shared__ int nid_s[KNN_K];
    if (tid < KNN_K) nid_s[tid] = idxb[row * KNN_K + tid];
    __syncthreads();
    const float c = ld_scalar(cp, fm);
    const float sc_c = sqrtf(fmaxf(c, 0.f));
    // per-row register fragments, d = lane + 64*t (each wave computes its own copy; L1-hot)
    float qpl[8], qgsl[8], ql[8];
    float x2 = 0.f, sqp = 0.f, qq = 0.f, qgs_sum = 0.f, qgb = 0.f;
    #pragma unroll
    for (int t = 0; t < 8; ++t) {
        const int d = lane + 64 * t;
        float qp = ldin(pos, (size_t)row * DDIM + d, fm);
        float q  = b2f(qkvB[(size_t)row * 1536 + d]);
        float gs = ldin(geo_s, d, fm);
        float gb = ldin(geo_b, d, fm);
        float qgs = q * gs;
        qpl[t] = qp; qgsl[t] = qgs; ql[t] = q;
        x2 += qp * qp; sqp += qp; qq += qgs * qp; qgs_sum += qgs; qgb += q * gb;
    }
    #pragma unroll
    for (int off = 32; off; off >>= 1) {
        x2 += __shfl_down(x2, off); sqp += __shfl_down(sqp, off);
        qq += __shfl_down(qq, off); qgs_sum += __shfl_down(qgs_sum, off);
        qgb += __shfl_down(qgb, off);
    }
    const float fscl = ld_scalar(f_sc, fm), ascl = ld_scalar(a_sc, fm);
    #pragma unroll
    for (int it = 0; it < 4; ++it) {
        const int kk = it * 4 + wv;
        const int j = nid_s[kk];
        const size_t nro = (size_t)(bb * NTOK + j) * DDIM;
        const size_t nro3 = (size_t)(bb * NTOK + j) * 1536 + 512;
        float xy = 0.f, y2 = 0.f, skp = 0.f, qk = 0.f, feat = 0.f;
        #pragma unroll
        for (int t = 0; t < 8; ++t) {
            const int d = lane + 64 * t;
            float kp = ldin(pos, nro + d, fm);
            float kv = b2f(qkvB[nro3 + d]);
            xy += qpl[t] * kp; y2 += kp * kp; skp += kp;
            qk += qgsl[t] * kp; feat += ql[t] * kv;
        }
        #pragma unroll
        for (int off = 32; off; off >>= 1) {
            xy += __shfl_down(xy, off); y2 += __shfl_down(y2, off);
            skp += __shfl_down(skp, off); qk += __shfl_down(qk, off);
            feat += __shfl_down(feat, off);
        }
        if (lane == 0) {
            const float xym = -xy;
            const float Af = 1.f + 2.f * c * xym + c * y2;
            const float Bf = 1.f - c * x2;
            float den = fmaxf(1.f + 2.f * c * xym + c * c * x2 * y2, 1e-8f);
            const float rden = 1.f / den;
            // n2 = ||mobius||^2 = rden^2 (Af^2 x2 - 2 Af Bf xy + Bf^2 y2)
            float n2 = fmaxf(Af * Af * x2 - 2.f * Af * Bf * xy + Bf * Bf * y2, 0.f) * rden * rden;
            const float ynorm = fmaxf(sqrtf(n2), 1e-8f);
            const float t_over = sc_c * ynorm;
            const float targ = fminf(t_over, 1.f - 1e-7f);
            const float scale = (targ > 0.f) ? (atanhf(targ) / t_over) : 1.f;
            const float S1 = scale * rden * (Bf * skp - Af * sqp);     // sum(g)
            const float mean = S1 * (1.f / DDIM);
            const float sq = scale * scale * n2;                        // sum(g^2)
            const float var = sq * (1.f / DDIM) - mean * mean;
            const float rstd = rsqrtf(fmaxf(var, 0.f) + 1e-6f);
            const float G = scale * rden * (Bf * qk - Af * qq);         // sum(q*gs*g)
            const float align = rstd * (G - mean * qgs_sum) + qgb;
            sc_s[kk] = fscl * feat + ascl * align;
        }
    }
    __syncthreads();
    float wgt[KNN_K];
    float mx = -1e30f;
    #pragma unroll
    for (int t = 0; t < KNN_K; ++t) mx = fmaxf(mx, sc_s[t]);
    float ssum = 0.f;
    #pragma unroll
    for (int t = 0; t < KNN_K; ++t) { float e = expf(sc_s[t] - mx); wgt[t] = e; ssum += e; }
    const float rs = 1.f / ssum;
    for (int d = tid; d < DDIM; d += 256) {
        float acc = 0.f;
        #pragma unroll
        for (int t = 0; t < KNN_K; ++t)
            acc += wgt[t] * b2f(qkvB[(size_t)(bb * NTOK + nid_s[t]) * 1536 + 1024 + d]);
        attnO[(size_t)row * DDIM + d] = __float2bfloat16(acc * rs);
    }
}

extern "C" void kernel_launch(void* const* d_in, const int* in_sizes, int n_in,
                              void* d_out, int out_size, void* d_ws, size_t ws_size,
                              hipStream_t stream) {
    const void* x    = d_in[0];
    const void* posb = d_in[1];
    const void* cb   = d_in[2];
    const void* Wq   = d_in[3];
    const void* bq   = d_in[4];
    const void* Wk   = d_in[5];
    const void* bk   = d_in[6];
    const void* Wv   = d_in[7];
    const void* bv   = d_in[8];
    const void* Wo   = d_in[9];
    const void* bo   = d_in[10];
    const void* W1   = d_in[11];
    const void* b1   = d_in[12];
    const void* W2   = d_in[13];
    const void* b2   = d_in[14];
    const void* ln1s = d_in[15];
    const void* ln1b = d_in[16];
    const void* ln2s = d_in[17];
    const void* ln2b = d_in[18];
    const void* geos = d_in[19];
    const void* geob = d_in[20];
    const void* asc  = d_in[21];
    const void* fsc  = d_in[22];

    float* wsf = (float*)d_ws;
    int* flag = (int*)wsf;
    size_t off = 16;
    hb* xnB   = (hb*)(wsf + off); off += 1048576;   // 4096x512 bf16; later hbuf (LN2 out)
    hb* qkvB  = (hb*)(wsf + off); off += 3145728;   // 4096x1536 bf16
    float* p2 = wsf + off;        off += 4096;
    int* idxb = (int*)(wsf + off); off += 65536;
    float* x1 = wsf + off;        off += 2097152;   // f32 4096x512
    float* argb = wsf + off;                         // NTOK^2 f32 (per batch)
    hb* hh    = (hb*)argb;        off += 4194304;   // later 4096x2048 bf16
    hb* ph    = (hb*)(wsf + off); off += 1048576;   // later attnO
    hb* pl    = (hb*)(wsf + off); off += 1048576;   // later W1T+W2T
    hb* WqkvT = (hb*)(wsf + off); off += 393216;    // 1536x512 bf16
    hb* WoT   = (hb*)(wsf + off); off += 131072;    // 512x512 bf16
    hb* attnO = ph;
    hb* W1T   = pl;                                  // 2048x512 bf16
    hb* W2T   = pl + 1048576;                        // 512x2048 bf16
    hb* hbuf  = xnB;

    // 0. dtype detection
    detect_kernel<<<1, 64, 0, stream>>>(x, flag);
    // weight transposes (N x K bf16)
    transpose_bf16<<<dim3(16, 16), 256, 0, stream>>>(Wq, WqkvT,              512, 512, flag);
    transpose_bf16<<<dim3(16, 16), 256, 0, stream>>>(Wk, WqkvT + 512 * 512,  512, 512, flag);
    transpose_bf16<<<dim3(16, 16), 256, 0, stream>>>(Wv, WqkvT + 1024 * 512, 512, 512, flag);
    transpose_bf16<<<dim3(16, 16), 256, 0, stream>>>(Wo, WoT,                512, 512, flag);
    // positions split + p2 (fused)
    possplit_p2<<<ROWS, 256, 0, stream>>>(posb, ph, pl, p2, flag);
    // 1. LN1 -> bf16
    ln_kernel<true><<<ROWS, 256, 0, stream>>>(x, ln1s, ln1b, xnB, flag);
    // 2. fused qkv GEMM
    gemm_bt<0><<<dim3(12, 32), 256, 0, stream>>>(xnB, WqkvT, bq, bk, bv, nullptr, qkvB,
                                                 1536, 512, 512, 512, 1536, flag);
    // 3. distances + top-16 per batch
    dist_mfma<<<dim3(16, 16), 256, 0, stream>>>(ph, pl, p2, cb, argb, 0, flag);
    topk_kernel<<<NTOK, 256, 0, stream>>>(argb, idxb, 0);
    dist_mfma<<<dim3(16, 16), 256, 0, stream>>>(ph, pl, p2, cb, argb, 1, flag);
    topk_kernel<<<NTOK, 256, 0, stream>>>(argb, idxb, 1);
    // FFN weight transposes (into pl region, dead after dist)
    transpose_bf16<<<dim3(64, 16), 256, 0, stream>>>(W1, W1T, 512, 2048, flag);
    transpose_bf16<<<dim3(16, 64), 256, 0, stream>>>(W2, W2T, 2048, 512, flag);
    // 5. fused geometric attention -> bf16 (overlays ph)
    attn_kernel<<<ROWS, 256, 0, stream>>>(posb, qkvB, idxb, cb, geos, geob, asc, fsc, attnO, flag);
    // 6. x1 = x + attn @ Wo + bo  (f32)
    gemm_bt<1><<<dim3(4, 32), 256, 0, stream>>>(attnO, WoT, bo, nullptr, nullptr, x, x1,
                                                512, 512, 512, 512, 512, flag);
    // 7. LN2 -> bf16
    ln_kernel<false><<<ROWS, 256, 0, stream>>>(x1, ln2s, ln2b, hbuf, flag);
    // 8. hh = gelu(h @ W1 + b1) -> bf16
    gemm_bt<2><<<dim3(16, 32), 256, 0, stream>>>(hbuf, W1T, b1, nullptr, nullptr, nullptr, hh,
                                                 2048, 512, 512, 512, 2048, flag);
    // 9. out = x1 + hh @ W2 + b2
    gemm_bt<3><<<dim3(4, 32), 256, 0, stream>>>(hh, W2T, b2, nullptr, nullptr, x1, d_out,
                                                512, 2048, 2048, 2048, 512, flag);

    (void)in_sizes; (void)n_in; (void)out_size; (void)ws_size;
}

// Round 6
// 405.838 us; speedup vs baseline: 2.5033x; 1.1277x over previous
//
#include <hip/hip_runtime.h>
#include <hip/hip_bf16.h>
#include <math.h>

#define NTOK 2048      // N
#define DDIM 512       // D
#define FDIM 2048      // F
#define KNN_K 16
#define ROWS 4096      // B*N

typedef __hip_bfloat16 hb;
typedef unsigned long long ull;
typedef short s8v __attribute__((ext_vector_type(8)));
typedef float f4v __attribute__((ext_vector_type(4)));

__device__ __forceinline__ float b2f(hb h) { return __bfloat162float(h); }

__device__ __forceinline__ float ldin(const void* p, size_t i, int f32m) {
    return f32m ? ((const float*)p)[i] : b2f(((const hb*)p)[i]);
}
__device__ __forceinline__ float ld_scalar(const void* p, int f32m) {
    return f32m ? *(const float*)p : b2f(*(const hb*)p);
}

__device__ __forceinline__ ull shfl_down_u64(ull x, int off) {
    unsigned lo = (unsigned)x, hi = (unsigned)(x >> 32);
    lo = __shfl_down(lo, off); hi = __shfl_down(hi, off);
    return ((ull)hi << 32) | lo;
}

__device__ __forceinline__ float gelu_f(float x) {
    float x3 = x * x * x;
    return 0.5f * x * (1.f + tanhf(0.7978845608028654f * (x + 0.044715f * x3)));
}

// ---------------- dtype detector ----------------
__global__ void detect_kernel(const void* __restrict__ x, int* __restrict__ flag) {
    const unsigned short* u = (const unsigned short*)x;
    int tid = threadIdx.x;
    int bad = 0;
    #pragma unroll
    for (int t = 0; t < 16; ++t) {
        unsigned short h = u[tid * 16 + t];
        int e = (h >> 7) & 0xFF;
        if (e == 0xFF) bad++;
        else if (e >= 0x8E) bad++;
        else if (e != 0 && e <= 0x66) bad++;
    }
    #pragma unroll
    for (int off = 32; off; off >>= 1) bad += __shfl_down(bad, off);
    if (tid == 0) *flag = (bad > 100) ? 1 : 0;
}

// ---------------- transpose external [K][N] -> bf16 [N][K] ----------------
__global__ void transpose_bf16(const void* __restrict__ src, hb* __restrict__ dst,
                               int K, int N, const int* __restrict__ fl) {
    const int fm = *fl;
    __shared__ float t[32][33];
    const int k0 = blockIdx.y * 32, n0 = blockIdx.x * 32;
    const int tx = threadIdx.x & 31, ty = threadIdx.x >> 5;   // 32 x 8
    #pragma unroll
    for (int r = 0; r < 32; r += 8)
        t[ty + r][tx] = ldin(src, (size_t)(k0 + ty + r) * N + n0 + tx, fm);
    __syncthreads();
    #pragma unroll
    for (int r = 0; r < 32; r += 8)
        dst[(size_t)(n0 + ty + r) * K + k0 + tx] = __float2bfloat16(t[tx][ty + r]);
}

// ---------------- positions hi/lo split + p2 (fused) ----------------
__global__ void possplit_p2(const void* __restrict__ pos, hb* __restrict__ ph,
                            hb* __restrict__ pl, float* __restrict__ p2,
                            const int* __restrict__ fl) {
    const int fm = *fl;
    const int row = blockIdx.x, tid = threadIdx.x;
    float s = 0.f;
    #pragma unroll
    for (int t = 0; t < 2; ++t) {
        size_t i = (size_t)row * DDIM + tid + 256 * t;
        float v = ldin(pos, i, fm);
        hb h = __float2bfloat16(v);
        ph[i] = h;
        pl[i] = __float2bfloat16(v - b2f(h));
        s += v * v;
    }
    const int lane = tid & 63, wv = tid >> 6;
    #pragma unroll
    for (int off = 32; off; off >>= 1) s += __shfl_down(s, off);
    __shared__ float ls[4];
    if (lane == 0) ls[wv] = s;
    __syncthreads();
    if (tid == 0) p2[row] = ls[0] + ls[1] + ls[2] + ls[3];
}

// ---------------- LayerNorm: out bf16 ----------------
template<bool EXT>
__global__ void ln_kernel(const void* __restrict__ xin,
                          const void* __restrict__ s, const void* __restrict__ b,
                          hb* __restrict__ y, const int* __restrict__ fl) {
    const int m = *fl;
    const int row = blockIdx.x, tid = threadIdx.x;
    float v0, v1;
    if (EXT) {
        v0 = ldin(xin, (size_t)row * DDIM + tid, m);
        v1 = ldin(xin, (size_t)row * DDIM + tid + 256, m);
    } else {
        const float* xp = (const float*)xin + (size_t)row * DDIM;
        v0 = xp[tid]; v1 = xp[tid + 256];
    }
    float sum = v0 + v1, sq = v0 * v0 + v1 * v1;
    const int lane = tid & 63, wv = tid >> 6;
    #pragma unroll
    for (int off = 32; off; off >>= 1) { sum += __shfl_down(sum, off); sq += __shfl_down(sq, off); }
    __shared__ float ls[8];
    if (lane == 0) { ls[wv] = sum; ls[4 + wv] = sq; }
    __syncthreads();
    float ts = ls[0] + ls[1] + ls[2] + ls[3];
    float tq = ls[4] + ls[5] + ls[6] + ls[7];
    float mean = ts * (1.f / DDIM);
    float var = tq * (1.f / DDIM) - mean * mean;
    float rstd = rsqrtf(var + 1e-6f);
    y[(size_t)row * DDIM + tid]       = __float2bfloat16(ldin(s, tid, m) * (v0 - mean) * rstd + ldin(b, tid, m));
    y[(size_t)row * DDIM + tid + 256] = __float2bfloat16(ldin(s, tid + 256, m) * (v1 - mean) * rstd + ldin(b, tid + 256, m));
}

// ================ pipelined MFMA GEMM: C[M][N] = A[M][K](bf16) @ Bt[N][K]^T ================
// TM=128 fixed. TN in {128, 64}. BK=64, register-prefetch software pipeline.
// EPI: 0 = qkv ; 1 = Wo(+res ext, out f32) ; 2 = W1 gelu ; 3 = W2(+res f32, out flagged)
template<int EPI, int TN, int BK>
__global__ __launch_bounds__(256, 2)
void gemm_bt(const hb* __restrict__ A, const hb* __restrict__ Bt,
             const void* __restrict__ bp0, const void* __restrict__ bp1, const void* __restrict__ bp2,
             const void* __restrict__ res, void* __restrict__ C,
             int N, int K, int lda, int ldb, int ldc,
             const int* __restrict__ fl) {
    constexpr int WY = (TN == 128) ? 2 : 4;
    constexpr int WX = (TN == 128) ? 2 : 1;
    constexpr int FI = 128 / WY / 16;            // 4 or 2
    constexpr int FJ = TN / WX / 16;             // 4
    constexpr int NA = 128 * BK / (256 * 8);     // 4
    constexpr int NB = TN * BK / (256 * 8);      // 4 or 2
    constexpr int LDSW = BK + 8;
    const int fm = *fl;
    __shared__ short As[128 * LDSW];
    __shared__ short Bs[TN * LDSW];
    const int tid = threadIdx.x, lane = tid & 63, wave = tid >> 6;
    const int wy = (TN == 128) ? (wave >> 1) : wave;
    const int wx = (TN == 128) ? (wave & 1) : 0;
    const int m0 = blockIdx.y * 128, n0 = blockIdx.x * TN;
    const int r0 = tid >> 3, c0 = (tid & 7) * 8;
    const int lm = lane & 15, lk = (lane >> 4) * 8;
    f4v acc[FI][FJ];
    #pragma unroll
    for (int i = 0; i < FI; ++i)
        #pragma unroll
        for (int j = 0; j < FJ; ++j) acc[i][j] = (f4v){0.f, 0.f, 0.f, 0.f};

    s8v an[NA], bn[NB];
    #pragma unroll
    for (int g = 0; g < NA; ++g) an[g] = *(const s8v*)(A + (size_t)(m0 + r0 + 32 * g) * lda + c0);
    #pragma unroll
    for (int g = 0; g < NB; ++g) bn[g] = *(const s8v*)(Bt + (size_t)(n0 + r0 + 32 * g) * ldb + c0);

    for (int k0 = 0; k0 < K; k0 += BK) {
        __syncthreads();
        #pragma unroll
        for (int g = 0; g < NA; ++g) *(s8v*)(As + (r0 + 32 * g) * LDSW + c0) = an[g];
        #pragma unroll
        for (int g = 0; g < NB; ++g) *(s8v*)(Bs + (r0 + 32 * g) * LDSW + c0) = bn[g];
        if (k0 + BK < K) {
            const int kn = k0 + BK;
            #pragma unroll
            for (int g = 0; g < NA; ++g) an[g] = *(const s8v*)(A + (size_t)(m0 + r0 + 32 * g) * lda + kn + c0);
            #pragma unroll
            for (int g = 0; g < NB; ++g) bn[g] = *(const s8v*)(Bt + (size_t)(n0 + r0 + 32 * g) * ldb + kn + c0);
        }
        __syncthreads();
        #pragma unroll
        for (int kc = 0; kc < BK; kc += 32) {
            s8v af[FI], bf[FJ];
            #pragma unroll
            for (int f = 0; f < FI; ++f)
                af[f] = *(const s8v*)(As + (wy * (128 / WY) + f * 16 + lm) * LDSW + kc + lk);
            #pragma unroll
            for (int f = 0; f < FJ; ++f)
                bf[f] = *(const s8v*)(Bs + (wx * (TN / WX) + f * 16 + lm) * LDSW + kc + lk);
            #pragma unroll
            for (int fi = 0; fi < FI; ++fi)
                #pragma unroll
                for (int fj = 0; fj < FJ; ++fj)
                    acc[fi][fj] = __builtin_amdgcn_mfma_f32_16x16x32_bf16(af[fi], bf[fj], acc[fi][fj], 0, 0, 0);
        }
    }

    const int embase = m0 + wy * (128 / WY) + (lane >> 4) * 4;
    const int enbase = n0 + wx * (TN / WX) + lm;
    #pragma unroll
    for (int fi = 0; fi < FI; ++fi) {
        #pragma unroll
        for (int fj = 0; fj < FJ; ++fj) {
            const int n = enbase + fj * 16;
            #pragma unroll
            for (int r = 0; r < 4; ++r) {
                const int m = embase + fi * 16 + r;
                float val = acc[fi][fj][r];
                size_t ci = (size_t)m * ldc + n;
                if (EPI == 0) {
                    const void* bp = (n < 512) ? bp0 : ((n < 1024) ? bp1 : bp2);
                    val += ldin(bp, n & 511, fm);
                    ((hb*)C)[ci] = __float2bfloat16(val);
                } else if (EPI == 1) {
                    val += ldin(bp0, n, fm) + ldin(res, (size_t)m * 512 + n, fm);
                    ((float*)C)[ci] = val;
                } else if (EPI == 2) {
                    val = gelu_f(val + ldin(bp0, n, fm));
                    ((hb*)C)[ci] = __float2bfloat16(val);
                } else {
                    val += ldin(bp0, n, fm) + ((const float*)res)[(size_t)m * 512 + n];
                    if (fm) ((float*)C)[ci] = val;
                    else ((hb*)C)[ci] = __float2bfloat16(val);
                }
            }
        }
    }
}

// ================ pipelined dist MFMA: per-batch hyperbolic arg, split hi/lo (3 passes) ================
__global__ __launch_bounds__(256, 2)
void dist_mfma(const hb* __restrict__ ph, const hb* __restrict__ pl,
               const float* __restrict__ p2, const void* __restrict__ cp,
               float* __restrict__ out, int bb, const int* __restrict__ fl) {
    constexpr int BK = 64, LDSW = BK + 8;
    constexpr int KI = DDIM / BK;           // 8 iters per pass
    const int fm = *fl;
    const float c = ld_scalar(cp, fm);
    const float* p2b = p2 + bb * NTOK;
    const size_t rb = (size_t)bb * NTOK;
    __shared__ short As[128 * LDSW];
    __shared__ short Bs[128 * LDSW];
    const int tid = threadIdx.x, lane = tid & 63, wave = tid >> 6;
    const int wy = wave >> 1, wx = wave & 1;
    const int i0 = blockIdx.y * 128, j0 = blockIdx.x * 128;
    const int r0 = tid >> 3, c0 = (tid & 7) * 8;
    const int lm = lane & 15, lk = (lane >> 4) * 8;
    f4v acc[4][4];
    #pragma unroll
    for (int i = 0; i < 4; ++i)
        #pragma unroll
        for (int j = 0; j < 4; ++j) acc[i][j] = (f4v){0.f, 0.f, 0.f, 0.f};

    const hb* Ap[3] = {ph, ph, pl};
    const hb* Bp[3] = {ph, pl, ph};
    s8v an[4], bn[4];
    {
        const hb* Asrc = Ap[0]; const hb* Bsrc = Bp[0];
        #pragma unroll
        for (int g = 0; g < 4; ++g) {
            an[g] = *(const s8v*)(Asrc + (rb + i0 + r0 + 32 * g) * DDIM + c0);
            bn[g] = *(const s8v*)(Bsrc + (rb + j0 + r0 + 32 * g) * DDIM + c0);
        }
    }
    for (int it = 0; it < 3 * KI; ++it) {
        __syncthreads();
        #pragma unroll
        for (int g = 0; g < 4; ++g) {
            *(s8v*)(As + (r0 + 32 * g) * LDSW + c0) = an[g];
            *(s8v*)(Bs + (r0 + 32 * g) * LDSW + c0) = bn[g];
        }
        if (it + 1 < 3 * KI) {
            const int p = (it + 1) / KI, kn = ((it + 1) % KI) * BK;
            const hb* Asrc = Ap[p]; const hb* Bsrc = Bp[p];
            #pragma unroll
            for (int g = 0; g < 4; ++g) {
                an[g] = *(const s8v*)(Asrc + (rb + i0 + r0 + 32 * g) * DDIM + kn + c0);
                bn[g] = *(const s8v*)(Bsrc + (rb + j0 + r0 + 32 * g) * DDIM + kn + c0);
            }
        }
        __syncthreads();
        #pragma unroll
        for (int kc = 0; kc < BK; kc += 32) {
            s8v af[4], bf[4];
            #pragma unroll
            for (int f = 0; f < 4; ++f) {
                af[f] = *(const s8v*)(As + (wy * 64 + f * 16 + lm) * LDSW + kc + lk);
                bf[f] = *(const s8v*)(Bs + (wx * 64 + f * 16 + lm) * LDSW + kc + lk);
            }
            #pragma unroll
            for (int fi = 0; fi < 4; ++fi)
                #pragma unroll
                for (int fj = 0; fj < 4; ++fj)
                    acc[fi][fj] = __builtin_amdgcn_mfma_f32_16x16x32_bf16(af[fi], bf[fj], acc[fi][fj], 0, 0, 0);
        }
    }

    const int eibase = i0 + wy * 64 + (lane >> 4) * 4;
    const int ejbase = j0 + wx * 64 + lm;
    #pragma unroll
    for (int fi = 0; fi < 4; ++fi) {
        #pragma unroll
        for (int fj = 0; fj < 4; ++fj) {
            const int jj = ejbase + fj * 16;
            const float p2j = p2b[jj];
            #pragma unroll
            for (int r = 0; r < 4; ++r) {
                const int ii = eibase + fi * 16 + r;
                const float p2i = p2b[ii];
                float diff = fmaxf(p2i + p2j - 2.f * acc[fi][fj][r], 0.f);
                float den = fmaxf((1.f - c * p2i) * (1.f - c * p2j), 1e-8f);
                out[(size_t)ii * NTOK + jj] = 1.f + 2.f * c * diff / den;
            }
        }
    }
}

// ---------------- top-16 smallest per row: register-resident, packed u64 keys ----------------
__global__ void topk_kernel(const float* __restrict__ argb, int* __restrict__ idxb, int bb) {
    const int r = blockIdx.x;
    const float* arow = argb + (size_t)r * NTOK;
    int* orow = idxb + ((size_t)bb * NTOK + r) * KNN_K;
    const int tid = threadIdx.x, lane = tid & 63, wv = tid >> 6;
    ull k8[8];
    #pragma unroll
    for (int i = 0; i < 8; ++i) {
        int idx = i * 256 + tid;
        unsigned int bbits = __float_as_uint(arow[idx]);
        k8[i] = ((ull)bbits << 32) | (unsigned int)idx;
    }
    __shared__ ull lw[4];
    for (int sel = 0; sel < KNN_K; ++sel) {
        ull m = k8[0];
        #pragma unroll
        for (int i = 1; i < 8; ++i) m = (k8[i] < m) ? k8[i] : m;
        #pragma unroll
        for (int off = 32; off; off >>= 1) {
            ull o = shfl_down_u64(m, off);
            m = (o < m) ? o : m;
        }
        if (lane == 0) lw[wv] = m;
        __syncthreads();
        ull m01 = (lw[0] < lw[1]) ? lw[0] : lw[1];
        ull m23 = (lw[2] < lw[3]) ? lw[2] : lw[3];
        ull m4 = (m01 < m23) ? m01 : m23;
        int widx = (int)(unsigned int)m4;
        if (tid == 0) orow[sel] = widx;
        if ((widx & 255) == tid) k8[widx >> 8] = ~0ull;
        __syncthreads();
    }
}

// ---------------- fused attention: algebraic form ----------------
__global__ void attn_kernel(const void* __restrict__ pos,
                            const hb* __restrict__ qkvB, const int* __restrict__ idxb,
                            const void* __restrict__ cp,
                            const void* __restrict__ geo_s, const void* __restrict__ geo_b,
                            const void* __restrict__ a_sc, const void* __restrict__ f_sc,
                            hb* __restrict__ attnO, const int* __restrict__ fl) {
    const int fm = *fl;
    const int row = blockIdx.x;
    const int bb = row >> 11;
    const int tid = threadIdx.x, lane = tid & 63, wv = tid >> 6;
    __shared__ float sc_s[KNN_K];
    __shared__ int nid_s[KNN_K];
    if (tid < KNN_K) nid_s[tid] = idxb[row * KNN_K + tid];
    __syncthreads();
    const float c = ld_scalar(cp, fm);
    const float sc_c = sqrtf(fmaxf(c, 0.f));
    float qpl[8], qgsl[8], ql[8];
    float x2 = 0.f, sqp = 0.f, qq = 0.f, qgs_sum = 0.f, qgb = 0.f;
    #pragma unroll
    for (int t = 0; t < 8; ++t) {
        const int d = lane + 64 * t;
        float qp = ldin(pos, (size_t)row * DDIM + d, fm);
        float q  = b2f(qkvB[(size_t)row * 1536 + d]);
        float gs = ldin(geo_s, d, fm);
        float gb = ldin(geo_b, d, fm);
        float qgs = q * gs;
        qpl[t] = qp; qgsl[t] = qgs; ql[t] = q;
        x2 += qp * qp; sqp += qp; qq += qgs * qp; qgs_sum += qgs; qgb += q * gb;
    }
    #pragma unroll
    for (int off = 32; off; off >>= 1) {
        x2 += __shfl_down(x2, off); sqp += __shfl_down(sqp, off);
        qq += __shfl_down(qq, off); qgs_sum += __shfl_down(qgs_sum, off);
        qgb += __shfl_down(qgb, off);
    }
    const float fscl = ld_scalar(f_sc, fm), ascl = ld_scalar(a_sc, fm);
    #pragma unroll
    for (int it = 0; it < 4; ++it) {
        const int kk = it * 4 + wv;
        const int j = nid_s[kk];
        const size_t nro = (size_t)(bb * NTOK + j) * DDIM;
        const size_t nro3 = (size_t)(bb * NTOK + j) * 1536 + 512;
        float xy = 0.f, y2 = 0.f, skp = 0.f, qk = 0.f, feat = 0.f;
        #pragma unroll
        for (int t = 0; t < 8; ++t) {
            const int d = lane + 64 * t;
            float kp = ldin(pos, nro + d, fm);
            float kv = b2f(qkvB[nro3 + d]);
            xy += qpl[t] * kp; y2 += kp * kp; skp += kp;
            qk += qgsl[t] * kp; feat += ql[t] * kv;
        }
        #pragma unroll
        for (int off = 32; off; off >>= 1) {
            xy += __shfl_down(xy, off); y2 += __shfl_down(y2, off);
            skp += __shfl_down(skp, off); qk += __shfl_down(qk, off);
            feat += __shfl_down(feat, off);
        }
        if (lane == 0) {
            const float xym = -xy;
            const float Af = 1.f + 2.f * c * xym + c * y2;
            const float Bf = 1.f - c * x2;
            float den = fmaxf(1.f + 2.f * c * xym + c * c * x2 * y2, 1e-8f);
            const float rden = 1.f / den;
            float n2 = fmaxf(Af * Af * x2 - 2.f * Af * Bf * xy + Bf * Bf * y2, 0.f) * rden * rden;
            const float ynorm = fmaxf(sqrtf(n2), 1e-8f);
            const float t_over = sc_c * ynorm;
            const float targ = fminf(t_over, 1.f - 1e-7f);
            const float scale = (targ > 0.f) ? (atanhf(targ) / t_over) : 1.f;
            const float S1 = scale * rden * (Bf * skp - Af * sqp);
            const float mean = S1 * (1.f / DDIM);
            const float sq = scale * scale * n2;
            const float var = sq * (1.f / DDIM) - mean * mean;
            const float rstd = rsqrtf(fmaxf(var, 0.f) + 1e-6f);
            const float G = scale * rden * (Bf * qk - Af * qq);
            const float align = rstd * (G - mean * qgs_sum) + qgb;
            sc_s[kk] = fscl * feat + ascl * align;
        }
    }
    __syncthreads();
    float wgt[KNN_K];
    float mx = -1e30f;
    #pragma unroll
    for (int t = 0; t < KNN_K; ++t) mx = fmaxf(mx, sc_s[t]);
    float ssum = 0.f;
    #pragma unroll
    for (int t = 0; t < KNN_K; ++t) { float e = expf(sc_s[t] - mx); wgt[t] = e; ssum += e; }
    const float rs = 1.f / ssum;
    for (int d = tid; d < DDIM; d += 256) {
        float acc = 0.f;
        #pragma unroll
        for (int t = 0; t < KNN_K; ++t)
            acc += wgt[t] * b2f(qkvB[(size_t)(bb * NTOK + nid_s[t]) * 1536 + 1024 + d]);
        attnO[(size_t)row * DDIM + d] = __float2bfloat16(acc * rs);
    }
}

extern "C" void kernel_launch(void* const* d_in, const int* in_sizes, int n_in,
                              void* d_out, int out_size, void* d_ws, size_t ws_size,
                              hipStream_t stream) {
    const void* x    = d_in[0];
    const void* posb = d_in[1];
    const void* cb   = d_in[2];
    const void* Wq   = d_in[3];
    const void* bq   = d_in[4];
    const void* Wk   = d_in[5];
    const void* bk   = d_in[6];
    const void* Wv   = d_in[7];
    const void* bv   = d_in[8];
    const void* Wo   = d_in[9];
    const void* bo   = d_in[10];
    const void* W1   = d_in[11];
    const void* b1   = d_in[12];
    const void* W2   = d_in[13];
    const void* b2   = d_in[14];
    const void* ln1s = d_in[15];
    const void* ln1b = d_in[16];
    const void* ln2s = d_in[17];
    const void* ln2b = d_in[18];
    const void* geos = d_in[19];
    const void* geob = d_in[20];
    const void* asc  = d_in[21];
    const void* fsc  = d_in[22];

    float* wsf = (float*)d_ws;
    int* flag = (int*)wsf;
    size_t off = 16;
    hb* xnB   = (hb*)(wsf + off); off += 1048576;   // 4096x512 bf16; later hbuf (LN2 out)
    hb* qkvB  = (hb*)(wsf + off); off += 3145728;   // 4096x1536 bf16
    float* p2 = wsf + off;        off += 4096;
    int* idxb = (int*)(wsf + off); off += 65536;
    float* x1 = wsf + off;        off += 2097152;   // f32 4096x512
    float* argb = wsf + off;                         // NTOK^2 f32 (per batch)
    hb* hh    = (hb*)argb;        off += 4194304;   // later 4096x2048 bf16
    hb* ph    = (hb*)(wsf + off); off += 1048576;   // later attnO
    hb* pl    = (hb*)(wsf + off); off += 1048576;   // later W1T+W2T
    hb* WqkvT = (hb*)(wsf + off); off += 393216;    // 1536x512 bf16
    hb* WoT   = (hb*)(wsf + off); off += 131072;    // 512x512 bf16
    hb* attnO = ph;
    hb* W1T   = pl;                                  // 2048x512 bf16
    hb* W2T   = pl + 1048576;                        // 512x2048 bf16
    hb* hbuf  = xnB;

    // 0. dtype detection
    detect_kernel<<<1, 64, 0, stream>>>(x, flag);
    // weight transposes (N x K bf16)
    transpose_bf16<<<dim3(16, 16), 256, 0, stream>>>(Wq, WqkvT,              512, 512, flag);
    transpose_bf16<<<dim3(16, 16), 256, 0, stream>>>(Wk, WqkvT + 512 * 512,  512, 512, flag);
    transpose_bf16<<<dim3(16, 16), 256, 0, stream>>>(Wv, WqkvT + 1024 * 512, 512, 512, flag);
    transpose_bf16<<<dim3(16, 16), 256, 0, stream>>>(Wo, WoT,                512, 512, flag);
    // positions split + p2
    possplit_p2<<<ROWS, 256, 0, stream>>>(posb, ph, pl, p2, flag);
    // 1. LN1 -> bf16
    ln_kernel<true><<<ROWS, 256, 0, stream>>>(x, ln1s, ln1b, xnB, flag);
    // 2. fused qkv GEMM
    gemm_bt<0, 128, 64><<<dim3(12, 32), 256, 0, stream>>>(xnB, WqkvT, bq, bk, bv, nullptr, qkvB,
                                                          1536, 512, 512, 512, 1536, flag);
    // 3. distances + top-16 per batch
    dist_mfma<<<dim3(16, 16), 256, 0, stream>>>(ph, pl, p2, cb, argb, 0, flag);
    topk_kernel<<<NTOK, 256, 0, stream>>>(argb, idxb, 0);
    dist_mfma<<<dim3(16, 16), 256, 0, stream>>>(ph, pl, p2, cb, argb, 1, flag);
    topk_kernel<<<NTOK, 256, 0, stream>>>(argb, idxb, 1);
    // FFN weight transposes (into pl region, dead after dist)
    transpose_bf16<<<dim3(64, 16), 256, 0, stream>>>(W1, W1T, 512, 2048, flag);
    transpose_bf16<<<dim3(16, 64), 256, 0, stream>>>(W2, W2T, 2048, 512, flag);
    // 5. fused geometric attention -> bf16 (overlays ph)
    attn_kernel<<<ROWS, 256, 0, stream>>>(posb, qkvB, idxb, cb, geos, geob, asc, fsc, attnO, flag);
    // 6. x1 = x + attn @ Wo + bo  (f32) — TN=64 tiles: 256 blocks
    gemm_bt<1, 64, 64><<<dim3(8, 32), 256, 0, stream>>>(attnO, WoT, bo, nullptr, nullptr, x, x1,
                                                        512, 512, 512, 512, 512, flag);
    // 7. LN2 -> bf16
    ln_kernel<false><<<ROWS, 256, 0, stream>>>(x1, ln2s, ln2b, hbuf, flag);
    // 8. hh = gelu(h @ W1 + b1) -> bf16
    gemm_bt<2, 128, 64><<<dim3(16, 32), 256, 0, stream>>>(hbuf, W1T, b1, nullptr, nullptr, nullptr, hh,
                                                          2048, 512, 512, 512, 2048, flag);
    // 9. out = x1 + hh @ W2 + b2 — TN=64 tiles: 256 blocks
    gemm_bt<3, 64, 64><<<dim3(8, 32), 256, 0, stream>>>(hh, W2T, b2, nullptr, nullptr, x1, d_out,
                                                        512, 2048, 2048, 2048, 512, flag);

    (void)in_sizes; (void)n_in; (void)out_size; (void)ws_size;
}

// Round 8
// 375.031 us; speedup vs baseline: 2.7089x; 1.0821x over previous
//
#include <hip/hip_runtime.h>
#include <hip/hip_bf16.h>
#include <math.h>

#define NTOK 2048      // N
#define DDIM 512       // D
#define FDIM 2048      // F
#define KNN_K 16
#define ROWS 4096      // B*N

typedef __hip_bfloat16 hb;
typedef unsigned long long ull;
typedef short s8v __attribute__((ext_vector_type(8)));
typedef short s4v __attribute__((ext_vector_type(4)));
typedef float f4v __attribute__((ext_vector_type(4)));

__device__ __forceinline__ float b2f(hb h) { return __bfloat162float(h); }
// bf16 stored as raw short bits -> f32 (bf16 is the top 16 bits of f32)
__device__ __forceinline__ float bits2f(short s) {
    return __uint_as_float(((unsigned int)(unsigned short)s) << 16);
}

__device__ __forceinline__ float ldin(const void* p, size_t i, int f32m) {
    return f32m ? ((const float*)p)[i] : b2f(((const hb*)p)[i]);
}
__device__ __forceinline__ float ld_scalar(const void* p, int f32m) {
    return f32m ? *(const float*)p : b2f(*(const hb*)p);
}

__device__ __forceinline__ ull shfl_down_u64(ull x, int off) {
    unsigned lo = (unsigned)x, hi = (unsigned)(x >> 32);
    lo = __shfl_down(lo, off); hi = __shfl_down(hi, off);
    return ((ull)hi << 32) | lo;
}

__device__ __forceinline__ float gelu_f(float x) {
    float x3 = x * x * x;
    return 0.5f * x * (1.f + tanhf(0.7978845608028654f * (x + 0.044715f * x3)));
}

// ---------------- dtype detector ----------------
__global__ void detect_kernel(const void* __restrict__ x, int* __restrict__ flag) {
    const unsigned short* u = (const unsigned short*)x;
    int tid = threadIdx.x;
    int bad = 0;
    #pragma unroll
    for (int t = 0; t < 16; ++t) {
        unsigned short h = u[tid * 16 + t];
        int e = (h >> 7) & 0xFF;
        if (e == 0xFF) bad++;
        else if (e >= 0x8E) bad++;
        else if (e != 0 && e <= 0x66) bad++;
    }
    #pragma unroll
    for (int off = 32; off; off >>= 1) bad += __shfl_down(bad, off);
    if (tid == 0) *flag = (bad > 100) ? 1 : 0;
}

// ---------------- transpose tile body ----------------
__device__ __forceinline__ void tr_tile(const void* src, hb* dst, int K, int N,
                                        int k0, int n0, int fm) {
    __shared__ float t[32][33];
    const int tx = threadIdx.x & 31, ty = threadIdx.x >> 5;   // 32 x 8
    #pragma unroll
    for (int r = 0; r < 32; r += 8)
        t[ty + r][tx] = ldin(src, (size_t)(k0 + ty + r) * N + n0 + tx, fm);
    __syncthreads();
    #pragma unroll
    for (int r = 0; r < 32; r += 8)
        dst[(size_t)(n0 + ty + r) * K + k0 + tx] = __float2bfloat16(t[tx][ty + r]);
}

// merged transpose A: Wq, Wk, Wv (into WqkvT) + Wo (into WoT); all 512x512
__global__ void transposeA(const void* __restrict__ Wq, const void* __restrict__ Wk,
                           const void* __restrict__ Wv, const void* __restrict__ Wo,
                           hb* __restrict__ WqkvT, hb* __restrict__ WoT,
                           const int* __restrict__ fl) {
    const int fm = *fl;
    const int bx = blockIdx.x;              // 0..1023
    const int seg = bx >> 8, t = bx & 255;
    const int n0 = (t & 15) * 32, k0 = (t >> 4) * 32;
    const void* src = (seg == 0) ? Wq : (seg == 1) ? Wk : (seg == 2) ? Wv : Wo;
    hb* dst = (seg == 3) ? WoT : (WqkvT + (size_t)seg * 512 * 512);
    tr_tile(src, dst, 512, 512, k0, n0, fm);
}

// merged transpose B: W1 (512x2048 -> W1T) + W2 (2048x512 -> W2T)
__global__ void transposeB(const void* __restrict__ W1, const void* __restrict__ W2,
                           hb* __restrict__ W1T, hb* __restrict__ W2T,
                           const int* __restrict__ fl) {
    const int fm = *fl;
    const int bx = blockIdx.x;              // 0..2047
    if (bx < 1024) {
        const int n0 = (bx & 63) * 32, k0 = (bx >> 6) * 32;
        tr_tile(W1, W1T, 512, 2048, k0, n0, fm);
    } else {
        const int b2 = bx - 1024;
        const int n0 = (b2 & 15) * 32, k0 = (b2 >> 4) * 32;
        tr_tile(W2, W2T, 2048, 512, k0, n0, fm);
    }
}

// ---------------- positions hi/lo split + p2 + spos (fused) ----------------
__global__ void possplit_p2(const void* __restrict__ pos, hb* __restrict__ ph,
                            hb* __restrict__ pl, float* __restrict__ p2,
                            float* __restrict__ spos, const int* __restrict__ fl) {
    const int fm = *fl;
    const int row = blockIdx.x, tid = threadIdx.x;
    float s = 0.f, s1 = 0.f;
    #pragma unroll
    for (int t = 0; t < 2; ++t) {
        size_t i = (size_t)row * DDIM + tid + 256 * t;
        float v = ldin(pos, i, fm);
        hb h = __float2bfloat16(v);
        ph[i] = h;
        pl[i] = __float2bfloat16(v - b2f(h));
        s += v * v; s1 += v;
    }
    const int lane = tid & 63, wv = tid >> 6;
    #pragma unroll
    for (int off = 32; off; off >>= 1) { s += __shfl_down(s, off); s1 += __shfl_down(s1, off); }
    __shared__ float ls[8];
    if (lane == 0) { ls[wv] = s; ls[4 + wv] = s1; }
    __syncthreads();
    if (tid == 0) {
        p2[row]   = ls[0] + ls[1] + ls[2] + ls[3];
        spos[row] = ls[4] + ls[5] + ls[6] + ls[7];
    }
}

// ---------------- LayerNorm: out bf16 ----------------
template<bool EXT>
__global__ void ln_kernel(const void* __restrict__ xin,
                          const void* __restrict__ s, const void* __restrict__ b,
                          hb* __restrict__ y, const int* __restrict__ fl) {
    const int m = *fl;
    const int row = blockIdx.x, tid = threadIdx.x;
    float v0, v1;
    if (EXT) {
        v0 = ldin(xin, (size_t)row * DDIM + tid, m);
        v1 = ldin(xin, (size_t)row * DDIM + tid + 256, m);
    } else {
        const float* xp = (const float*)xin + (size_t)row * DDIM;
        v0 = xp[tid]; v1 = xp[tid + 256];
    }
    float sum = v0 + v1, sq = v0 * v0 + v1 * v1;
    const int lane = tid & 63, wv = tid >> 6;
    #pragma unroll
    for (int off = 32; off; off >>= 1) { sum += __shfl_down(sum, off); sq += __shfl_down(sq, off); }
    __shared__ float ls[8];
    if (lane == 0) { ls[wv] = sum; ls[4 + wv] = sq; }
    __syncthreads();
    float ts = ls[0] + ls[1] + ls[2] + ls[3];
    float tq = ls[4] + ls[5] + ls[6] + ls[7];
    float mean = ts * (1.f / DDIM);
    float var = tq * (1.f / DDIM) - mean * mean;
    float rstd = rsqrtf(var + 1e-6f);
    y[(size_t)row * DDIM + tid]       = __float2bfloat16(ldin(s, tid, m) * (v0 - mean) * rstd + ldin(b, tid, m));
    y[(size_t)row * DDIM + tid + 256] = __float2bfloat16(ldin(s, tid + 256, m) * (v1 - mean) * rstd + ldin(b, tid + 256, m));
}

// ================ pipelined MFMA GEMM ================
template<int EPI, int TN, int BK>
__global__ __launch_bounds__(256, 2)
void gemm_bt(const hb* __restrict__ A, const hb* __restrict__ Bt,
             const void* __restrict__ bp0, const void* __restrict__ bp1, const void* __restrict__ bp2,
             const void* __restrict__ res, void* __restrict__ C,
             int N, int K, int lda, int ldb, int ldc,
             const int* __restrict__ fl) {
    constexpr int WY = (TN == 128) ? 2 : 4;
    constexpr int WX = (TN == 128) ? 2 : 1;
    constexpr int FI = 128 / WY / 16;
    constexpr int FJ = TN / WX / 16;
    constexpr int NA = 128 * BK / (256 * 8);
    constexpr int NB = TN * BK / (256 * 8);
    constexpr int LDSW = BK + 8;
    const int fm = *fl;
    __shared__ short As[128 * LDSW];
    __shared__ short Bs[TN * LDSW];
    const int tid = threadIdx.x, lane = tid & 63, wave = tid >> 6;
    const int wy = (TN == 128) ? (wave >> 1) : wave;
    const int wx = (TN == 128) ? (wave & 1) : 0;
    const int m0 = blockIdx.y * 128, n0 = blockIdx.x * TN;
    const int r0 = tid >> 3, c0 = (tid & 7) * 8;
    const int lm = lane & 15, lk = (lane >> 4) * 8;
    f4v acc[FI][FJ];
    #pragma unroll
    for (int i = 0; i < FI; ++i)
        #pragma unroll
        for (int j = 0; j < FJ; ++j) acc[i][j] = (f4v){0.f, 0.f, 0.f, 0.f};

    s8v an[NA], bn[NB];
    #pragma unroll
    for (int g = 0; g < NA; ++g) an[g] = *(const s8v*)(A + (size_t)(m0 + r0 + 32 * g) * lda + c0);
    #pragma unroll
    for (int g = 0; g < NB; ++g) bn[g] = *(const s8v*)(Bt + (size_t)(n0 + r0 + 32 * g) * ldb + c0);

    for (int k0 = 0; k0 < K; k0 += BK) {
        __syncthreads();
        #pragma unroll
        for (int g = 0; g < NA; ++g) *(s8v*)(As + (r0 + 32 * g) * LDSW + c0) = an[g];
        #pragma unroll
        for (int g = 0; g < NB; ++g) *(s8v*)(Bs + (r0 + 32 * g) * LDSW + c0) = bn[g];
        if (k0 + BK < K) {
            const int kn = k0 + BK;
            #pragma unroll
            for (int g = 0; g < NA; ++g) an[g] = *(const s8v*)(A + (size_t)(m0 + r0 + 32 * g) * lda + kn + c0);
            #pragma unroll
            for (int g = 0; g < NB; ++g) bn[g] = *(const s8v*)(Bt + (size_t)(n0 + r0 + 32 * g) * ldb + kn + c0);
        }
        __syncthreads();
        #pragma unroll
        for (int kc = 0; kc < BK; kc += 32) {
            s8v af[FI], bf[FJ];
            #pragma unroll
            for (int f = 0; f < FI; ++f)
                af[f] = *(const s8v*)(As + (wy * (128 / WY) + f * 16 + lm) * LDSW + kc + lk);
            #pragma unroll
            for (int f = 0; f < FJ; ++f)
                bf[f] = *(const s8v*)(Bs + (wx * (TN / WX) + f * 16 + lm) * LDSW + kc + lk);
            #pragma unroll
            for (int fi = 0; fi < FI; ++fi)
                #pragma unroll
                for (int fj = 0; fj < FJ; ++fj)
                    acc[fi][fj] = __builtin_amdgcn_mfma_f32_16x16x32_bf16(af[fi], bf[fj], acc[fi][fj], 0, 0, 0);
        }
    }

    const int embase = m0 + wy * (128 / WY) + (lane >> 4) * 4;
    const int enbase = n0 + wx * (TN / WX) + lm;
    #pragma unroll
    for (int fi = 0; fi < FI; ++fi) {
        #pragma unroll
        for (int fj = 0; fj < FJ; ++fj) {
            const int n = enbase + fj * 16;
            #pragma unroll
            for (int r = 0; r < 4; ++r) {
                const int m = embase + fi * 16 + r;
                float val = acc[fi][fj][r];
                size_t ci = (size_t)m * ldc + n;
                if (EPI == 0) {
                    const void* bp = (n < 512) ? bp0 : ((n < 1024) ? bp1 : bp2);
                    val += ldin(bp, n & 511, fm);
                    ((hb*)C)[ci] = __float2bfloat16(val);
                } else if (EPI == 1) {
                    val += ldin(bp0, n, fm) + ldin(res, (size_t)m * 512 + n, fm);
                    ((float*)C)[ci] = val;
                } else if (EPI == 2) {
                    val = gelu_f(val + ldin(bp0, n, fm));
                    ((hb*)C)[ci] = __float2bfloat16(val);
                } else {
                    val += ldin(bp0, n, fm) + ((const float*)res)[(size_t)m * 512 + n];
                    if (fm) ((float*)C)[ci] = val;
                    else ((hb*)C)[ci] = __float2bfloat16(val);
                }
            }
        }
    }
}

// ================ pipelined dist MFMA (3 hi/lo passes) ================
__global__ __launch_bounds__(256, 2)
void dist_mfma(const hb* __restrict__ ph, const hb* __restrict__ pl,
               const float* __restrict__ p2, const void* __restrict__ cp,
               float* __restrict__ out, int bb, const int* __restrict__ fl) {
    constexpr int BK = 64, LDSW = BK + 8;
    constexpr int KI = DDIM / BK;
    const int fm = *fl;
    const float c = ld_scalar(cp, fm);
    const float* p2b = p2 + bb * NTOK;
    const size_t rb = (size_t)bb * NTOK;
    __shared__ short As[128 * LDSW];
    __shared__ short Bs[128 * LDSW];
    const int tid = threadIdx.x, lane = tid & 63, wave = tid >> 6;
    const int wy = wave >> 1, wx = wave & 1;
    const int i0 = blockIdx.y * 128, j0 = blockIdx.x * 128;
    const int r0 = tid >> 3, c0 = (tid & 7) * 8;
    const int lm = lane & 15, lk = (lane >> 4) * 8;
    f4v acc[4][4];
    #pragma unroll
    for (int i = 0; i < 4; ++i)
        #pragma unroll
        for (int j = 0; j < 4; ++j) acc[i][j] = (f4v){0.f, 0.f, 0.f, 0.f};

    const hb* Ap[3] = {ph, ph, pl};
    const hb* Bp[3] = {ph, pl, ph};
    s8v an[4], bn[4];
    {
        const hb* Asrc = Ap[0]; const hb* Bsrc = Bp[0];
        #pragma unroll
        for (int g = 0; g < 4; ++g) {
            an[g] = *(const s8v*)(Asrc + (rb + i0 + r0 + 32 * g) * DDIM + c0);
            bn[g] = *(const s8v*)(Bsrc + (rb + j0 + r0 + 32 * g) * DDIM + c0);
        }
    }
    for (int it = 0; it < 3 * KI; ++it) {
        __syncthreads();
        #pragma unroll
        for (int g = 0; g < 4; ++g) {
            *(s8v*)(As + (r0 + 32 * g) * LDSW + c0) = an[g];
            *(s8v*)(Bs + (r0 + 32 * g) * LDSW + c0) = bn[g];
        }
        if (it + 1 < 3 * KI) {
            const int p = (it + 1) / KI, kn = ((it + 1) % KI) * BK;
            const hb* Asrc = Ap[p]; const hb* Bsrc = Bp[p];
            #pragma unroll
            for (int g = 0; g < 4; ++g) {
                an[g] = *(const s8v*)(Asrc + (rb + i0 + r0 + 32 * g) * DDIM + kn + c0);
                bn[g] = *(const s8v*)(Bsrc + (rb + j0 + r0 + 32 * g) * DDIM + kn + c0);
            }
        }
        __syncthreads();
        #pragma unroll
        for (int kc = 0; kc < BK; kc += 32) {
            s8v af[4], bf[4];
            #pragma unroll
            for (int f = 0; f < 4; ++f) {
                af[f] = *(const s8v*)(As + (wy * 64 + f * 16 + lm) * LDSW + kc + lk);
                bf[f] = *(const s8v*)(Bs + (wx * 64 + f * 16 + lm) * LDSW + kc + lk);
            }
            #pragma unroll
            for (int fi = 0; fi < 4; ++fi)
                #pragma unroll
                for (int fj = 0; fj < 4; ++fj)
                    acc[fi][fj] = __builtin_amdgcn_mfma_f32_16x16x32_bf16(af[fi], bf[fj], acc[fi][fj], 0, 0, 0);
        }
    }

    const int eibase = i0 + wy * 64 + (lane >> 4) * 4;
    const int ejbase = j0 + wx * 64 + lm;
    #pragma unroll
    for (int fi = 0; fi < 4; ++fi) {
        #pragma unroll
        for (int fj = 0; fj < 4; ++fj) {
            const int jj = ejbase + fj * 16;
            const float p2j = p2b[jj];
            #pragma unroll
            for (int r = 0; r < 4; ++r) {
                const int ii = eibase + fi * 16 + r;
                const float p2i = p2b[ii];
                float diff = fmaxf(p2i + p2j - 2.f * acc[fi][fj][r], 0.f);
                float den = fmaxf((1.f - c * p2i) * (1.f - c * p2j), 1e-8f);
                out[(size_t)ii * NTOK + jj] = 1.f + 2.f * c * diff / den;
            }
        }
    }
}

// ---------------- top-16 smallest per row + selected arg values ----------------
__global__ void topk_kernel(const float* __restrict__ argb, int* __restrict__ idxb,
                            float* __restrict__ argvb, int bb) {
    const int r = blockIdx.x;
    const float* arow = argb + (size_t)r * NTOK;
    int* orow = idxb + ((size_t)bb * NTOK + r) * KNN_K;
    float* vrow = argvb + ((size_t)bb * NTOK + r) * KNN_K;
    const int tid = threadIdx.x, lane = tid & 63, wv = tid >> 6;
    ull k8[8];
    #pragma unroll
    for (int i = 0; i < 8; ++i) {
        int idx = i * 256 + tid;
        unsigned int bbits = __float_as_uint(arow[idx]);
        k8[i] = ((ull)bbits << 32) | (unsigned int)idx;
    }
    __shared__ ull lw[4];
    for (int sel = 0; sel < KNN_K; ++sel) {
        ull m = k8[0];
        #pragma unroll
        for (int i = 1; i < 8; ++i) m = (k8[i] < m) ? k8[i] : m;
        #pragma unroll
        for (int off = 32; off; off >>= 1) {
            ull o = shfl_down_u64(m, off);
            m = (o < m) ? o : m;
        }
        if (lane == 0) lw[wv] = m;
        __syncthreads();
        ull m01 = (lw[0] < lw[1]) ? lw[0] : lw[1];
        ull m23 = (lw[2] < lw[3]) ? lw[2] : lw[3];
        ull m4 = (m01 < m23) ? m01 : m23;
        int widx = (int)(unsigned int)m4;
        if (tid == 0) {
            orow[sel] = widx;
            vrow[sel] = __uint_as_float((unsigned int)(m4 >> 32));
        }
        if ((widx & 255) == tid) k8[widx >> 8] = ~0ull;
        __syncthreads();
    }
}

// ---------------- fused attention v3: stat elimination + 16-lane groups ----------------
__global__ void attn_kernel(const void* __restrict__ pos,
                            const hb* __restrict__ qkvB, const int* __restrict__ idxb,
                            const float* __restrict__ argvb,
                            const float* __restrict__ p2, const float* __restrict__ spos,
                            const void* __restrict__ cp,
                            const void* __restrict__ geo_s, const void* __restrict__ geo_b,
                            const void* __restrict__ a_sc, const void* __restrict__ f_sc,
                            hb* __restrict__ attnO, const int* __restrict__ fl) {
    const int fm = *fl;
    const int row = blockIdx.x;
    const int bb = row >> 11;
    const int tid = threadIdx.x, lane = tid & 63, wv = tid >> 6;
    const int l16 = lane & 15, grp = lane >> 4;
    const int kk = wv * 4 + grp;                    // this group's neighbor 0..15
    __shared__ float qgsL[DDIM], qL[DDIM];
    __shared__ float sc_s[KNN_K], wgt_s[KNN_K];
    __shared__ int nid_s[KNN_K];
    __shared__ float red3[12];

    const float c = ld_scalar(cp, fm);
    const float cs = fmaxf(c, 1e-20f);
    const float sc_c = sqrtf(fmaxf(c, 0.f));

    // Phase A: cooperative row stats (qq, qgs_sum, qgb) + stage qgs, q in LDS
    float qq = 0.f, qgs_sum = 0.f, qgb = 0.f;
    {
        const int d0 = tid * 2;
        float qp0 = ldin(pos, (size_t)row * DDIM + d0, fm);
        float qp1 = ldin(pos, (size_t)row * DDIM + d0 + 1, fm);
        float q0 = b2f(qkvB[(size_t)row * 1536 + d0]);
        float q1 = b2f(qkvB[(size_t)row * 1536 + d0 + 1]);
        float gs0 = ldin(geo_s, d0, fm), gs1 = ldin(geo_s, d0 + 1, fm);
        float gb0 = ldin(geo_b, d0, fm), gb1 = ldin(geo_b, d0 + 1, fm);
        float a0 = q0 * gs0, a1 = q1 * gs1;
        qgsL[d0] = a0; qgsL[d0 + 1] = a1;
        qL[d0] = q0; qL[d0 + 1] = q1;
        qq = a0 * qp0 + a1 * qp1;
        qgs_sum = a0 + a1;
        qgb = q0 * gb0 + q1 * gb1;
    }
    if (tid < KNN_K) nid_s[tid] = idxb[row * KNN_K + tid];
    #pragma unroll
    for (int off = 32; off; off >>= 1) {
        qq += __shfl_down(qq, off);
        qgs_sum += __shfl_down(qgs_sum, off);
        qgb += __shfl_down(qgb, off);
    }
    if (lane == 0) { red3[wv] = qq; red3[4 + wv] = qgs_sum; red3[8 + wv] = qgb; }
    __syncthreads();
    const float QQ  = red3[0] + red3[1] + red3[2] + red3[3];
    const float QGS = red3[4] + red3[5] + red3[6] + red3[7];
    const float QGB = red3[8] + red3[9] + red3[10] + red3[11];

    // Phase B: per-group neighbor dots (qk = qgs·kp, feat = q·kv)
    const int j = nid_s[kk];
    const size_t nro = (size_t)(bb * NTOK + j) * DDIM;
    const size_t nrk = (size_t)(bb * NTOK + j) * 1536 + 512;
    float qk = 0.f, feat = 0.f;
    if (fm) {
        #pragma unroll
        for (int i = 0; i < 8; ++i) {
            const int d = l16 * 4 + i * 64;
            f4v kp = *(const f4v*)((const float*)pos + nro + d);
            f4v qg = *(const f4v*)(qgsL + d);
            qk += qg[0] * kp[0] + qg[1] * kp[1] + qg[2] * kp[2] + qg[3] * kp[3];
        }
    } else {
        #pragma unroll
        for (int i = 0; i < 8; ++i) {
            const int d = l16 * 4 + i * 64;
            s4v kp4 = *(const s4v*)((const hb*)pos + nro + d);
            f4v qg = *(const f4v*)(qgsL + d);
            #pragma unroll
            for (int e = 0; e < 4; ++e) qk += qg[e] * bits2f(kp4[e]);
        }
    }
    #pragma unroll
    for (int i = 0; i < 4; ++i) {
        const int d = l16 * 8 + i * 128;
        s8v kv = *(const s8v*)(qkvB + nrk + d);
        f4v q0 = *(const f4v*)(qL + d);
        f4v q1 = *(const f4v*)(qL + d + 4);
        #pragma unroll
        for (int e = 0; e < 4; ++e)
            feat += q0[e] * bits2f(kv[e]) + q1[e] * bits2f(kv[e + 4]);
    }
    #pragma unroll
    for (int off = 8; off; off >>= 1) {
        qk += __shfl_down(qk, off, 16);
        feat += __shfl_down(feat, off, 16);
    }
    if (l16 == 0) {
        const float p2i = p2[row], p2j = p2[bb * NTOK + j];
        const float sposi = spos[row], sposj = spos[bb * NTOK + j];
        const float argv = argvb[row * KNN_K + kk];
        const float den_d = fmaxf((1.f - c * p2i) * (1.f - c * p2j), 1e-8f);
        const float diff = (argv - 1.f) * den_d / (2.f * cs);
        const float xy = 0.5f * (p2i + p2j - diff);
        const float x2 = p2i, y2 = p2j;
        const float Af = 1.f - 2.f * c * xy + c * y2;
        const float Bf = 1.f - c * x2;
        float den = fmaxf(1.f - 2.f * c * xy + c * c * x2 * y2, 1e-8f);
        const float rden = 1.f / den;
        float n2 = fmaxf(Af * Af * x2 - 2.f * Af * Bf * xy + Bf * Bf * y2, 0.f) * rden * rden;
        const float ynorm = fmaxf(sqrtf(n2), 1e-8f);
        const float t_over = sc_c * ynorm;
        const float targ = fminf(t_over, 1.f - 1e-7f);
        const float scale = (targ > 0.f) ? (atanhf(targ) / t_over) : 1.f;
        const float S1 = scale * rden * (Bf * sposj - Af * sposi);
        const float mean = S1 * (1.f / DDIM);
        const float sq = scale * scale * n2;
        const float var = sq * (1.f / DDIM) - mean * mean;
        const float rstd = rsqrtf(fmaxf(var, 0.f) + 1e-6f);
        const float G = scale * rden * (Bf * qk - Af * QQ);
        const float align = rstd * (G - mean * QGS) + QGB;
        sc_s[kk] = ld_scalar(f_sc, fm) * feat + ld_scalar(a_sc, fm) * align;
    }
    __syncthreads();
    // Phase D: softmax by 16 lanes of wave 0
    if (tid < 16) {
        float v = sc_s[tid];
        float mx = v;
        #pragma unroll
        for (int off = 8; off; off >>= 1) mx = fmaxf(mx, __shfl_xor(mx, off, 16));
        float e = expf(v - mx);
        float s = e;
        #pragma unroll
        for (int off = 8; off; off >>= 1) s += __shfl_xor(s, off, 16);
        wgt_s[tid] = e / s;
    }
    __syncthreads();
    // Phase E: V accumulation, 2 dims/thread
    {
        const int d0 = tid * 2;
        float acc0 = 0.f, acc1 = 0.f;
        #pragma unroll
        for (int t = 0; t < KNN_K; ++t) {
            const hb* vp = qkvB + (size_t)(bb * NTOK + nid_s[t]) * 1536 + 1024 + d0;
            float w = wgt_s[t];
            acc0 += w * b2f(vp[0]);
            acc1 += w * b2f(vp[1]);
        }
        attnO[(size_t)row * DDIM + d0]     = __float2bfloat16(acc0);
        attnO[(size_t)row * DDIM + d0 + 1] = __float2bfloat16(acc1);
    }
}

extern "C" void kernel_launch(void* const* d_in, const int* in_sizes, int n_in,
                              void* d_out, int out_size, void* d_ws, size_t ws_size,
                              hipStream_t stream) {
    const void* x    = d_in[0];
    const void* posb = d_in[1];
    const void* cb   = d_in[2];
    const void* Wq   = d_in[3];
    const void* bq   = d_in[4];
    const void* Wk   = d_in[5];
    const void* bk   = d_in[6];
    const void* Wv   = d_in[7];
    const void* bv   = d_in[8];
    const void* Wo   = d_in[9];
    const void* bo   = d_in[10];
    const void* W1   = d_in[11];
    const void* b1   = d_in[12];
    const void* W2   = d_in[13];
    const void* b2   = d_in[14];
    const void* ln1s = d_in[15];
    const void* ln1b = d_in[16];
    const void* ln2s = d_in[17];
    const void* ln2b = d_in[18];
    const void* geos = d_in[19];
    const void* geob = d_in[20];
    const void* asc  = d_in[21];
    const void* fsc  = d_in[22];

    float* wsf = (float*)d_ws;
    int* flag = (int*)wsf;
    size_t off = 16;
    hb* xnB   = (hb*)(wsf + off); off += 1048576;   // 4096x512 bf16; later hbuf (LN2 out)
    hb* qkvB  = (hb*)(wsf + off); off += 3145728;   // 4096x1536 bf16
    float* p2 = wsf + off;        off += 4096;
    float* spos = wsf + off;      off += 4096;
    int* idxb = (int*)(wsf + off); off += 65536;
    float* argvb = wsf + off;     off += 65536;
    float* x1 = wsf + off;        off += 2097152;   // f32 4096x512
    float* argb = wsf + off;                         // NTOK^2 f32 (per batch)
    hb* hh    = (hb*)argb;        off += 4194304;   // later 4096x2048 bf16
    hb* ph    = (hb*)(wsf + off); off += 1048576;   // later attnO
    hb* pl    = (hb*)(wsf + off); off += 1048576;   // later W1T+W2T
    hb* WqkvT = (hb*)(wsf + off); off += 393216;    // 1536x512 bf16
    hb* WoT   = (hb*)(wsf + off); off += 131072;    // 512x512 bf16
    hb* attnO = ph;
    hb* W1T   = pl;                                  // 2048x512 bf16
    hb* W2T   = pl + 1048576;                        // 512x2048 bf16
    hb* hbuf  = xnB;

    // 0. dtype detection
    detect_kernel<<<1, 64, 0, stream>>>(x, flag);
    // attention weight transposes (merged)
    transposeA<<<1024, 256, 0, stream>>>(Wq, Wk, Wv, Wo, WqkvT, WoT, flag);
    // positions split + p2 + spos
    possplit_p2<<<ROWS, 256, 0, stream>>>(posb, ph, pl, p2, spos, flag);
    // 1. LN1 -> bf16
    ln_kernel<true><<<ROWS, 256, 0, stream>>>(x, ln1s, ln1b, xnB, flag);
    // 2. fused qkv GEMM
    gemm_bt<0, 128, 64><<<dim3(12, 32), 256, 0, stream>>>(xnB, WqkvT, bq, bk, bv, nullptr, qkvB,
                                                          1536, 512, 512, 512, 1536, flag);
    // 3. distances + top-16 per batch
    dist_mfma<<<dim3(16, 16), 256, 0, stream>>>(ph, pl, p2, cb, argb, 0, flag);
    topk_kernel<<<NTOK, 256, 0, stream>>>(argb, idxb, argvb, 0);
    dist_mfma<<<dim3(16, 16), 256, 0, stream>>>(ph, pl, p2, cb, argb, 1, flag);
    topk_kernel<<<NTOK, 256, 0, stream>>>(argb, idxb, argvb, 1);
    // FFN weight transposes (into pl region, dead after dist)
    transposeB<<<2048, 256, 0, stream>>>(W1, W2, W1T, W2T, flag);
    // 5. fused geometric attention -> bf16 (overlays ph)
    attn_kernel<<<ROWS, 256, 0, stream>>>(posb, qkvB, idxb, argvb, p2, spos, cb,
                                          geos, geob, asc, fsc, attnO, flag);
    // 6. x1 = x + attn @ Wo + bo  (f32)
    gemm_bt<1, 64, 64><<<dim3(8, 32), 256, 0, stream>>>(attnO, WoT, bo, nullptr, nullptr, x, x1,
                                                        512, 512, 512, 512, 512, flag);
    // 7. LN2 -> bf16
    ln_kernel<false><<<ROWS, 256, 0, stream>>>(x1, ln2s, ln2b, hbuf, flag);
    // 8. hh = gelu(h @ W1 + b1) -> bf16
    gemm_bt<2, 128, 64><<<dim3(16, 32), 256, 0, stream>>>(hbuf, W1T, b1, nullptr, nullptr, nullptr, hh,
                                                          2048, 512, 512, 512, 2048, flag);
    // 9. out = x1 + hh @ W2 + b2
    gemm_bt<3, 64, 64><<<dim3(8, 32), 256, 0, stream>>>(hh, W2T, b2, nullptr, nullptr, x1, d_out,
                                                        512, 2048, 2048, 2048, 512, flag);

    (void)in_sizes; (void)n_in; (void)out_size; (void)ws_size;
}

// Round 9
// 362.928 us; speedup vs baseline: 2.7992x; 1.0333x over previous
//
#include <hip/hip_runtime.h>
#include <hip/hip_bf16.h>
#include <math.h>

#define NTOK 2048      // N
#define DDIM 512       // D
#define FDIM 2048      // F
#define KNN_K 16
#define ROWS 4096      // B*N

typedef __hip_bfloat16 hb;
typedef unsigned long long ull;
typedef short s8v __attribute__((ext_vector_type(8)));
typedef short s4v __attribute__((ext_vector_type(4)));
typedef float f4v __attribute__((ext_vector_type(4)));

__device__ __forceinline__ float b2f(hb h) { return __bfloat162float(h); }
__device__ __forceinline__ float bits2f(short s) {
    return __uint_as_float(((unsigned int)(unsigned short)s) << 16);
}

__device__ __forceinline__ float ldin(const void* p, size_t i, int f32m) {
    return f32m ? ((const float*)p)[i] : b2f(((const hb*)p)[i]);
}
__device__ __forceinline__ float ld_scalar(const void* p, int f32m) {
    return f32m ? *(const float*)p : b2f(*(const hb*)p);
}

__device__ __forceinline__ ull shfl_xor_u64(ull x, int mask) {
    unsigned lo = (unsigned)x, hi = (unsigned)(x >> 32);
    lo = __shfl_xor(lo, mask); hi = __shfl_xor(hi, mask);
    return ((ull)hi << 32) | lo;
}

__device__ __forceinline__ float gelu_f(float x) {
    float x3 = x * x * x;
    return 0.5f * x * (1.f + tanhf(0.7978845608028654f * (x + 0.044715f * x3)));
}

// ---------------- dtype detector ----------------
__global__ void detect_kernel(const void* __restrict__ x, int* __restrict__ flag) {
    const unsigned short* u = (const unsigned short*)x;
    int tid = threadIdx.x;
    int bad = 0;
    #pragma unroll
    for (int t = 0; t < 16; ++t) {
        unsigned short h = u[tid * 16 + t];
        int e = (h >> 7) & 0xFF;
        if (e == 0xFF) bad++;
        else if (e >= 0x8E) bad++;
        else if (e != 0 && e <= 0x66) bad++;
    }
    #pragma unroll
    for (int off = 32; off; off >>= 1) bad += __shfl_down(bad, off);
    if (tid == 0) *flag = (bad > 100) ? 1 : 0;
}

// ---------------- transpose tile body ----------------
__device__ __forceinline__ void tr_tile(const void* src, hb* dst, int K, int N,
                                        int k0, int n0, int fm) {
    __shared__ float t[32][33];
    const int tx = threadIdx.x & 31, ty = threadIdx.x >> 5;   // 32 x 8
    #pragma unroll
    for (int r = 0; r < 32; r += 8)
        t[ty + r][tx] = ldin(src, (size_t)(k0 + ty + r) * N + n0 + tx, fm);
    __syncthreads();
    #pragma unroll
    for (int r = 0; r < 32; r += 8)
        dst[(size_t)(n0 + ty + r) * K + k0 + tx] = __float2bfloat16(t[tx][ty + r]);
}

__global__ void transposeA(const void* __restrict__ Wq, const void* __restrict__ Wk,
                           const void* __restrict__ Wv, const void* __restrict__ Wo,
                           hb* __restrict__ WqkvT, hb* __restrict__ WoT,
                           const int* __restrict__ fl) {
    const int fm = *fl;
    const int bx = blockIdx.x;              // 0..1023
    const int seg = bx >> 8, t = bx & 255;
    const int n0 = (t & 15) * 32, k0 = (t >> 4) * 32;
    const void* src = (seg == 0) ? Wq : (seg == 1) ? Wk : (seg == 2) ? Wv : Wo;
    hb* dst = (seg == 3) ? WoT : (WqkvT + (size_t)seg * 512 * 512);
    tr_tile(src, dst, 512, 512, k0, n0, fm);
}

__global__ void transposeB(const void* __restrict__ W1, const void* __restrict__ W2,
                           hb* __restrict__ W1T, hb* __restrict__ W2T,
                           const int* __restrict__ fl) {
    const int fm = *fl;
    const int bx = blockIdx.x;              // 0..2047
    if (bx < 1024) {
        const int n0 = (bx & 63) * 32, k0 = (bx >> 6) * 32;
        tr_tile(W1, W1T, 512, 2048, k0, n0, fm);
    } else {
        const int b2 = bx - 1024;
        const int n0 = (b2 & 15) * 32, k0 = (b2 >> 4) * 32;
        tr_tile(W2, W2T, 2048, 512, k0, n0, fm);
    }
}

// ---------------- prep: pos hi/lo split + p2 + spos + LN1 (fused) ----------------
__global__ void prep_kernel(const void* __restrict__ pos, const void* __restrict__ x,
                            const void* __restrict__ s, const void* __restrict__ b,
                            hb* __restrict__ ph, hb* __restrict__ pl,
                            float* __restrict__ p2, float* __restrict__ spos,
                            hb* __restrict__ xnB, const int* __restrict__ fl) {
    const int fm = *fl;
    const int row = blockIdx.x, tid = threadIdx.x;
    float s2 = 0.f, s1 = 0.f;
    #pragma unroll
    for (int t = 0; t < 2; ++t) {
        size_t i = (size_t)row * DDIM + tid + 256 * t;
        float v = ldin(pos, i, fm);
        hb h = __float2bfloat16(v);
        ph[i] = h;
        pl[i] = __float2bfloat16(v - b2f(h));
        s2 += v * v; s1 += v;
    }
    float v0 = ldin(x, (size_t)row * DDIM + tid, fm);
    float v1 = ldin(x, (size_t)row * DDIM + tid + 256, fm);
    float sum = v0 + v1, sq = v0 * v0 + v1 * v1;
    const int lane = tid & 63, wv = tid >> 6;
    #pragma unroll
    for (int off = 32; off; off >>= 1) {
        s2 += __shfl_down(s2, off); s1 += __shfl_down(s1, off);
        sum += __shfl_down(sum, off); sq += __shfl_down(sq, off);
    }
    __shared__ float ls[16];
    if (lane == 0) { ls[wv] = s2; ls[4 + wv] = s1; ls[8 + wv] = sum; ls[12 + wv] = sq; }
    __syncthreads();
    if (tid == 0) {
        p2[row]   = ls[0] + ls[1] + ls[2] + ls[3];
        spos[row] = ls[4] + ls[5] + ls[6] + ls[7];
    }
    float ts = ls[8] + ls[9] + ls[10] + ls[11];
    float tq = ls[12] + ls[13] + ls[14] + ls[15];
    float mean = ts * (1.f / DDIM);
    float var = tq * (1.f / DDIM) - mean * mean;
    float rstd = rsqrtf(var + 1e-6f);
    xnB[(size_t)row * DDIM + tid]       = __float2bfloat16(ldin(s, tid, fm) * (v0 - mean) * rstd + ldin(b, tid, fm));
    xnB[(size_t)row * DDIM + tid + 256] = __float2bfloat16(ldin(s, tid + 256, fm) * (v1 - mean) * rstd + ldin(b, tid + 256, fm));
}

// ---------------- LayerNorm (internal f32 in) ----------------
__global__ void ln_kernel(const float* __restrict__ xin,
                          const void* __restrict__ s, const void* __restrict__ b,
                          hb* __restrict__ y, const int* __restrict__ fl) {
    const int m = *fl;
    const int row = blockIdx.x, tid = threadIdx.x;
    const float* xp = xin + (size_t)row * DDIM;
    float v0 = xp[tid], v1 = xp[tid + 256];
    float sum = v0 + v1, sq = v0 * v0 + v1 * v1;
    const int lane = tid & 63, wv = tid >> 6;
    #pragma unroll
    for (int off = 32; off; off >>= 1) { sum += __shfl_down(sum, off); sq += __shfl_down(sq, off); }
    __shared__ float ls[8];
    if (lane == 0) { ls[wv] = sum; ls[4 + wv] = sq; }
    __syncthreads();
    float ts = ls[0] + ls[1] + ls[2] + ls[3];
    float tq = ls[4] + ls[5] + ls[6] + ls[7];
    float mean = ts * (1.f / DDIM);
    float var = tq * (1.f / DDIM) - mean * mean;
    float rstd = rsqrtf(var + 1e-6f);
    y[(size_t)row * DDIM + tid]       = __float2bfloat16(ldin(s, tid, m) * (v0 - mean) * rstd + ldin(b, tid, m));
    y[(size_t)row * DDIM + tid + 256] = __float2bfloat16(ldin(s, tid + 256, m) * (v1 - mean) * rstd + ldin(b, tid + 256, m));
}

// ================ pipelined MFMA GEMM ================
template<int EPI, int TN, int BK>
__global__ __launch_bounds__(256, 2)
void gemm_bt(const hb* __restrict__ A, const hb* __restrict__ Bt,
             const void* __restrict__ bp0, const void* __restrict__ bp1, const void* __restrict__ bp2,
             const void* __restrict__ res, void* __restrict__ C,
             int N, int K, int lda, int ldb, int ldc,
             const int* __restrict__ fl) {
    constexpr int WY = (TN == 128) ? 2 : 4;
    constexpr int WX = (TN == 128) ? 2 : 1;
    constexpr int FI = 128 / WY / 16;
    constexpr int FJ = TN / WX / 16;
    constexpr int NA = 128 * BK / (256 * 8);
    constexpr int NB = TN * BK / (256 * 8);
    constexpr int LDSW = BK + 8;
    const int fm = *fl;
    __shared__ short As[128 * LDSW];
    __shared__ short Bs[TN * LDSW];
    const int tid = threadIdx.x, lane = tid & 63, wave = tid >> 6;
    const int wy = (TN == 128) ? (wave >> 1) : wave;
    const int wx = (TN == 128) ? (wave & 1) : 0;
    const int m0 = blockIdx.y * 128, n0 = blockIdx.x * TN;
    const int r0 = tid >> 3, c0 = (tid & 7) * 8;
    const int lm = lane & 15, lk = (lane >> 4) * 8;
    f4v acc[FI][FJ];
    #pragma unroll
    for (int i = 0; i < FI; ++i)
        #pragma unroll
        for (int j = 0; j < FJ; ++j) acc[i][j] = (f4v){0.f, 0.f, 0.f, 0.f};

    s8v an[NA], bn[NB];
    #pragma unroll
    for (int g = 0; g < NA; ++g) an[g] = *(const s8v*)(A + (size_t)(m0 + r0 + 32 * g) * lda + c0);
    #pragma unroll
    for (int g = 0; g < NB; ++g) bn[g] = *(const s8v*)(Bt + (size_t)(n0 + r0 + 32 * g) * ldb + c0);

    for (int k0 = 0; k0 < K; k0 += BK) {
        __syncthreads();
        #pragma unroll
        for (int g = 0; g < NA; ++g) *(s8v*)(As + (r0 + 32 * g) * LDSW + c0) = an[g];
        #pragma unroll
        for (int g = 0; g < NB; ++g) *(s8v*)(Bs + (r0 + 32 * g) * LDSW + c0) = bn[g];
        if (k0 + BK < K) {
            const int kn = k0 + BK;
            #pragma unroll
            for (int g = 0; g < NA; ++g) an[g] = *(const s8v*)(A + (size_t)(m0 + r0 + 32 * g) * lda + kn + c0);
            #pragma unroll
            for (int g = 0; g < NB; ++g) bn[g] = *(const s8v*)(Bt + (size_t)(n0 + r0 + 32 * g) * ldb + kn + c0);
        }
        __syncthreads();
        #pragma unroll
        for (int kc = 0; kc < BK; kc += 32) {
            s8v af[FI], bf[FJ];
            #pragma unroll
            for (int f = 0; f < FI; ++f)
                af[f] = *(const s8v*)(As + (wy * (128 / WY) + f * 16 + lm) * LDSW + kc + lk);
            #pragma unroll
            for (int f = 0; f < FJ; ++f)
                bf[f] = *(const s8v*)(Bs + (wx * (TN / WX) + f * 16 + lm) * LDSW + kc + lk);
            #pragma unroll
            for (int fi = 0; fi < FI; ++fi)
                #pragma unroll
                for (int fj = 0; fj < FJ; ++fj)
                    acc[fi][fj] = __builtin_amdgcn_mfma_f32_16x16x32_bf16(af[fi], bf[fj], acc[fi][fj], 0, 0, 0);
        }
    }

    const int embase = m0 + wy * (128 / WY) + (lane >> 4) * 4;
    const int enbase = n0 + wx * (TN / WX) + lm;
    #pragma unroll
    for (int fi = 0; fi < FI; ++fi) {
        #pragma unroll
        for (int fj = 0; fj < FJ; ++fj) {
            const int n = enbase + fj * 16;
            #pragma unroll
            for (int r = 0; r < 4; ++r) {
                const int m = embase + fi * 16 + r;
                float val = acc[fi][fj][r];
                size_t ci = (size_t)m * ldc + n;
                if (EPI == 0) {
                    const void* bp = (n < 512) ? bp0 : ((n < 1024) ? bp1 : bp2);
                    val += ldin(bp, n & 511, fm);
                    ((hb*)C)[ci] = __float2bfloat16(val);
                } else if (EPI == 1) {
                    val += ldin(bp0, n, fm) + ldin(res, (size_t)m * 512 + n, fm);
                    ((float*)C)[ci] = val;
                } else if (EPI == 2) {
                    val = gelu_f(val + ldin(bp0, n, fm));
                    ((hb*)C)[ci] = __float2bfloat16(val);
                } else {
                    val += ldin(bp0, n, fm) + ((const float*)res)[(size_t)m * 512 + n];
                    if (fm) ((float*)C)[ci] = val;
                    else ((hb*)C)[ci] = __float2bfloat16(val);
                }
            }
        }
    }
}

// ================ symmetric dist MFMA: upper-triangular tiles, mirror-write, both batches ================
__global__ __launch_bounds__(256, 2)
void dist_mfma(const hb* __restrict__ ph, const hb* __restrict__ pl,
               const float* __restrict__ p2, const void* __restrict__ cp,
               float* __restrict__ argb, const int* __restrict__ fl) {
    constexpr int BK = 64, LDSW = BK + 8;
    constexpr int KI = DDIM / BK;
    const int fm = *fl;
    const float c = ld_scalar(cp, fm);
    const int bb = blockIdx.z;
    const float* p2b = p2 + bb * NTOK;
    const size_t rb = (size_t)bb * NTOK;
    float* out = argb + (size_t)bb * NTOK * NTOK;
    // triangular block index -> (bi, bj), bi <= bj
    int t = blockIdx.x, bi = 0, rem = 16;
    while (t >= rem) { t -= rem; bi++; rem = 16 - bi; }
    const int bj = bi + t;
    const int i0 = bi * 128, j0 = bj * 128;

    __shared__ short As[128 * LDSW];
    __shared__ short Bs[128 * LDSW];
    const int tid = threadIdx.x, lane = tid & 63, wave = tid >> 6;
    const int wy = wave >> 1, wx = wave & 1;
    const int r0 = tid >> 3, c0 = (tid & 7) * 8;
    const int lm = lane & 15, lk = (lane >> 4) * 8;
    f4v acc[4][4];
    #pragma unroll
    for (int i = 0; i < 4; ++i)
        #pragma unroll
        for (int j = 0; j < 4; ++j) acc[i][j] = (f4v){0.f, 0.f, 0.f, 0.f};

    const hb* Ap[3] = {ph, ph, pl};
    const hb* Bp[3] = {ph, pl, ph};
    s8v an[4], bn[4];
    #pragma unroll
    for (int g = 0; g < 4; ++g) {
        an[g] = *(const s8v*)(Ap[0] + (rb + i0 + r0 + 32 * g) * DDIM + c0);
        bn[g] = *(const s8v*)(Bp[0] + (rb + j0 + r0 + 32 * g) * DDIM + c0);
    }
    for (int it = 0; it < 3 * KI; ++it) {
        __syncthreads();
        #pragma unroll
        for (int g = 0; g < 4; ++g) {
            *(s8v*)(As + (r0 + 32 * g) * LDSW + c0) = an[g];
            *(s8v*)(Bs + (r0 + 32 * g) * LDSW + c0) = bn[g];
        }
        if (it + 1 < 3 * KI) {
            const int p = (it + 1) / KI, kn = ((it + 1) % KI) * BK;
            #pragma unroll
            for (int g = 0; g < 4; ++g) {
                an[g] = *(const s8v*)(Ap[p] + (rb + i0 + r0 + 32 * g) * DDIM + kn + c0);
                bn[g] = *(const s8v*)(Bp[p] + (rb + j0 + r0 + 32 * g) * DDIM + kn + c0);
            }
        }
        __syncthreads();
        #pragma unroll
        for (int kc = 0; kc < BK; kc += 32) {
            s8v af[4], bf[4];
            #pragma unroll
            for (int f = 0; f < 4; ++f) {
                af[f] = *(const s8v*)(As + (wy * 64 + f * 16 + lm) * LDSW + kc + lk);
                bf[f] = *(const s8v*)(Bs + (wx * 64 + f * 16 + lm) * LDSW + kc + lk);
            }
            #pragma unroll
            for (int fi = 0; fi < 4; ++fi)
                #pragma unroll
                for (int fj = 0; fj < 4; ++fj)
                    acc[fi][fj] = __builtin_amdgcn_mfma_f32_16x16x32_bf16(af[fi], bf[fj], acc[fi][fj], 0, 0, 0);
        }
    }

    const int eibase = i0 + wy * 64 + (lane >> 4) * 4;
    const int ejbase = j0 + wx * 64 + lm;
    const bool diag = (bi == bj);
    #pragma unroll
    for (int fi = 0; fi < 4; ++fi) {
        #pragma unroll
        for (int fj = 0; fj < 4; ++fj) {
            const int jj = ejbase + fj * 16;
            const float p2j = p2b[jj];
            #pragma unroll
            for (int r = 0; r < 4; ++r) {
                const int ii = eibase + fi * 16 + r;
                const float p2i = p2b[ii];
                float diff = fmaxf(p2i + p2j - 2.f * acc[fi][fj][r], 0.f);
                float den = fmaxf((1.f - c * p2i) * (1.f - c * p2j), 1e-8f);
                float argv = 1.f + 2.f * c * diff / den;
                out[(size_t)ii * NTOK + jj] = argv;
                if (!diag) out[(size_t)jj * NTOK + ii] = argv;
                else if (ii != jj) out[(size_t)jj * NTOK + ii] = argv;
            }
        }
    }
}

// ---------------- top-16: wave-local selection + single merge (both batches, one launch) ----------------
__global__ void topk_kernel(const float* __restrict__ argb, int* __restrict__ idxb,
                            float* __restrict__ argvb) {
    const int row = blockIdx.x;                 // 0..4095
    const int bb = row >> 11, r = row & (NTOK - 1);
    const float* arow = argb + (size_t)bb * NTOK * NTOK + (size_t)r * NTOK;
    int* orow = idxb + (size_t)row * KNN_K;
    float* vrow = argvb + (size_t)row * KNN_K;
    const int tid = threadIdx.x, lane = tid & 63, wv = tid >> 6;
    __shared__ ull cand[64];
    // wave w owns elements [w*512, (w+1)*512): idx = w*512 + lane + 64*i
    ull k8[8];
    #pragma unroll
    for (int i = 0; i < 8; ++i) {
        int idx = wv * 512 + lane + 64 * i;
        unsigned int bbits = __float_as_uint(arow[idx]);
        k8[i] = ((ull)bbits << 32) | (unsigned int)idx;
    }
    for (int sel = 0; sel < KNN_K; ++sel) {
        ull m = k8[0];
        #pragma unroll
        for (int i = 1; i < 8; ++i) m = (k8[i] < m) ? k8[i] : m;
        #pragma unroll
        for (int mask = 1; mask < 64; mask <<= 1) {
            ull o = shfl_xor_u64(m, mask);
            m = (o < m) ? o : m;
        }
        const int widx = (int)(unsigned int)m;
        if ((widx & 63) == lane) k8[(widx >> 6) & 7] = ~0ull;
        if (lane == 0) cand[wv * KNN_K + sel] = m;
    }
    __syncthreads();
    if (wv == 0) {
        ull key = cand[lane];
        for (int sel = 0; sel < KNN_K; ++sel) {
            ull m = key;
            #pragma unroll
            for (int mask = 1; mask < 64; mask <<= 1) {
                ull o = shfl_xor_u64(m, mask);
                m = (o < m) ? o : m;
            }
            if (lane == 0) {
                orow[sel] = (int)(unsigned int)m;
                vrow[sel] = __uint_as_float((unsigned int)(m >> 32));
            }
            if (key == m) key = ~0ull;
        }
    }
}

// ---------------- fused attention: stat elimination + 16-lane groups ----------------
__global__ void attn_kernel(const void* __restrict__ pos,
                            const hb* __restrict__ qkvB, const int* __restrict__ idxb,
                            const float* __restrict__ argvb,
                            const float* __restrict__ p2, const float* __restrict__ spos,
                            const void* __restrict__ cp,
                            const void* __restrict__ geo_s, const void* __restrict__ geo_b,
                            const void* __restrict__ a_sc, const void* __restrict__ f_sc,
                            hb* __restrict__ attnO, const int* __restrict__ fl) {
    const int fm = *fl;
    const int row = blockIdx.x;
    const int bb = row >> 11;
    const int tid = threadIdx.x, lane = tid & 63, wv = tid >> 6;
    const int l16 = lane & 15, grp = lane >> 4;
    const int kk = wv * 4 + grp;
    __shared__ float qgsL[DDIM], qL[DDIM];
    __shared__ float sc_s[KNN_K], wgt_s[KNN_K];
    __shared__ int nid_s[KNN_K];
    __shared__ float red3[12];

    const float c = ld_scalar(cp, fm);
    const float cs = fmaxf(c, 1e-20f);
    const float sc_c = sqrtf(fmaxf(c, 0.f));

    float qq = 0.f, qgs_sum = 0.f, qgb = 0.f;
    {
        const int d0 = tid * 2;
        float qp0 = ldin(pos, (size_t)row * DDIM + d0, fm);
        float qp1 = ldin(pos, (size_t)row * DDIM + d0 + 1, fm);
        float q0 = b2f(qkvB[(size_t)row * 1536 + d0]);
        float q1 = b2f(qkvB[(size_t)row * 1536 + d0 + 1]);
        float gs0 = ldin(geo_s, d0, fm), gs1 = ldin(geo_s, d0 + 1, fm);
        float gb0 = ldin(geo_b, d0, fm), gb1 = ldin(geo_b, d0 + 1, fm);
        float a0 = q0 * gs0, a1 = q1 * gs1;
        qgsL[d0] = a0; qgsL[d0 + 1] = a1;
        qL[d0] = q0; qL[d0 + 1] = q1;
        qq = a0 * qp0 + a1 * qp1;
        qgs_sum = a0 + a1;
        qgb = q0 * gb0 + q1 * gb1;
    }
    if (tid < KNN_K) nid_s[tid] = idxb[row * KNN_K + tid];
    #pragma unroll
    for (int off = 32; off; off >>= 1) {
        qq += __shfl_down(qq, off);
        qgs_sum += __shfl_down(qgs_sum, off);
        qgb += __shfl_down(qgb, off);
    }
    if (lane == 0) { red3[wv] = qq; red3[4 + wv] = qgs_sum; red3[8 + wv] = qgb; }
    __syncthreads();
    const float QQ  = red3[0] + red3[1] + red3[2] + red3[3];
    const float QGS = red3[4] + red3[5] + red3[6] + red3[7];
    const float QGB = red3[8] + red3[9] + red3[10] + red3[11];

    const int j = nid_s[kk];
    const size_t nro = (size_t)(bb * NTOK + j) * DDIM;
    const size_t nrk = (size_t)(bb * NTOK + j) * 1536 + 512;
    float qk = 0.f, feat = 0.f;
    if (fm) {
        #pragma unroll
        for (int i = 0; i < 8; ++i) {
            const int d = l16 * 4 + i * 64;
            f4v kp = *(const f4v*)((const float*)pos + nro + d);
            f4v qg = *(const f4v*)(qgsL + d);
            qk += qg[0] * kp[0] + qg[1] * kp[1] + qg[2] * kp[2] + qg[3] * kp[3];
        }
    } else {
        #pragma unroll
        for (int i = 0; i < 8; ++i) {
            const int d = l16 * 4 + i * 64;
            s4v kp4 = *(const s4v*)((const hb*)pos + nro + d);
            f4v qg = *(const f4v*)(qgsL + d);
            #pragma unroll
            for (int e = 0; e < 4; ++e) qk += qg[e] * bits2f(kp4[e]);
        }
    }
    #pragma unroll
    for (int i = 0; i < 4; ++i) {
        const int d = l16 * 8 + i * 128;
        s8v kv = *(const s8v*)(qkvB + nrk + d);
        f4v q0 = *(const f4v*)(qL + d);
        f4v q1 = *(const f4v*)(qL + d + 4);
        #pragma unroll
        for (int e = 0; e < 4; ++e)
            feat += q0[e] * bits2f(kv[e]) + q1[e] * bits2f(kv[e + 4]);
    }
    #pragma unroll
    for (int off = 8; off; off >>= 1) {
        qk += __shfl_down(qk, off, 16);
        feat += __shfl_down(feat, off, 16);
    }
    if (l16 == 0) {
        const float p2i = p2[row], p2j = p2[bb * NTOK + j];
        const float sposi = spos[row], sposj = spos[bb * NTOK + j];
        const float argv = argvb[row * KNN_K + kk];
        const float den_d = fmaxf((1.f - c * p2i) * (1.f - c * p2j), 1e-8f);
        const float diff = (argv - 1.f) * den_d / (2.f * cs);
        const float xy = 0.5f * (p2i + p2j - diff);
        const float x2 = p2i, y2 = p2j;
        const float Af = 1.f - 2.f * c * xy + c * y2;
        const float Bf = 1.f - c * x2;
        float den = fmaxf(1.f - 2.f * c * xy + c * c * x2 * y2, 1e-8f);
        const float rden = 1.f / den;
        float n2 = fmaxf(Af * Af * x2 - 2.f * Af * Bf * xy + Bf * Bf * y2, 0.f) * rden * rden;
        const float ynorm = fmaxf(sqrtf(n2), 1e-8f);
        const float t_over = sc_c * ynorm;
        const float targ = fminf(t_over, 1.f - 1e-7f);
        const float scale = (targ > 0.f) ? (atanhf(targ) / t_over) : 1.f;
        const float S1 = scale * rden * (Bf * sposj - Af * sposi);
        const float mean = S1 * (1.f / DDIM);
        const float sq = scale * scale * n2;
        const float var = sq * (1.f / DDIM) - mean * mean;
        const float rstd = rsqrtf(fmaxf(var, 0.f) + 1e-6f);
        const float G = scale * rden * (Bf * qk - Af * QQ);
        const float align = rstd * (G - mean * QGS) + QGB;
        sc_s[kk] = ld_scalar(f_sc, fm) * feat + ld_scalar(a_sc, fm) * align;
    }
    __syncthreads();
    if (tid < 16) {
        float v = sc_s[tid];
        float mx = v;
        #pragma unroll
        for (int off = 8; off; off >>= 1) mx = fmaxf(mx, __shfl_xor(mx, off, 16));
        float e = expf(v - mx);
        float s = e;
        #pragma unroll
        for (int off = 8; off; off >>= 1) s += __shfl_xor(s, off, 16);
        wgt_s[tid] = e / s;
    }
    __syncthreads();
    {
        const int d0 = tid * 2;
        float acc0 = 0.f, acc1 = 0.f;
        #pragma unroll
        for (int t = 0; t < KNN_K; ++t) {
            const hb* vp = qkvB + (size_t)(bb * NTOK + nid_s[t]) * 1536 + 1024 + d0;
            float w = wgt_s[t];
            acc0 += w * b2f(vp[0]);
            acc1 += w * b2f(vp[1]);
        }
        attnO[(size_t)row * DDIM + d0]     = __float2bfloat16(acc0);
        attnO[(size_t)row * DDIM + d0 + 1] = __float2bfloat16(acc1);
    }
}

extern "C" void kernel_launch(void* const* d_in, const int* in_sizes, int n_in,
                              void* d_out, int out_size, void* d_ws, size_t ws_size,
                              hipStream_t stream) {
    const void* x    = d_in[0];
    const void* posb = d_in[1];
    const void* cb   = d_in[2];
    const void* Wq   = d_in[3];
    const void* bq   = d_in[4];
    const void* Wk   = d_in[5];
    const void* bk   = d_in[6];
    const void* Wv   = d_in[7];
    const void* bv   = d_in[8];
    const void* Wo   = d_in[9];
    const void* bo   = d_in[10];
    const void* W1   = d_in[11];
    const void* b1   = d_in[12];
    const void* W2   = d_in[13];
    const void* b2   = d_in[14];
    const void* ln1s = d_in[15];
    const void* ln1b = d_in[16];
    const void* ln2s = d_in[17];
    const void* ln2b = d_in[18];
    const void* geos = d_in[19];
    const void* geob = d_in[20];
    const void* asc  = d_in[21];
    const void* fsc  = d_in[22];

    float* wsf = (float*)d_ws;
    int* flag = (int*)wsf;
    size_t off = 16;
    hb* xnB   = (hb*)(wsf + off); off += 1048576;   // 4096x512 bf16; later hbuf (LN2 out)
    hb* qkvB  = (hb*)(wsf + off); off += 3145728;   // 4096x1536 bf16
    float* p2 = wsf + off;        off += 4096;
    float* spos = wsf + off;      off += 4096;
    int* idxb = (int*)(wsf + off); off += 65536;
    float* argvb = wsf + off;     off += 65536;
    float* x1 = wsf + off;        off += 2097152;   // f32 4096x512
    float* argb = wsf + off;                         // 2 x NTOK^2 f32
    hb* hh    = (hb*)argb;        off += 8388608;   // hh overlays argb (dead by FFN)
    hb* ph    = (hb*)(wsf + off); off += 1048576;   // later attnO
    hb* pl    = (hb*)(wsf + off); off += 1048576;   // later W1T+W2T
    hb* WqkvT = (hb*)(wsf + off); off += 393216;    // 1536x512 bf16
    hb* WoT   = (hb*)(wsf + off); off += 131072;    // 512x512 bf16
    hb* attnO = ph;
    hb* W1T   = pl;                                  // 2048x512 bf16
    hb* W2T   = pl + 1048576;                        // 512x2048 bf16
    hb* hbuf  = xnB;

    // 0. dtype detection
    detect_kernel<<<1, 64, 0, stream>>>(x, flag);
    // attention weight transposes
    transposeA<<<1024, 256, 0, stream>>>(Wq, Wk, Wv, Wo, WqkvT, WoT, flag);
    // prep: pos split + p2 + spos + LN1
    prep_kernel<<<ROWS, 256, 0, stream>>>(posb, x, ln1s, ln1b, ph, pl, p2, spos, xnB, flag);
    // qkv GEMM
    gemm_bt<0, 128, 64><<<dim3(12, 32), 256, 0, stream>>>(xnB, WqkvT, bq, bk, bv, nullptr, qkvB,
                                                          1536, 512, 512, 512, 1536, flag);
    // distances (symmetric, both batches) + top-16 (both batches)
    dist_mfma<<<dim3(136, 1, 2), 256, 0, stream>>>(ph, pl, p2, cb, argb, flag);
    topk_kernel<<<ROWS, 256, 0, stream>>>(argb, idxb, argvb);
    // FFN weight transposes (pl dead after dist)
    transposeB<<<2048, 256, 0, stream>>>(W1, W2, W1T, W2T, flag);
    // fused geometric attention (overlays ph)
    attn_kernel<<<ROWS, 256, 0, stream>>>(posb, qkvB, idxb, argvb, p2, spos, cb,
                                          geos, geob, asc, fsc, attnO, flag);
    // x1 = x + attn @ Wo + bo  (f32)
    gemm_bt<1, 64, 64><<<dim3(8, 32), 256, 0, stream>>>(attnO, WoT, bo, nullptr, nullptr, x, x1,
                                                        512, 512, 512, 512, 512, flag);
    // LN2 -> bf16
    ln_kernel<<<ROWS, 256, 0, stream>>>(x1, ln2s, ln2b, hbuf, flag);
    // hh = gelu(h @ W1 + b1) -> bf16
    gemm_bt<2, 128, 64><<<dim3(16, 32), 256, 0, stream>>>(hbuf, W1T, b1, nullptr, nullptr, nullptr, hh,
                                                          2048, 512, 512, 512, 2048, flag);
    // out = x1 + hh @ W2 + b2
    gemm_bt<3, 64, 64><<<dim3(8, 32), 256, 0, stream>>>(hh, W2T, b2, nullptr, nullptr, x1, d_out,
                                                        512, 2048, 2048, 2048, 512, flag);

    (void)in_sizes; (void)n_in; (void)out_size; (void)ws_size;
}

// Round 10
// 344.244 us; speedup vs baseline: 2.9512x; 1.0543x over previous
//
#include <hip/hip_runtime.h>
#include <hip/hip_bf16.h>
#include <math.h>

#define NTOK 2048      // N
#define DDIM 512       // D
#define FDIM 2048      // F
#define KNN_K 16
#define ROWS 4096      // B*N

typedef __hip_bfloat16 hb;
typedef unsigned long long ull;
typedef short s8v __attribute__((ext_vector_type(8)));
typedef short s4v __attribute__((ext_vector_type(4)));
typedef float f4v __attribute__((ext_vector_type(4)));

__device__ __forceinline__ float b2f(hb h) { return __bfloat162float(h); }
__device__ __forceinline__ float bits2f(short s) {
    return __uint_as_float(((unsigned int)(unsigned short)s) << 16);
}

__device__ __forceinline__ float ldin(const void* p, size_t i, int f32m) {
    return f32m ? ((const float*)p)[i] : b2f(((const hb*)p)[i]);
}
__device__ __forceinline__ float ld_scalar(const void* p, int f32m) {
    return f32m ? *(const float*)p : b2f(*(const hb*)p);
}

__device__ __forceinline__ ull shfl_xor_u64(ull x, int mask) {
    unsigned lo = (unsigned)x, hi = (unsigned)(x >> 32);
    lo = __shfl_xor(lo, mask); hi = __shfl_xor(hi, mask);
    return ((ull)hi << 32) | lo;
}

__device__ __forceinline__ float gelu_f(float x) {
    float x3 = x * x * x;
    return 0.5f * x * (1.f + tanhf(0.7978845608028654f * (x + 0.044715f * x3)));
}

// ---------------- dtype detector ----------------
__global__ void detect_kernel(const void* __restrict__ x, int* __restrict__ flag) {
    const unsigned short* u = (const unsigned short*)x;
    int tid = threadIdx.x;
    int bad = 0;
    #pragma unroll
    for (int t = 0; t < 16; ++t) {
        unsigned short h = u[tid * 16 + t];
        int e = (h >> 7) & 0xFF;
        if (e == 0xFF) bad++;
        else if (e >= 0x8E) bad++;
        else if (e != 0 && e <= 0x66) bad++;
    }
    #pragma unroll
    for (int off = 32; off; off >>= 1) bad += __shfl_down(bad, off);
    if (tid == 0) *flag = (bad > 100) ? 1 : 0;
}

// ---------------- transpose tile body ----------------
__device__ __forceinline__ void tr_tile(const void* src, hb* dst, int K, int N,
                                        int k0, int n0, int fm) {
    __shared__ float t[32][33];
    const int tx = threadIdx.x & 31, ty = threadIdx.x >> 5;   // 32 x 8
    #pragma unroll
    for (int r = 0; r < 32; r += 8)
        t[ty + r][tx] = ldin(src, (size_t)(k0 + ty + r) * N + n0 + tx, fm);
    __syncthreads();
    #pragma unroll
    for (int r = 0; r < 32; r += 8)
        dst[(size_t)(n0 + ty + r) * K + k0 + tx] = __float2bfloat16(t[tx][ty + r]);
}

__global__ void transposeA(const void* __restrict__ Wq, const void* __restrict__ Wk,
                           const void* __restrict__ Wv, const void* __restrict__ Wo,
                           hb* __restrict__ WqkvT, hb* __restrict__ WoT,
                           const int* __restrict__ fl) {
    const int fm = *fl;
    const int bx = blockIdx.x;              // 0..1023
    const int seg = bx >> 8, t = bx & 255;
    const int n0 = (t & 15) * 32, k0 = (t >> 4) * 32;
    const void* src = (seg == 0) ? Wq : (seg == 1) ? Wk : (seg == 2) ? Wv : Wo;
    hb* dst = (seg == 3) ? WoT : (WqkvT + (size_t)seg * 512 * 512);
    tr_tile(src, dst, 512, 512, k0, n0, fm);
}

__global__ void transposeB(const void* __restrict__ W1, const void* __restrict__ W2,
                           hb* __restrict__ W1T, hb* __restrict__ W2T,
                           const int* __restrict__ fl) {
    const int fm = *fl;
    const int bx = blockIdx.x;              // 0..2047
    if (bx < 1024) {
        const int n0 = (bx & 63) * 32, k0 = (bx >> 6) * 32;
        tr_tile(W1, W1T, 512, 2048, k0, n0, fm);
    } else {
        const int b2 = bx - 1024;
        const int n0 = (b2 & 15) * 32, k0 = (b2 >> 4) * 32;
        tr_tile(W2, W2T, 2048, 512, k0, n0, fm);
    }
}

// ---------------- prep: pos hi/lo split + p2 + spos + LN1 (fused) ----------------
__global__ void prep_kernel(const void* __restrict__ pos, const void* __restrict__ x,
                            const void* __restrict__ s, const void* __restrict__ b,
                            hb* __restrict__ ph, hb* __restrict__ pl,
                            float* __restrict__ p2, float* __restrict__ spos,
                            hb* __restrict__ xnB, const int* __restrict__ fl) {
    const int fm = *fl;
    const int row = blockIdx.x, tid = threadIdx.x;
    float s2 = 0.f, s1 = 0.f;
    #pragma unroll
    for (int t = 0; t < 2; ++t) {
        size_t i = (size_t)row * DDIM + tid + 256 * t;
        float v = ldin(pos, i, fm);
        hb h = __float2bfloat16(v);
        ph[i] = h;
        pl[i] = __float2bfloat16(v - b2f(h));
        s2 += v * v; s1 += v;
    }
    float v0 = ldin(x, (size_t)row * DDIM + tid, fm);
    float v1 = ldin(x, (size_t)row * DDIM + tid + 256, fm);
    float sum = v0 + v1, sq = v0 * v0 + v1 * v1;
    const int lane = tid & 63, wv = tid >> 6;
    #pragma unroll
    for (int off = 32; off; off >>= 1) {
        s2 += __shfl_down(s2, off); s1 += __shfl_down(s1, off);
        sum += __shfl_down(sum, off); sq += __shfl_down(sq, off);
    }
    __shared__ float ls[16];
    if (lane == 0) { ls[wv] = s2; ls[4 + wv] = s1; ls[8 + wv] = sum; ls[12 + wv] = sq; }
    __syncthreads();
    if (tid == 0) {
        p2[row]   = ls[0] + ls[1] + ls[2] + ls[3];
        spos[row] = ls[4] + ls[5] + ls[6] + ls[7];
    }
    float ts = ls[8] + ls[9] + ls[10] + ls[11];
    float tq = ls[12] + ls[13] + ls[14] + ls[15];
    float mean = ts * (1.f / DDIM);
    float var = tq * (1.f / DDIM) - mean * mean;
    float rstd = rsqrtf(var + 1e-6f);
    xnB[(size_t)row * DDIM + tid]       = __float2bfloat16(ldin(s, tid, fm) * (v0 - mean) * rstd + ldin(b, tid, fm));
    xnB[(size_t)row * DDIM + tid + 256] = __float2bfloat16(ldin(s, tid + 256, fm) * (v1 - mean) * rstd + ldin(b, tid + 256, fm));
}

// ---------------- LayerNorm (internal f32 in) ----------------
__global__ void ln_kernel(const float* __restrict__ xin,
                          const void* __restrict__ s, const void* __restrict__ b,
                          hb* __restrict__ y, const int* __restrict__ fl) {
    const int m = *fl;
    const int row = blockIdx.x, tid = threadIdx.x;
    const float* xp = xin + (size_t)row * DDIM;
    float v0 = xp[tid], v1 = xp[tid + 256];
    float sum = v0 + v1, sq = v0 * v0 + v1 * v1;
    const int lane = tid & 63, wv = tid >> 6;
    #pragma unroll
    for (int off = 32; off; off >>= 1) { sum += __shfl_down(sum, off); sq += __shfl_down(sq, off); }
    __shared__ float ls[8];
    if (lane == 0) { ls[wv] = sum; ls[4 + wv] = sq; }
    __syncthreads();
    float ts = ls[0] + ls[1] + ls[2] + ls[3];
    float tq = ls[4] + ls[5] + ls[6] + ls[7];
    float mean = ts * (1.f / DDIM);
    float var = tq * (1.f / DDIM) - mean * mean;
    float rstd = rsqrtf(var + 1e-6f);
    y[(size_t)row * DDIM + tid]       = __float2bfloat16(ldin(s, tid, m) * (v0 - mean) * rstd + ldin(b, tid, m));
    y[(size_t)row * DDIM + tid + 256] = __float2bfloat16(ldin(s, tid + 256, m) * (v1 - mean) * rstd + ldin(b, tid + 256, m));
}

// ================ pipelined MFMA GEMM ================
template<int EPI, int TN, int BK>
__global__ __launch_bounds__(256, 2)
void gemm_bt(const hb* __restrict__ A, const hb* __restrict__ Bt,
             const void* __restrict__ bp0, const void* __restrict__ bp1, const void* __restrict__ bp2,
             const void* __restrict__ res, void* __restrict__ C,
             int N, int K, int lda, int ldb, int ldc,
             const int* __restrict__ fl) {
    constexpr int WY = (TN == 128) ? 2 : 4;
    constexpr int WX = (TN == 128) ? 2 : 1;
    constexpr int FI = 128 / WY / 16;
    constexpr int FJ = TN / WX / 16;
    constexpr int NA = 128 * BK / (256 * 8);
    constexpr int NB = TN * BK / (256 * 8);
    constexpr int LDSW = BK + 8;
    const int fm = *fl;
    __shared__ short As[128 * LDSW];
    __shared__ short Bs[TN * LDSW];
    const int tid = threadIdx.x, lane = tid & 63, wave = tid >> 6;
    const int wy = (TN == 128) ? (wave >> 1) : wave;
    const int wx = (TN == 128) ? (wave & 1) : 0;
    const int m0 = blockIdx.y * 128, n0 = blockIdx.x * TN;
    const int r0 = tid >> 3, c0 = (tid & 7) * 8;
    const int lm = lane & 15, lk = (lane >> 4) * 8;
    f4v acc[FI][FJ];
    #pragma unroll
    for (int i = 0; i < FI; ++i)
        #pragma unroll
        for (int j = 0; j < FJ; ++j) acc[i][j] = (f4v){0.f, 0.f, 0.f, 0.f};

    s8v an[NA], bn[NB];
    #pragma unroll
    for (int g = 0; g < NA; ++g) an[g] = *(const s8v*)(A + (size_t)(m0 + r0 + 32 * g) * lda + c0);
    #pragma unroll
    for (int g = 0; g < NB; ++g) bn[g] = *(const s8v*)(Bt + (size_t)(n0 + r0 + 32 * g) * ldb + c0);

    for (int k0 = 0; k0 < K; k0 += BK) {
        __syncthreads();
        #pragma unroll
        for (int g = 0; g < NA; ++g) *(s8v*)(As + (r0 + 32 * g) * LDSW + c0) = an[g];
        #pragma unroll
        for (int g = 0; g < NB; ++g) *(s8v*)(Bs + (r0 + 32 * g) * LDSW + c0) = bn[g];
        if (k0 + BK < K) {
            const int kn = k0 + BK;
            #pragma unroll
            for (int g = 0; g < NA; ++g) an[g] = *(const s8v*)(A + (size_t)(m0 + r0 + 32 * g) * lda + kn + c0);
            #pragma unroll
            for (int g = 0; g < NB; ++g) bn[g] = *(const s8v*)(Bt + (size_t)(n0 + r0 + 32 * g) * ldb + kn + c0);
        }
        __syncthreads();
        #pragma unroll
        for (int kc = 0; kc < BK; kc += 32) {
            s8v af[FI], bf[FJ];
            #pragma unroll
            for (int f = 0; f < FI; ++f)
                af[f] = *(const s8v*)(As + (wy * (128 / WY) + f * 16 + lm) * LDSW + kc + lk);
            #pragma unroll
            for (int f = 0; f < FJ; ++f)
                bf[f] = *(const s8v*)(Bs + (wx * (TN / WX) + f * 16 + lm) * LDSW + kc + lk);
            #pragma unroll
            for (int fi = 0; fi < FI; ++fi)
                #pragma unroll
                for (int fj = 0; fj < FJ; ++fj)
                    acc[fi][fj] = __builtin_amdgcn_mfma_f32_16x16x32_bf16(af[fi], bf[fj], acc[fi][fj], 0, 0, 0);
        }
    }

    const int embase = m0 + wy * (128 / WY) + (lane >> 4) * 4;
    const int enbase = n0 + wx * (TN / WX) + lm;
    #pragma unroll
    for (int fi = 0; fi < FI; ++fi) {
        #pragma unroll
        for (int fj = 0; fj < FJ; ++fj) {
            const int n = enbase + fj * 16;
            #pragma unroll
            for (int r = 0; r < 4; ++r) {
                const int m = embase + fi * 16 + r;
                float val = acc[fi][fj][r];
                size_t ci = (size_t)m * ldc + n;
                if (EPI == 0) {
                    const void* bp = (n < 512) ? bp0 : ((n < 1024) ? bp1 : bp2);
                    val += ldin(bp, n & 511, fm);
                    ((hb*)C)[ci] = __float2bfloat16(val);
                } else if (EPI == 1) {
                    val += ldin(bp0, n, fm) + ldin(res, (size_t)m * 512 + n, fm);
                    ((float*)C)[ci] = val;
                } else if (EPI == 2) {
                    val = gelu_f(val + ldin(bp0, n, fm));
                    ((hb*)C)[ci] = __float2bfloat16(val);
                } else {
                    val += ldin(bp0, n, fm) + ((const float*)res)[(size_t)m * 512 + n];
                    if (fm) ((float*)C)[ci] = val;
                    else ((hb*)C)[ci] = __float2bfloat16(val);
                }
            }
        }
    }
}

// ================ dist v3: fused hi/lo (2 accumulators), triangular, LDS-transposed mirror ================
__global__ __launch_bounds__(256, 2)
void dist_mfma(const hb* __restrict__ ph, const hb* __restrict__ pl,
               const float* __restrict__ p2, const void* __restrict__ cp,
               float* __restrict__ argb, const int* __restrict__ fl) {
    constexpr int BK = 32, LDSW = BK + 8;       // 40 shorts/row per staged tile
    constexpr int KI = DDIM / BK;               // 16 k-iterations
    constexpr int TSH = 128 * LDSW;             // shorts per tile (5120)
    __shared__ float Tm[128 * 132];             // 67584 B: mirror scratch; aliased for staging
    short* Sb = (short*)Tm;                     // 4 tiles at Sb + t*TSH (40960 B total)

    const int fm = *fl;
    const float c = ld_scalar(cp, fm);
    const int bb = blockIdx.z;
    const float* p2b = p2 + bb * NTOK;
    const size_t rb = (size_t)bb * NTOK;
    float* out = argb + (size_t)bb * NTOK * NTOK;
    // triangular block index -> (bi, bj), bi <= bj
    int t = blockIdx.x, bi = 0, rem = 16;
    while (t >= rem) { t -= rem; bi++; rem = 16 - bi; }
    const int bj = bi + t;
    const int i0 = bi * 128, j0 = bj * 128;
    const bool diag = (bi == bj);

    const int tid = threadIdx.x, lane = tid & 63, wave = tid >> 6;
    const int wy = wave >> 1, wx = wave & 1;
    const int r0 = tid >> 2, c0 = (tid & 3) * 8;      // 64 rows x 32 cols per pass, 2 passes
    const int lm = lane & 15, lk = (lane >> 4) * 8;

    const hb* src[4] = { ph + (rb + i0) * DDIM, pl + (rb + i0) * DDIM,
                         ph + (rb + j0) * DDIM, pl + (rb + j0) * DDIM };

    f4v acc_hh[4][4], acc_x[4][4];
    #pragma unroll
    for (int i = 0; i < 4; ++i)
        #pragma unroll
        for (int j = 0; j < 4; ++j) { acc_hh[i][j] = (f4v){0.f,0.f,0.f,0.f}; acc_x[i][j] = (f4v){0.f,0.f,0.f,0.f}; }

    s8v pf[4][2];
    #pragma unroll
    for (int tt = 0; tt < 4; ++tt)
        #pragma unroll
        for (int g = 0; g < 2; ++g)
            pf[tt][g] = *(const s8v*)(src[tt] + (size_t)(r0 + 64 * g) * DDIM + c0);

    for (int it = 0; it < KI; ++it) {
        __syncthreads();
        #pragma unroll
        for (int tt = 0; tt < 4; ++tt)
            #pragma unroll
            for (int g = 0; g < 2; ++g)
                *(s8v*)(Sb + tt * TSH + (r0 + 64 * g) * LDSW + c0) = pf[tt][g];
        if (it + 1 < KI) {
            const int kn = (it + 1) * BK;
            #pragma unroll
            for (int tt = 0; tt < 4; ++tt)
                #pragma unroll
                for (int g = 0; g < 2; ++g)
                    pf[tt][g] = *(const s8v*)(src[tt] + (size_t)(r0 + 64 * g) * DDIM + kn + c0);
        }
        __syncthreads();
        s8v ah[4], al[4], bh[4], bl[4];
        #pragma unroll
        for (int f = 0; f < 4; ++f) {
            ah[f] = *(const s8v*)(Sb + 0 * TSH + (wy * 64 + f * 16 + lm) * LDSW + lk);
            al[f] = *(const s8v*)(Sb + 1 * TSH + (wy * 64 + f * 16 + lm) * LDSW + lk);
            bh[f] = *(const s8v*)(Sb + 2 * TSH + (wx * 64 + f * 16 + lm) * LDSW + lk);
            bl[f] = *(const s8v*)(Sb + 3 * TSH + (wx * 64 + f * 16 + lm) * LDSW + lk);
        }
        #pragma unroll
        for (int fi = 0; fi < 4; ++fi)
            #pragma unroll
            for (int fj = 0; fj < 4; ++fj) {
                acc_hh[fi][fj] = __builtin_amdgcn_mfma_f32_16x16x32_bf16(ah[fi], bh[fj], acc_hh[fi][fj], 0, 0, 0);
                acc_x[fi][fj]  = __builtin_amdgcn_mfma_f32_16x16x32_bf16(ah[fi], bl[fj], acc_x[fi][fj], 0, 0, 0);
                acc_x[fi][fj]  = __builtin_amdgcn_mfma_f32_16x16x32_bf16(al[fi], bh[fj], acc_x[fi][fj], 0, 0, 0);
            }
    }

    __syncthreads();            // staging dead; Tm reused as mirror scratch
    const int eibase = i0 + wy * 64 + (lane >> 4) * 4;
    const int ejbase = j0 + wx * 64 + lm;
    #pragma unroll
    for (int fi = 0; fi < 4; ++fi) {
        #pragma unroll
        for (int fj = 0; fj < 4; ++fj) {
            const int jj = ejbase + fj * 16;
            const float p2j = p2b[jj];
            #pragma unroll
            for (int r = 0; r < 4; ++r) {
                const int ii = eibase + fi * 16 + r;
                const float p2i = p2b[ii];
                const float xy = acc_hh[fi][fj][r] + acc_x[fi][fj][r];
                float diff = fmaxf(p2i + p2j - 2.f * xy, 0.f);
                float den = fmaxf((1.f - c * p2i) * (1.f - c * p2j), 1e-8f);
                float argv = 1.f + 2.f * c * diff / den;
                out[(size_t)ii * NTOK + jj] = argv;
                if (!diag) Tm[(jj - j0) * 132 + (ii - i0)] = argv;
            }
        }
    }
    if (!diag) {
        __syncthreads();
        // coalesced mirror: rows of transposed tile -> out[(j0+rowT)*NTOK + i0 + col]
        #pragma unroll
        for (int k = 0; k < 16; ++k) {
            const int lin = k * 256 + tid;      // f4v units, 4096 total
            const int rowT = lin >> 5;          // 32 f4v per 128-col row
            const int c4 = (lin & 31) * 4;
            f4v v = *(const f4v*)(Tm + rowT * 132 + c4);
            *(f4v*)(out + (size_t)(j0 + rowT) * NTOK + i0 + c4) = v;
        }
    }
}

// ---------------- top-16: wave-local selection + single merge (both batches, one launch) ----------------
__global__ void topk_kernel(const float* __restrict__ argb, int* __restrict__ idxb,
                            float* __restrict__ argvb) {
    const int row = blockIdx.x;                 // 0..4095
    const int bb = row >> 11, r = row & (NTOK - 1);
    const float* arow = argb + (size_t)bb * NTOK * NTOK + (size_t)r * NTOK;
    int* orow = idxb + (size_t)row * KNN_K;
    float* vrow = argvb + (size_t)row * KNN_K;
    const int tid = threadIdx.x, lane = tid & 63, wv = tid >> 6;
    __shared__ ull cand[64];
    ull k8[8];
    #pragma unroll
    for (int i = 0; i < 8; ++i) {
        int idx = wv * 512 + lane + 64 * i;
        unsigned int bbits = __float_as_uint(arow[idx]);
        k8[i] = ((ull)bbits << 32) | (unsigned int)idx;
    }
    for (int sel = 0; sel < KNN_K; ++sel) {
        ull m = k8[0];
        #pragma unroll
        for (int i = 1; i < 8; ++i) m = (k8[i] < m) ? k8[i] : m;
        #pragma unroll
        for (int mask = 1; mask < 64; mask <<= 1) {
            ull o = shfl_xor_u64(m, mask);
            m = (o < m) ? o : m;
        }
        const int widx = (int)(unsigned int)m;
        if ((widx & 63) == lane) k8[(widx >> 6) & 7] = ~0ull;
        if (lane == 0) cand[wv * KNN_K + sel] = m;
    }
    __syncthreads();
    if (wv == 0) {
        ull key = cand[lane];
        for (int sel = 0; sel < KNN_K; ++sel) {
            ull m = key;
            #pragma unroll
            for (int mask = 1; mask < 64; mask <<= 1) {
                ull o = shfl_xor_u64(m, mask);
                m = (o < m) ? o : m;
            }
            if (lane == 0) {
                orow[sel] = (int)(unsigned int)m;
                vrow[sel] = __uint_as_float((unsigned int)(m >> 32));
            }
            if (key == m) key = ~0ull;
        }
    }
}

// ---------------- fused attention: stat elimination + 16-lane groups ----------------
__global__ void attn_kernel(const void* __restrict__ pos,
                            const hb* __restrict__ qkvB, const int* __restrict__ idxb,
                            const float* __restrict__ argvb,
                            const float* __restrict__ p2, const float* __restrict__ spos,
                            const void* __restrict__ cp,
                            const void* __restrict__ geo_s, const void* __restrict__ geo_b,
                            const void* __restrict__ a_sc, const void* __restrict__ f_sc,
                            hb* __restrict__ attnO, const int* __restrict__ fl) {
    const int fm = *fl;
    const int row = blockIdx.x;
    const int bb = row >> 11;
    const int tid = threadIdx.x, lane = tid & 63, wv = tid >> 6;
    const int l16 = lane & 15, grp = lane >> 4;
    const int kk = wv * 4 + grp;
    __shared__ float qgsL[DDIM], qL[DDIM];
    __shared__ float sc_s[KNN_K], wgt_s[KNN_K];
    __shared__ int nid_s[KNN_K];
    __shared__ float red3[12];

    const float c = ld_scalar(cp, fm);
    const float cs = fmaxf(c, 1e-20f);
    const float sc_c = sqrtf(fmaxf(c, 0.f));

    float qq = 0.f, qgs_sum = 0.f, qgb = 0.f;
    {
        const int d0 = tid * 2;
        float qp0 = ldin(pos, (size_t)row * DDIM + d0, fm);
        float qp1 = ldin(pos, (size_t)row * DDIM + d0 + 1, fm);
        float q0 = b2f(qkvB[(size_t)row * 1536 + d0]);
        float q1 = b2f(qkvB[(size_t)row * 1536 + d0 + 1]);
        float gs0 = ldin(geo_s, d0, fm), gs1 = ldin(geo_s, d0 + 1, fm);
        float gb0 = ldin(geo_b, d0, fm), gb1 = ldin(geo_b, d0 + 1, fm);
        float a0 = q0 * gs0, a1 = q1 * gs1;
        qgsL[d0] = a0; qgsL[d0 + 1] = a1;
        qL[d0] = q0; qL[d0 + 1] = q1;
        qq = a0 * qp0 + a1 * qp1;
        qgs_sum = a0 + a1;
        qgb = q0 * gb0 + q1 * gb1;
    }
    if (tid < KNN_K) nid_s[tid] = idxb[row * KNN_K + tid];
    #pragma unroll
    for (int off = 32; off; off >>= 1) {
        qq += __shfl_down(qq, off);
        qgs_sum += __shfl_down(qgs_sum, off);
        qgb += __shfl_down(qgb, off);
    }
    if (lane == 0) { red3[wv] = qq; red3[4 + wv] = qgs_sum; red3[8 + wv] = qgb; }
    __syncthreads();
    const float QQ  = red3[0] + red3[1] + red3[2] + red3[3];
    const float QGS = red3[4] + red3[5] + red3[6] + red3[7];
    const float QGB = red3[8] + red3[9] + red3[10] + red3[11];

    const int j = nid_s[kk];
    const size_t nro = (size_t)(bb * NTOK + j) * DDIM;
    const size_t nrk = (size_t)(bb * NTOK + j) * 1536 + 512;
    float qk = 0.f, feat = 0.f;
    if (fm) {
        #pragma unroll
        for (int i = 0; i < 8; ++i) {
            const int d = l16 * 4 + i * 64;
            f4v kp = *(const f4v*)((const float*)pos + nro + d);
            f4v qg = *(const f4v*)(qgsL + d);
            qk += qg[0] * kp[0] + qg[1] * kp[1] + qg[2] * kp[2] + qg[3] * kp[3];
        }
    } else {
        #pragma unroll
        for (int i = 0; i < 8; ++i) {
            const int d = l16 * 4 + i * 64;
            s4v kp4 = *(const s4v*)((const hb*)pos + nro + d);
            f4v qg = *(const f4v*)(qgsL + d);
            #pragma unroll
            for (int e = 0; e < 4; ++e) qk += qg[e] * bits2f(kp4[e]);
        }
    }
    #pragma unroll
    for (int i = 0; i < 4; ++i) {
        const int d = l16 * 8 + i * 128;
        s8v kv = *(const s8v*)(qkvB + nrk + d);
        f4v q0 = *(const f4v*)(qL + d);
        f4v q1 = *(const f4v*)(qL + d + 4);
        #pragma unroll
        for (int e = 0; e < 4; ++e)
            feat += q0[e] * bits2f(kv[e]) + q1[e] * bits2f(kv[e + 4]);
    }
    #pragma unroll
    for (int off = 8; off; off >>= 1) {
        qk += __shfl_down(qk, off, 16);
        feat += __shfl_down(feat, off, 16);
    }
    if (l16 == 0) {
        const float p2i = p2[row], p2j = p2[bb * NTOK + j];
        const float sposi = spos[row], sposj = spos[bb * NTOK + j];
        const float argv = argvb[row * KNN_K + kk];
        const float den_d = fmaxf((1.f - c * p2i) * (1.f - c * p2j), 1e-8f);
        const float diff = (argv - 1.f) * den_d / (2.f * cs);
        const float xy = 0.5f * (p2i + p2j - diff);
        const float x2 = p2i, y2 = p2j;
        const float Af = 1.f - 2.f * c * xy + c * y2;
        const float Bf = 1.f - c * x2;
        float den = fmaxf(1.f - 2.f * c * xy + c * c * x2 * y2, 1e-8f);
        const float rden = 1.f / den;
        float n2 = fmaxf(Af * Af * x2 - 2.f * Af * Bf * xy + Bf * Bf * y2, 0.f) * rden * rden;
        const float ynorm = fmaxf(sqrtf(n2), 1e-8f);
        const float t_over = sc_c * ynorm;
        const float targ = fminf(t_over, 1.f - 1e-7f);
        const float scale = (targ > 0.f) ? (atanhf(targ) / t_over) : 1.f;
        const float S1 = scale * rden * (Bf * sposj - Af * sposi);
        const float mean = S1 * (1.f / DDIM);
        const float sq = scale * scale * n2;
        const float var = sq * (1.f / DDIM) - mean * mean;
        const float rstd = rsqrtf(fmaxf(var, 0.f) + 1e-6f);
        const float G = scale * rden * (Bf * qk - Af * QQ);
        const float align = rstd * (G - mean * QGS) + QGB;
        sc_s[kk] = ld_scalar(f_sc, fm) * feat + ld_scalar(a_sc, fm) * align;
    }
    __syncthreads();
    if (tid < 16) {
        float v = sc_s[tid];
        float mx = v;
        #pragma unroll
        for (int off = 8; off; off >>= 1) mx = fmaxf(mx, __shfl_xor(mx, off, 16));
        float e = expf(v - mx);
        float s = e;
        #pragma unroll
        for (int off = 8; off; off >>= 1) s += __shfl_xor(s, off, 16);
        wgt_s[tid] = e / s;
    }
    __syncthreads();
    {
        const int d0 = tid * 2;
        float acc0 = 0.f, acc1 = 0.f;
        #pragma unroll
        for (int t = 0; t < KNN_K; ++t) {
            const hb* vp = qkvB + (size_t)(bb * NTOK + nid_s[t]) * 1536 + 1024 + d0;
            float w = wgt_s[t];
            acc0 += w * b2f(vp[0]);
            acc1 += w * b2f(vp[1]);
        }
        attnO[(size_t)row * DDIM + d0]     = __float2bfloat16(acc0);
        attnO[(size_t)row * DDIM + d0 + 1] = __float2bfloat16(acc1);
    }
}

extern "C" void kernel_launch(void* const* d_in, const int* in_sizes, int n_in,
                              void* d_out, int out_size, void* d_ws, size_t ws_size,
                              hipStream_t stream) {
    const void* x    = d_in[0];
    const void* posb = d_in[1];
    const void* cb   = d_in[2];
    const void* Wq   = d_in[3];
    const void* bq   = d_in[4];
    const void* Wk   = d_in[5];
    const void* bk   = d_in[6];
    const void* Wv   = d_in[7];
    const void* bv   = d_in[8];
    const void* Wo   = d_in[9];
    const void* bo   = d_in[10];
    const void* W1   = d_in[11];
    const void* b1   = d_in[12];
    const void* W2   = d_in[13];
    const void* b2   = d_in[14];
    const void* ln1s = d_in[15];
    const void* ln1b = d_in[16];
    const void* ln2s = d_in[17];
    const void* ln2b = d_in[18];
    const void* geos = d_in[19];
    const void* geob = d_in[20];
    const void* asc  = d_in[21];
    const void* fsc  = d_in[22];

    float* wsf = (float*)d_ws;
    int* flag = (int*)wsf;
    size_t off = 16;
    hb* xnB   = (hb*)(wsf + off); off += 1048576;   // 4096x512 bf16; later hbuf (LN2 out)
    hb* qkvB  = (hb*)(wsf + off); off += 3145728;   // 4096x1536 bf16
    float* p2 = wsf + off;        off += 4096;
    float* spos = wsf + off;      off += 4096;
    int* idxb = (int*)(wsf + off); off += 65536;
    float* argvb = wsf + off;     off += 65536;
    float* x1 = wsf + off;        off += 2097152;   // f32 4096x512
    float* argb = wsf + off;                         // 2 x NTOK^2 f32
    hb* hh    = (hb*)argb;        off += 8388608;   // hh overlays argb (dead by FFN)
    hb* ph    = (hb*)(wsf + off); off += 1048576;   // later attnO
    hb* pl    = (hb*)(wsf + off); off += 1048576;   // later W1T+W2T
    hb* WqkvT = (hb*)(wsf + off); off += 393216;    // 1536x512 bf16
    hb* WoT   = (hb*)(wsf + off); off += 131072;    // 512x512 bf16
    hb* attnO = ph;
    hb* W1T   = pl;                                  // 2048x512 bf16
    hb* W2T   = pl + 1048576;                        // 512x2048 bf16
    hb* hbuf  = xnB;

    // 0. dtype detection
    detect_kernel<<<1, 64, 0, stream>>>(x, flag);
    // attention weight transposes
    transposeA<<<1024, 256, 0, stream>>>(Wq, Wk, Wv, Wo, WqkvT, WoT, flag);
    // prep: pos split + p2 + spos + LN1
    prep_kernel<<<ROWS, 256, 0, stream>>>(posb, x, ln1s, ln1b, ph, pl, p2, spos, xnB, flag);
    // qkv GEMM
    gemm_bt<0, 128, 64><<<dim3(12, 32), 256, 0, stream>>>(xnB, WqkvT, bq, bk, bv, nullptr, qkvB,
                                                          1536, 512, 512, 512, 1536, flag);
    // distances (symmetric fused hi/lo, both batches) + top-16 (both batches)
    dist_mfma<<<dim3(136, 1, 2), 256, 0, stream>>>(ph, pl, p2, cb, argb, flag);
    topk_kernel<<<ROWS, 256, 0, stream>>>(argb, idxb, argvb);
    // FFN weight transposes (pl dead after dist)
    transposeB<<<2048, 256, 0, stream>>>(W1, W2, W1T, W2T, flag);
    // fused geometric attention (overlays ph)
    attn_kernel<<<ROWS, 256, 0, stream>>>(posb, qkvB, idxb, argvb, p2, spos, cb,
                                          geos, geob, asc, fsc, attnO, flag);
    // x1 = x + attn @ Wo + bo  (f32)
    gemm_bt<1, 64, 64><<<dim3(8, 32), 256, 0, stream>>>(attnO, WoT, bo, nullptr, nullptr, x, x1,
                                                        512, 512, 512, 512, 512, flag);
    // LN2 -> bf16
    ln_kernel<<<ROWS, 256, 0, stream>>>(x1, ln2s, ln2b, hbuf, flag);
    // hh = gelu(h @ W1 + b1) -> bf16
    gemm_bt<2, 128, 64><<<dim3(16, 32), 256, 0, stream>>>(hbuf, W1T, b1, nullptr, nullptr, nullptr, hh,
                                                          2048, 512, 512, 512, 2048, flag);
    // out = x1 + hh @ W2 + b2
    gemm_bt<3, 64, 64><<<dim3(8, 32), 256, 0, stream>>>(hh, W2T, b2, nullptr, nullptr, x1, d_out,
                                                        512, 2048, 2048, 2048, 512, flag);

    (void)in_sizes; (void)n_in; (void)out_size; (void)ws_size;
}

// Round 11
// 329.973 us; speedup vs baseline: 3.0788x; 1.0433x over previous
//
#include <hip/hip_runtime.h>
#include <hip/hip_bf16.h>
#include <math.h>

#define NTOK 2048      // N
#define DDIM 512       // D
#define FDIM 2048      // F
#define KNN_K 16
#define ROWS 4096      // B*N

typedef __hip_bfloat16 hb;
typedef unsigned long long ull;
typedef short s8v __attribute__((ext_vector_type(8)));
typedef short s4v __attribute__((ext_vector_type(4)));
typedef float f4v __attribute__((ext_vector_type(4)));

__device__ __forceinline__ float b2f(hb h) { return __bfloat162float(h); }
__device__ __forceinline__ float bits2f(short s) {
    return __uint_as_float(((unsigned int)(unsigned short)s) << 16);
}

__device__ __forceinline__ float ldin(const void* p, size_t i, int f32m) {
    return f32m ? ((const float*)p)[i] : b2f(((const hb*)p)[i]);
}
__device__ __forceinline__ float ld_scalar(const void* p, int f32m) {
    return f32m ? *(const float*)p : b2f(*(const hb*)p);
}

__device__ __forceinline__ ull shfl_xor_u64(ull x, int mask) {
    unsigned lo = (unsigned)x, hi = (unsigned)(x >> 32);
    lo = __shfl_xor(lo, mask); hi = __shfl_xor(hi, mask);
    return ((ull)hi << 32) | lo;
}

__device__ __forceinline__ float gelu_f(float x) {
    float x3 = x * x * x;
    return 0.5f * x * (1.f + tanhf(0.7978845608028654f * (x + 0.044715f * x3)));
}

// ---------------- dtype detector ----------------
__global__ void detect_kernel(const void* __restrict__ x, int* __restrict__ flag) {
    const unsigned short* u = (const unsigned short*)x;
    int tid = threadIdx.x;
    int bad = 0;
    #pragma unroll
    for (int t = 0; t < 16; ++t) {
        unsigned short h = u[tid * 16 + t];
        int e = (h >> 7) & 0xFF;
        if (e == 0xFF) bad++;
        else if (e >= 0x8E) bad++;
        else if (e != 0 && e <= 0x66) bad++;
    }
    #pragma unroll
    for (int off = 32; off; off >>= 1) bad += __shfl_down(bad, off);
    if (tid == 0) *flag = (bad > 100) ? 1 : 0;
}

// ---------------- transpose tile body ----------------
__device__ __forceinline__ void tr_tile(const void* src, hb* dst, int K, int N,
                                        int k0, int n0, int fm) {
    __shared__ float t[32][33];
    const int tx = threadIdx.x & 31, ty = threadIdx.x >> 5;   // 32 x 8
    #pragma unroll
    for (int r = 0; r < 32; r += 8)
        t[ty + r][tx] = ldin(src, (size_t)(k0 + ty + r) * N + n0 + tx, fm);
    __syncthreads();
    #pragma unroll
    for (int r = 0; r < 32; r += 8)
        dst[(size_t)(n0 + ty + r) * K + k0 + tx] = __float2bfloat16(t[tx][ty + r]);
}

__global__ void transposeA(const void* __restrict__ Wq, const void* __restrict__ Wk,
                           const void* __restrict__ Wv, const void* __restrict__ Wo,
                           hb* __restrict__ WqkvT, hb* __restrict__ WoT,
                           const int* __restrict__ fl) {
    const int fm = *fl;
    const int bx = blockIdx.x;              // 0..1023
    const int seg = bx >> 8, t = bx & 255;
    const int n0 = (t & 15) * 32, k0 = (t >> 4) * 32;
    const void* src = (seg == 0) ? Wq : (seg == 1) ? Wk : (seg == 2) ? Wv : Wo;
    hb* dst = (seg == 3) ? WoT : (WqkvT + (size_t)seg * 512 * 512);
    tr_tile(src, dst, 512, 512, k0, n0, fm);
}

__global__ void transposeB(const void* __restrict__ W1, const void* __restrict__ W2,
                           hb* __restrict__ W1T, hb* __restrict__ W2T,
                           const int* __restrict__ fl) {
    const int fm = *fl;
    const int bx = blockIdx.x;              // 0..2047
    if (bx < 1024) {
        const int n0 = (bx & 63) * 32, k0 = (bx >> 6) * 32;
        tr_tile(W1, W1T, 512, 2048, k0, n0, fm);
    } else {
        const int b2 = bx - 1024;
        const int n0 = (b2 & 15) * 32, k0 = (b2 >> 4) * 32;
        tr_tile(W2, W2T, 2048, 512, k0, n0, fm);
    }
}

// ---------------- prep: pos hi/lo split + p2 + spos + LN1 (fused) ----------------
__global__ void prep_kernel(const void* __restrict__ pos, const void* __restrict__ x,
                            const void* __restrict__ s, const void* __restrict__ b,
                            hb* __restrict__ ph, hb* __restrict__ pl,
                            float* __restrict__ p2, float* __restrict__ spos,
                            hb* __restrict__ xnB, const int* __restrict__ fl) {
    const int fm = *fl;
    const int row = blockIdx.x, tid = threadIdx.x;
    float s2 = 0.f, s1 = 0.f;
    #pragma unroll
    for (int t = 0; t < 2; ++t) {
        size_t i = (size_t)row * DDIM + tid + 256 * t;
        float v = ldin(pos, i, fm);
        hb h = __float2bfloat16(v);
        ph[i] = h;
        pl[i] = __float2bfloat16(v - b2f(h));
        s2 += v * v; s1 += v;
    }
    float v0 = ldin(x, (size_t)row * DDIM + tid, fm);
    float v1 = ldin(x, (size_t)row * DDIM + tid + 256, fm);
    float sum = v0 + v1, sq = v0 * v0 + v1 * v1;
    const int lane = tid & 63, wv = tid >> 6;
    #pragma unroll
    for (int off = 32; off; off >>= 1) {
        s2 += __shfl_down(s2, off); s1 += __shfl_down(s1, off);
        sum += __shfl_down(sum, off); sq += __shfl_down(sq, off);
    }
    __shared__ float ls[16];
    if (lane == 0) { ls[wv] = s2; ls[4 + wv] = s1; ls[8 + wv] = sum; ls[12 + wv] = sq; }
    __syncthreads();
    if (tid == 0) {
        p2[row]   = ls[0] + ls[1] + ls[2] + ls[3];
        spos[row] = ls[4] + ls[5] + ls[6] + ls[7];
    }
    float ts = ls[8] + ls[9] + ls[10] + ls[11];
    float tq = ls[12] + ls[13] + ls[14] + ls[15];
    float mean = ts * (1.f / DDIM);
    float var = tq * (1.f / DDIM) - mean * mean;
    float rstd = rsqrtf(var + 1e-6f);
    xnB[(size_t)row * DDIM + tid]       = __float2bfloat16(ldin(s, tid, fm) * (v0 - mean) * rstd + ldin(b, tid, fm));
    xnB[(size_t)row * DDIM + tid + 256] = __float2bfloat16(ldin(s, tid + 256, fm) * (v1 - mean) * rstd + ldin(b, tid + 256, fm));
}

// ---------------- LayerNorm (internal f32 in) ----------------
__global__ void ln_kernel(const float* __restrict__ xin,
                          const void* __restrict__ s, const void* __restrict__ b,
                          hb* __restrict__ y, const int* __restrict__ fl) {
    const int m = *fl;
    const int row = blockIdx.x, tid = threadIdx.x;
    const float* xp = xin + (size_t)row * DDIM;
    float v0 = xp[tid], v1 = xp[tid + 256];
    float sum = v0 + v1, sq = v0 * v0 + v1 * v1;
    const int lane = tid & 63, wv = tid >> 6;
    #pragma unroll
    for (int off = 32; off; off >>= 1) { sum += __shfl_down(sum, off); sq += __shfl_down(sq, off); }
    __shared__ float ls[8];
    if (lane == 0) { ls[wv] = sum; ls[4 + wv] = sq; }
    __syncthreads();
    float ts = ls[0] + ls[1] + ls[2] + ls[3];
    float tq = ls[4] + ls[5] + ls[6] + ls[7];
    float mean = ts * (1.f / DDIM);
    float var = tq * (1.f / DDIM) - mean * mean;
    float rstd = rsqrtf(var + 1e-6f);
    y[(size_t)row * DDIM + tid]       = __float2bfloat16(ldin(s, tid, m) * (v0 - mean) * rstd + ldin(b, tid, m));
    y[(size_t)row * DDIM + tid + 256] = __float2bfloat16(ldin(s, tid + 256, m) * (v1 - mean) * rstd + ldin(b, tid + 256, m));
}

// ================ pipelined MFMA GEMM ================
template<int EPI, int TN, int BK>
__global__ __launch_bounds__(256, 2)
void gemm_bt(const hb* __restrict__ A, const hb* __restrict__ Bt,
             const void* __restrict__ bp0, const void* __restrict__ bp1, const void* __restrict__ bp2,
             const void* __restrict__ res, void* __restrict__ C,
             int N, int K, int lda, int ldb, int ldc,
             const int* __restrict__ fl) {
    constexpr int WY = (TN == 128) ? 2 : 4;
    constexpr int WX = (TN == 128) ? 2 : 1;
    constexpr int FI = 128 / WY / 16;
    constexpr int FJ = TN / WX / 16;
    constexpr int NA = 128 * BK / (256 * 8);
    constexpr int NB = TN * BK / (256 * 8);
    constexpr int LDSW = BK + 8;
    const int fm = *fl;
    __shared__ short As[128 * LDSW];
    __shared__ short Bs[TN * LDSW];
    const int tid = threadIdx.x, lane = tid & 63, wave = tid >> 6;
    const int wy = (TN == 128) ? (wave >> 1) : wave;
    const int wx = (TN == 128) ? (wave & 1) : 0;
    const int m0 = blockIdx.y * 128, n0 = blockIdx.x * TN;
    const int r0 = tid >> 3, c0 = (tid & 7) * 8;
    const int lm = lane & 15, lk = (lane >> 4) * 8;
    f4v acc[FI][FJ];
    #pragma unroll
    for (int i = 0; i < FI; ++i)
        #pragma unroll
        for (int j = 0; j < FJ; ++j) acc[i][j] = (f4v){0.f, 0.f, 0.f, 0.f};

    s8v an[NA], bn[NB];
    #pragma unroll
    for (int g = 0; g < NA; ++g) an[g] = *(const s8v*)(A + (size_t)(m0 + r0 + 32 * g) * lda + c0);
    #pragma unroll
    for (int g = 0; g < NB; ++g) bn[g] = *(const s8v*)(Bt + (size_t)(n0 + r0 + 32 * g) * ldb + c0);

    for (int k0 = 0; k0 < K; k0 += BK) {
        __syncthreads();
        #pragma unroll
        for (int g = 0; g < NA; ++g) *(s8v*)(As + (r0 + 32 * g) * LDSW + c0) = an[g];
        #pragma unroll
        for (int g = 0; g < NB; ++g) *(s8v*)(Bs + (r0 + 32 * g) * LDSW + c0) = bn[g];
        if (k0 + BK < K) {
            const int kn = k0 + BK;
            #pragma unroll
            for (int g = 0; g < NA; ++g) an[g] = *(const s8v*)(A + (size_t)(m0 + r0 + 32 * g) * lda + kn + c0);
            #pragma unroll
            for (int g = 0; g < NB; ++g) bn[g] = *(const s8v*)(Bt + (size_t)(n0 + r0 + 32 * g) * ldb + kn + c0);
        }
        __syncthreads();
        #pragma unroll
        for (int kc = 0; kc < BK; kc += 32) {
            s8v af[FI], bf[FJ];
            #pragma unroll
            for (int f = 0; f < FI; ++f)
                af[f] = *(const s8v*)(As + (wy * (128 / WY) + f * 16 + lm) * LDSW + kc + lk);
            #pragma unroll
            for (int f = 0; f < FJ; ++f)
                bf[f] = *(const s8v*)(Bs + (wx * (TN / WX) + f * 16 + lm) * LDSW + kc + lk);
            #pragma unroll
            for (int fi = 0; fi < FI; ++fi)
                #pragma unroll
                for (int fj = 0; fj < FJ; ++fj)
                    acc[fi][fj] = __builtin_amdgcn_mfma_f32_16x16x32_bf16(af[fi], bf[fj], acc[fi][fj], 0, 0, 0);
        }
    }

    const int embase = m0 + wy * (128 / WY) + (lane >> 4) * 4;
    const int enbase = n0 + wx * (TN / WX) + lm;
    #pragma unroll
    for (int fi = 0; fi < FI; ++fi) {
        #pragma unroll
        for (int fj = 0; fj < FJ; ++fj) {
            const int n = enbase + fj * 16;
            #pragma unroll
            for (int r = 0; r < 4; ++r) {
                const int m = embase + fi * 16 + r;
                float val = acc[fi][fj][r];
                size_t ci = (size_t)m * ldc + n;
                if (EPI == 0) {
                    const void* bp = (n < 512) ? bp0 : ((n < 1024) ? bp1 : bp2);
                    val += ldin(bp, n & 511, fm);
                    ((hb*)C)[ci] = __float2bfloat16(val);
                } else if (EPI == 1) {
                    val += ldin(bp0, n, fm) + ldin(res, (size_t)m * 512 + n, fm);
                    ((float*)C)[ci] = val;
                } else if (EPI == 2) {
                    val = gelu_f(val + ldin(bp0, n, fm));
                    ((hb*)C)[ci] = __float2bfloat16(val);
                } else {
                    val += ldin(bp0, n, fm) + ((const float*)res)[(size_t)m * 512 + n];
                    if (fm) ((float*)C)[ci] = val;
                    else ((hb*)C)[ci] = __float2bfloat16(val);
                }
            }
        }
    }
}

// ================ dist v3: fused hi/lo (2 accumulators), triangular, LDS-transposed mirror ================
__global__ __launch_bounds__(256, 2)
void dist_mfma(const hb* __restrict__ ph, const hb* __restrict__ pl,
               const float* __restrict__ p2, const void* __restrict__ cp,
               float* __restrict__ argb, const int* __restrict__ fl) {
    constexpr int BK = 32, LDSW = BK + 8;       // 40 shorts/row per staged tile
    constexpr int KI = DDIM / BK;               // 16 k-iterations
    constexpr int TSH = 128 * LDSW;             // shorts per tile (5120)
    __shared__ float Tm[128 * 132];             // 67584 B: mirror scratch; aliased for staging
    short* Sb = (short*)Tm;                     // 4 tiles at Sb + t*TSH (40960 B total)

    const int fm = *fl;
    const float c = ld_scalar(cp, fm);
    const int bb = blockIdx.z;
    const float* p2b = p2 + bb * NTOK;
    const size_t rb = (size_t)bb * NTOK;
    float* out = argb + (size_t)bb * NTOK * NTOK;
    // triangular block index -> (bi, bj), bi <= bj
    int t = blockIdx.x, bi = 0, rem = 16;
    while (t >= rem) { t -= rem; bi++; rem = 16 - bi; }
    const int bj = bi + t;
    const int i0 = bi * 128, j0 = bj * 128;
    const bool diag = (bi == bj);

    const int tid = threadIdx.x, lane = tid & 63, wave = tid >> 6;
    const int wy = wave >> 1, wx = wave & 1;
    const int r0 = tid >> 2, c0 = (tid & 3) * 8;      // 64 rows x 32 cols per pass, 2 passes
    const int lm = lane & 15, lk = (lane >> 4) * 8;

    const hb* src[4] = { ph + (rb + i0) * DDIM, pl + (rb + i0) * DDIM,
                         ph + (rb + j0) * DDIM, pl + (rb + j0) * DDIM };

    f4v acc_hh[4][4], acc_x[4][4];
    #pragma unroll
    for (int i = 0; i < 4; ++i)
        #pragma unroll
        for (int j = 0; j < 4; ++j) { acc_hh[i][j] = (f4v){0.f,0.f,0.f,0.f}; acc_x[i][j] = (f4v){0.f,0.f,0.f,0.f}; }

    s8v pf[4][2];
    #pragma unroll
    for (int tt = 0; tt < 4; ++tt)
        #pragma unroll
        for (int g = 0; g < 2; ++g)
            pf[tt][g] = *(const s8v*)(src[tt] + (size_t)(r0 + 64 * g) * DDIM + c0);

    for (int it = 0; it < KI; ++it) {
        __syncthreads();
        #pragma unroll
        for (int tt = 0; tt < 4; ++tt)
            #pragma unroll
            for (int g = 0; g < 2; ++g)
                *(s8v*)(Sb + tt * TSH + (r0 + 64 * g) * LDSW + c0) = pf[tt][g];
        if (it + 1 < KI) {
            const int kn = (it + 1) * BK;
            #pragma unroll
            for (int tt = 0; tt < 4; ++tt)
                #pragma unroll
                for (int g = 0; g < 2; ++g)
                    pf[tt][g] = *(const s8v*)(src[tt] + (size_t)(r0 + 64 * g) * DDIM + kn + c0);
        }
        __syncthreads();
        s8v ah[4], al[4], bh[4], bl[4];
        #pragma unroll
        for (int f = 0; f < 4; ++f) {
            ah[f] = *(const s8v*)(Sb + 0 * TSH + (wy * 64 + f * 16 + lm) * LDSW + lk);
            al[f] = *(const s8v*)(Sb + 1 * TSH + (wy * 64 + f * 16 + lm) * LDSW + lk);
            bh[f] = *(const s8v*)(Sb + 2 * TSH + (wx * 64 + f * 16 + lm) * LDSW + lk);
            bl[f] = *(const s8v*)(Sb + 3 * TSH + (wx * 64 + f * 16 + lm) * LDSW + lk);
        }
        #pragma unroll
        for (int fi = 0; fi < 4; ++fi)
            #pragma unroll
            for (int fj = 0; fj < 4; ++fj) {
                acc_hh[fi][fj] = __builtin_amdgcn_mfma_f32_16x16x32_bf16(ah[fi], bh[fj], acc_hh[fi][fj], 0, 0, 0);
                acc_x[fi][fj]  = __builtin_amdgcn_mfma_f32_16x16x32_bf16(ah[fi], bl[fj], acc_x[fi][fj], 0, 0, 0);
                acc_x[fi][fj]  = __builtin_amdgcn_mfma_f32_16x16x32_bf16(al[fi], bh[fj], acc_x[fi][fj], 0, 0, 0);
            }
    }

    __syncthreads();            // staging dead; Tm reused as mirror scratch
    const int eibase = i0 + wy * 64 + (lane >> 4) * 4;
    const int ejbase = j0 + wx * 64 + lm;
    #pragma unroll
    for (int fi = 0; fi < 4; ++fi) {
        #pragma unroll
        for (int fj = 0; fj < 4; ++fj) {
            const int jj = ejbase + fj * 16;
            const float p2j = p2b[jj];
            #pragma unroll
            for (int r = 0; r < 4; ++r) {
                const int ii = eibase + fi * 16 + r;
                const float p2i = p2b[ii];
                const float xy = acc_hh[fi][fj][r] + acc_x[fi][fj][r];
                float diff = fmaxf(p2i + p2j - 2.f * xy, 0.f);
                float den = fmaxf((1.f - c * p2i) * (1.f - c * p2j), 1e-8f);
                float argv = 1.f + 2.f * c * diff / den;
                out[(size_t)ii * NTOK + jj] = argv;
                if (!diag) Tm[(jj - j0) * 132 + (ii - i0)] = argv;
            }
        }
    }
    if (!diag) {
        __syncthreads();
        #pragma unroll
        for (int k = 0; k < 16; ++k) {
            const int lin = k * 256 + tid;      // f4v units, 4096 total
            const int rowT = lin >> 5;          // 32 f4v per 128-col row
            const int c4 = (lin & 31) * 4;
            f4v v = *(const f4v*)(Tm + rowT * 132 + c4);
            *(f4v*)(out + (size_t)(j0 + rowT) * NTOK + i0 + c4) = v;
        }
    }
}

// ---------------- top-16 v4: one wave per row, 32 keys/lane, no merge ----------------
__global__ void topk_kernel(const float* __restrict__ argb, int* __restrict__ idxb,
                            float* __restrict__ argvb) {
    const int row = blockIdx.x * 4 + (threadIdx.x >> 6);     // 0..4095
    const int bb = row >> 11, r = row & (NTOK - 1);
    const float* arow = argb + (size_t)bb * NTOK * NTOK + (size_t)r * NTOK;
    const int lane = threadIdx.x & 63;
    // load 32 keys per lane: idx = lane*4 + e + 256*i  (16B/lane coalesced)
    ull k[32];
    #pragma unroll
    for (int i = 0; i < 8; ++i) {
        f4v v = *(const f4v*)(arow + lane * 4 + i * 256);
        #pragma unroll
        for (int e = 0; e < 4; ++e) {
            const unsigned idx = lane * 4 + e + i * 256;
            k[i * 4 + e] = ((ull)__float_as_uint(v[e]) << 32) | idx;
        }
    }
    ull res = ~0ull;
    for (int sel = 0; sel < KNN_K; ++sel) {
        // tree min over 32 regs
        ull t16[16];
        #pragma unroll
        for (int i = 0; i < 16; ++i) t16[i] = (k[2 * i] < k[2 * i + 1]) ? k[2 * i] : k[2 * i + 1];
        #pragma unroll
        for (int i = 0; i < 8; ++i) t16[i] = (t16[2 * i] < t16[2 * i + 1]) ? t16[2 * i] : t16[2 * i + 1];
        #pragma unroll
        for (int i = 0; i < 4; ++i) t16[i] = (t16[2 * i] < t16[2 * i + 1]) ? t16[2 * i] : t16[2 * i + 1];
        ull m01 = (t16[0] < t16[1]) ? t16[0] : t16[1];
        ull m23 = (t16[2] < t16[3]) ? t16[2] : t16[3];
        ull m = (m01 < m23) ? m01 : m23;
        // wave butterfly
        #pragma unroll
        for (int mask = 1; mask < 64; mask <<= 1) {
            ull o = shfl_xor_u64(m, mask);
            m = (o < m) ? o : m;
        }
        // m is wave-uniform: invalidate owner reg (uniform reg id -> scalar branch)
        const unsigned widx = (unsigned)m;
        const int regid = (int)(((widx >> 8) << 2) | (widx & 3));
        const bool mine = (int)((widx >> 2) & 63) == lane;
        #pragma unroll
        for (int rr = 0; rr < 32; ++rr)
            if (rr == regid && mine) k[rr] = ~0ull;
        if (lane == sel) res = m;
    }
    if (lane < KNN_K) {
        idxb[(size_t)row * KNN_K + lane] = (int)(unsigned)res;
        argvb[(size_t)row * KNN_K + lane] = __uint_as_float((unsigned)(res >> 32));
    }
}

// ---------------- fused attention: stat elimination + 16-lane groups ----------------
__global__ void attn_kernel(const void* __restrict__ pos,
                            const hb* __restrict__ qkvB, const int* __restrict__ idxb,
                            const float* __restrict__ argvb,
                            const float* __restrict__ p2, const float* __restrict__ spos,
                            const void* __restrict__ cp,
                            const void* __restrict__ geo_s, const void* __restrict__ geo_b,
                            const void* __restrict__ a_sc, const void* __restrict__ f_sc,
                            hb* __restrict__ attnO, const int* __restrict__ fl) {
    const int fm = *fl;
    const int row = blockIdx.x;
    const int bb = row >> 11;
    const int tid = threadIdx.x, lane = tid & 63, wv = tid >> 6;
    const int l16 = lane & 15, grp = lane >> 4;
    const int kk = wv * 4 + grp;
    __shared__ float qgsL[DDIM], qL[DDIM];
    __shared__ float sc_s[KNN_K], wgt_s[KNN_K];
    __shared__ int nid_s[KNN_K];
    __shared__ float red3[12];

    const float c = ld_scalar(cp, fm);
    const float cs = fmaxf(c, 1e-20f);
    const float sc_c = sqrtf(fmaxf(c, 0.f));

    float qq = 0.f, qgs_sum = 0.f, qgb = 0.f;
    {
        const int d0 = tid * 2;
        float qp0 = ldin(pos, (size_t)row * DDIM + d0, fm);
        float qp1 = ldin(pos, (size_t)row * DDIM + d0 + 1, fm);
        float q0 = b2f(qkvB[(size_t)row * 1536 + d0]);
        float q1 = b2f(qkvB[(size_t)row * 1536 + d0 + 1]);
        float gs0 = ldin(geo_s, d0, fm), gs1 = ldin(geo_s, d0 + 1, fm);
        float gb0 = ldin(geo_b, d0, fm), gb1 = ldin(geo_b, d0 + 1, fm);
        float a0 = q0 * gs0, a1 = q1 * gs1;
        qgsL[d0] = a0; qgsL[d0 + 1] = a1;
        qL[d0] = q0; qL[d0 + 1] = q1;
        qq = a0 * qp0 + a1 * qp1;
        qgs_sum = a0 + a1;
        qgb = q0 * gb0 + q1 * gb1;
    }
    if (tid < KNN_K) nid_s[tid] = idxb[row * KNN_K + tid];
    #pragma unroll
    for (int off = 32; off; off >>= 1) {
        qq += __shfl_down(qq, off);
        qgs_sum += __shfl_down(qgs_sum, off);
        qgb += __shfl_down(qgb, off);
    }
    if (lane == 0) { red3[wv] = qq; red3[4 + wv] = qgs_sum; red3[8 + wv] = qgb; }
    __syncthreads();
    const float QQ  = red3[0] + red3[1] + red3[2] + red3[3];
    const float QGS = red3[4] + red3[5] + red3[6] + red3[7];
    const float QGB = red3[8] + red3[9] + red3[10] + red3[11];

    const int j = nid_s[kk];
    const size_t nro = (size_t)(bb * NTOK + j) * DDIM;
    const size_t nrk = (size_t)(bb * NTOK + j) * 1536 + 512;
    float qk = 0.f, feat = 0.f;
    if (fm) {
        #pragma unroll
        for (int i = 0; i < 8; ++i) {
            const int d = l16 * 4 + i * 64;
            f4v kp = *(const f4v*)((const float*)pos + nro + d);
            f4v qg = *(const f4v*)(qgsL + d);
            qk += qg[0] * kp[0] + qg[1] * kp[1] + qg[2] * kp[2] + qg[3] * kp[3];
        }
    } else {
        #pragma unroll
        for (int i = 0; i < 8; ++i) {
            const int d = l16 * 4 + i * 64;
            s4v kp4 = *(const s4v*)((const hb*)pos + nro + d);
            f4v qg = *(const f4v*)(qgsL + d);
            #pragma unroll
            for (int e = 0; e < 4; ++e) qk += qg[e] * bits2f(kp4[e]);
        }
    }
    #pragma unroll
    for (int i = 0; i < 4; ++i) {
        const int d = l16 * 8 + i * 128;
        s8v kv = *(const s8v*)(qkvB + nrk + d);
        f4v q0 = *(const f4v*)(qL + d);
        f4v q1 = *(const f4v*)(qL + d + 4);
        #pragma unroll
        for (int e = 0; e < 4; ++e)
            feat += q0[e] * bits2f(kv[e]) + q1[e] * bits2f(kv[e + 4]);
    }
    #pragma unroll
    for (int off = 8; off; off >>= 1) {
        qk += __shfl_down(qk, off, 16);
        feat += __shfl_down(feat, off, 16);
    }
    if (l16 == 0) {
        const float p2i = p2[row], p2j = p2[bb * NTOK + j];
        const float sposi = spos[row], sposj = spos[bb * NTOK + j];
        const float argv = argvb[row * KNN_K + kk];
        const float den_d = fmaxf((1.f - c * p2i) * (1.f - c * p2j), 1e-8f);
        const float diff = (argv - 1.f) * den_d / (2.f * cs);
        const float xy = 0.5f * (p2i + p2j - diff);
        const float x2 = p2i, y2 = p2j;
        const float Af = 1.f - 2.f * c * xy + c * y2;
        const float Bf = 1.f - c * x2;
        float den = fmaxf(1.f - 2.f * c * xy + c * c * x2 * y2, 1e-8f);
        const float rden = 1.f / den;
        float n2 = fmaxf(Af * Af * x2 - 2.f * Af * Bf * xy + Bf * Bf * y2, 0.f) * rden * rden;
        const float ynorm = fmaxf(sqrtf(n2), 1e-8f);
        const float t_over = sc_c * ynorm;
        const float targ = fminf(t_over, 1.f - 1e-7f);
        const float scale = (targ > 0.f) ? (atanhf(targ) / t_over) : 1.f;
        const float S1 = scale * rden * (Bf * sposj - Af * sposi);
        const float mean = S1 * (1.f / DDIM);
        const float sq = scale * scale * n2;
        const float var = sq * (1.f / DDIM) - mean * mean;
        const float rstd = rsqrtf(fmaxf(var, 0.f) + 1e-6f);
        const float G = scale * rden * (Bf * qk - Af * QQ);
        const float align = rstd * (G - mean * QGS) + QGB;
        sc_s[kk] = ld_scalar(f_sc, fm) * feat + ld_scalar(a_sc, fm) * align;
    }
    __syncthreads();
    if (tid < 16) {
        float v = sc_s[tid];
        float mx = v;
        #pragma unroll
        for (int off = 8; off; off >>= 1) mx = fmaxf(mx, __shfl_xor(mx, off, 16));
        float e = expf(v - mx);
        float s = e;
        #pragma unroll
        for (int off = 8; off; off >>= 1) s += __shfl_xor(s, off, 16);
        wgt_s[tid] = e / s;
    }
    __syncthreads();
    {
        const int d0 = tid * 2;
        float acc0 = 0.f, acc1 = 0.f;
        #pragma unroll
        for (int t = 0; t < KNN_K; ++t) {
            const hb* vp = qkvB + (size_t)(bb * NTOK + nid_s[t]) * 1536 + 1024 + d0;
            float w = wgt_s[t];
            acc0 += w * b2f(vp[0]);
            acc1 += w * b2f(vp[1]);
        }
        attnO[(size_t)row * DDIM + d0]     = __float2bfloat16(acc0);
        attnO[(size_t)row * DDIM + d0 + 1] = __float2bfloat16(acc1);
    }
}

extern "C" void kernel_launch(void* const* d_in, const int* in_sizes, int n_in,
                              void* d_out, int out_size, void* d_ws, size_t ws_size,
                              hipStream_t stream) {
    const void* x    = d_in[0];
    const void* posb = d_in[1];
    const void* cb   = d_in[2];
    const void* Wq   = d_in[3];
    const void* bq   = d_in[4];
    const void* Wk   = d_in[5];
    const void* bk   = d_in[6];
    const void* Wv   = d_in[7];
    const void* bv   = d_in[8];
    const void* Wo   = d_in[9];
    const void* bo   = d_in[10];
    const void* W1   = d_in[11];
    const void* b1   = d_in[12];
    const void* W2   = d_in[13];
    const void* b2   = d_in[14];
    const void* ln1s = d_in[15];
    const void* ln1b = d_in[16];
    const void* ln2s = d_in[17];
    const void* ln2b = d_in[18];
    const void* geos = d_in[19];
    const void* geob = d_in[20];
    const void* asc  = d_in[21];
    const void* fsc  = d_in[22];

    float* wsf = (float*)d_ws;
    int* flag = (int*)wsf;
    size_t off = 16;
    hb* xnB   = (hb*)(wsf + off); off += 1048576;   // 4096x512 bf16; later hbuf (LN2 out)
    hb* qkvB  = (hb*)(wsf + off); off += 3145728;   // 4096x1536 bf16
    float* p2 = wsf + off;        off += 4096;
    float* spos = wsf + off;      off += 4096;
    int* idxb = (int*)(wsf + off); off += 65536;
    float* argvb = wsf + off;     off += 65536;
    float* x1 = wsf + off;        off += 2097152;   // f32 4096x512
    float* argb = wsf + off;                         // 2 x NTOK^2 f32
    hb* hh    = (hb*)argb;        off += 8388608;   // hh overlays argb (dead by FFN)
    hb* ph    = (hb*)(wsf + off); off += 1048576;   // later attnO
    hb* pl    = (hb*)(wsf + off); off += 1048576;   // later W1T+W2T
    hb* WqkvT = (hb*)(wsf + off); off += 393216;    // 1536x512 bf16
    hb* WoT   = (hb*)(wsf + off); off += 131072;    // 512x512 bf16
    hb* attnO = ph;
    hb* W1T   = pl;                                  // 2048x512 bf16
    hb* W2T   = pl + 1048576;                        // 512x2048 bf16
    hb* hbuf  = xnB;

    // 0. dtype detection
    detect_kernel<<<1, 64, 0, stream>>>(x, flag);
    // attention weight transposes
    transposeA<<<1024, 256, 0, stream>>>(Wq, Wk, Wv, Wo, WqkvT, WoT, flag);
    // prep: pos split + p2 + spos + LN1
    prep_kernel<<<ROWS, 256, 0, stream>>>(posb, x, ln1s, ln1b, ph, pl, p2, spos, xnB, flag);
    // qkv GEMM
    gemm_bt<0, 128, 64><<<dim3(12, 32), 256, 0, stream>>>(xnB, WqkvT, bq, bk, bv, nullptr, qkvB,
                                                          1536, 512, 512, 512, 1536, flag);
    // distances (symmetric fused hi/lo, both batches) + top-16 (1 wave/row)
    dist_mfma<<<dim3(136, 1, 2), 256, 0, stream>>>(ph, pl, p2, cb, argb, flag);
    topk_kernel<<<1024, 256, 0, stream>>>(argb, idxb, argvb);
    // FFN weight transposes (pl dead after dist)
    transposeB<<<2048, 256, 0, stream>>>(W1, W2, W1T, W2T, flag);
    // fused geometric attention (overlays ph)
    attn_kernel<<<ROWS, 256, 0, stream>>>(posb, qkvB, idxb, argvb, p2, spos, cb,
                                          geos, geob, asc, fsc, attnO, flag);
    // x1 = x + attn @ Wo + bo  (f32)
    gemm_bt<1, 64, 64><<<dim3(8, 32), 256, 0, stream>>>(attnO, WoT, bo, nullptr, nullptr, x, x1,
                                                        512, 512, 512, 512, 512, flag);
    // LN2 -> bf16
    ln_kernel<<<ROWS, 256, 0, stream>>>(x1, ln2s, ln2b, hbuf, flag);
    // hh = gelu(h @ W1 + b1) -> bf16
    gemm_bt<2, 128, 64><<<dim3(16, 32), 256, 0, stream>>>(hbuf, W1T, b1, nullptr, nullptr, nullptr, hh,
                                                          2048, 512, 512, 512, 2048, flag);
    // out = x1 + hh @ W2 + b2
    gemm_bt<3, 64, 64><<<dim3(8, 32), 256, 0, stream>>>(hh, W2T, b2, nullptr, nullptr, x1, d_out,
                                                        512, 2048, 2048, 2048, 512, flag);

    (void)in_sizes; (void)n_in; (void)out_size; (void)ws_size;
}

// Round 12
// 325.987 us; speedup vs baseline: 3.1164x; 1.0122x over previous
//
#include <hip/hip_runtime.h>
#include <hip/hip_bf16.h>
#include <math.h>

#define NTOK 2048      // N
#define DDIM 512       // D
#define FDIM 2048      // F
#define KNN_K 16
#define ROWS 4096      // B*N

typedef __hip_bfloat16 hb;
typedef unsigned long long ull;
typedef short s8v __attribute__((ext_vector_type(8)));
typedef short s4v __attribute__((ext_vector_type(4)));
typedef float f4v __attribute__((ext_vector_type(4)));

__device__ __forceinline__ float b2f(hb h) { return __bfloat162float(h); }
__device__ __forceinline__ float bits2f(short s) {
    return __uint_as_float(((unsigned int)(unsigned short)s) << 16);
}

__device__ __forceinline__ float ldin(const void* p, size_t i, int f32m) {
    return f32m ? ((const float*)p)[i] : b2f(((const hb*)p)[i]);
}
__device__ __forceinline__ float ld_scalar(const void* p, int f32m) {
    return f32m ? *(const float*)p : b2f(*(const hb*)p);
}

// wave-uniform inline dtype detection (all lanes read x's first 1024 halves as bf16;
// f32 buffer -> ~435/1024 wild exponents, bf16 -> ~0). Butterfly so every lane agrees.
__device__ __forceinline__ int detect_fm(const void* x) {
    const unsigned short* u = (const unsigned short*)x;
    const int lane = threadIdx.x & 63;
    int bad = 0;
    #pragma unroll
    for (int t = 0; t < 16; ++t) {
        unsigned short h = u[lane * 16 + t];
        int e = (h >> 7) & 0xFF;
        if (e == 0xFF) bad++;
        else if (e >= 0x8E) bad++;
        else if (e != 0 && e <= 0x66) bad++;
    }
    #pragma unroll
    for (int off = 1; off < 64; off <<= 1) bad += __shfl_xor(bad, off);
    return bad > 100 ? 1 : 0;
}

__device__ __forceinline__ ull shfl_xor_u64(ull x, int mask) {
    unsigned lo = (unsigned)x, hi = (unsigned)(x >> 32);
    lo = __shfl_xor(lo, mask); hi = __shfl_xor(hi, mask);
    return ((ull)hi << 32) | lo;
}

__device__ __forceinline__ float gelu_f(float x) {
    float x3 = x * x * x;
    return 0.5f * x * (1.f + tanhf(0.7978845608028654f * (x + 0.044715f * x3)));
}

// ---------------- transpose tile body ----------------
__device__ __forceinline__ void tr_tile(const void* src, hb* dst, int K, int N,
                                        int k0, int n0, int fm) {
    __shared__ float t[32][33];
    const int tx = threadIdx.x & 31, ty = threadIdx.x >> 5;   // 32 x 8
    #pragma unroll
    for (int r = 0; r < 32; r += 8)
        t[ty + r][tx] = ldin(src, (size_t)(k0 + ty + r) * N + n0 + tx, fm);
    __syncthreads();
    #pragma unroll
    for (int r = 0; r < 32; r += 8)
        dst[(size_t)(n0 + ty + r) * K + k0 + tx] = __float2bfloat16(t[tx][ty + r]);
}

// ---------------- setup: all weight transposes + pos split + p2 + spos + LN1 ----------------
// blocks 0..1023:    Wq/Wk/Wv/Wo transposes (512x512 each)
// blocks 1024..3071: W1 (512x2048) + W2 (2048x512) transposes
// blocks 3072..7167: prep rows
__global__ void setup_kernel(const void* __restrict__ pos, const void* __restrict__ x,
                             const void* __restrict__ ln1s, const void* __restrict__ ln1b,
                             const void* __restrict__ Wq, const void* __restrict__ Wk,
                             const void* __restrict__ Wv, const void* __restrict__ Wo,
                             const void* __restrict__ W1, const void* __restrict__ W2,
                             hb* __restrict__ ph, hb* __restrict__ pl,
                             float* __restrict__ p2, float* __restrict__ spos,
                             hb* __restrict__ xnB,
                             hb* __restrict__ WqkvT, hb* __restrict__ WoT,
                             hb* __restrict__ W1T, hb* __restrict__ W2T) {
    const int fm = detect_fm(x);
    const int bx = blockIdx.x;
    if (bx < 1024) {
        const int seg = bx >> 8, t = bx & 255;
        const int n0 = (t & 15) * 32, k0 = (t >> 4) * 32;
        const void* src = (seg == 0) ? Wq : (seg == 1) ? Wk : (seg == 2) ? Wv : Wo;
        hb* dst = (seg == 3) ? WoT : (WqkvT + (size_t)seg * 512 * 512);
        tr_tile(src, dst, 512, 512, k0, n0, fm);
    } else if (bx < 3072) {
        const int b = bx - 1024;
        if (b < 1024) {
            const int n0 = (b & 63) * 32, k0 = (b >> 6) * 32;
            tr_tile(W1, W1T, 512, 2048, k0, n0, fm);
        } else {
            const int b2 = b - 1024;
            const int n0 = (b2 & 15) * 32, k0 = (b2 >> 4) * 32;
            tr_tile(W2, W2T, 2048, 512, k0, n0, fm);
        }
    } else {
        const int row = bx - 3072, tid = threadIdx.x;
        float s2 = 0.f, s1 = 0.f;
        #pragma unroll
        for (int t = 0; t < 2; ++t) {
            size_t i = (size_t)row * DDIM + tid + 256 * t;
            float v = ldin(pos, i, fm);
            hb h = __float2bfloat16(v);
            ph[i] = h;
            pl[i] = __float2bfloat16(v - b2f(h));
            s2 += v * v; s1 += v;
        }
        float v0 = ldin(x, (size_t)row * DDIM + tid, fm);
        float v1 = ldin(x, (size_t)row * DDIM + tid + 256, fm);
        float sum = v0 + v1, sq = v0 * v0 + v1 * v1;
        const int lane = tid & 63, wv = tid >> 6;
        #pragma unroll
        for (int off = 32; off; off >>= 1) {
            s2 += __shfl_down(s2, off); s1 += __shfl_down(s1, off);
            sum += __shfl_down(sum, off); sq += __shfl_down(sq, off);
        }
        __shared__ float ls[16];
        if (lane == 0) { ls[wv] = s2; ls[4 + wv] = s1; ls[8 + wv] = sum; ls[12 + wv] = sq; }
        __syncthreads();
        if (tid == 0) {
            p2[row]   = ls[0] + ls[1] + ls[2] + ls[3];
            spos[row] = ls[4] + ls[5] + ls[6] + ls[7];
        }
        float ts = ls[8] + ls[9] + ls[10] + ls[11];
        float tq = ls[12] + ls[13] + ls[14] + ls[15];
        float mean = ts * (1.f / DDIM);
        float var = tq * (1.f / DDIM) - mean * mean;
        float rstd = rsqrtf(var + 1e-6f);
        xnB[(size_t)row * DDIM + tid]       = __float2bfloat16(ldin(ln1s, tid, fm) * (v0 - mean) * rstd + ldin(ln1b, tid, fm));
        xnB[(size_t)row * DDIM + tid + 256] = __float2bfloat16(ldin(ln1s, tid + 256, fm) * (v1 - mean) * rstd + ldin(ln1b, tid + 256, fm));
    }
}

// ---------------- LayerNorm (internal f32 in) ----------------
__global__ void ln_kernel(const float* __restrict__ xin,
                          const void* __restrict__ s, const void* __restrict__ b,
                          hb* __restrict__ y, const void* __restrict__ xd) {
    const int m = detect_fm(xd);
    const int row = blockIdx.x, tid = threadIdx.x;
    const float* xp = xin + (size_t)row * DDIM;
    float v0 = xp[tid], v1 = xp[tid + 256];
    float sum = v0 + v1, sq = v0 * v0 + v1 * v1;
    const int lane = tid & 63, wv = tid >> 6;
    #pragma unroll
    for (int off = 32; off; off >>= 1) { sum += __shfl_down(sum, off); sq += __shfl_down(sq, off); }
    __shared__ float ls[8];
    if (lane == 0) { ls[wv] = sum; ls[4 + wv] = sq; }
    __syncthreads();
    float ts = ls[0] + ls[1] + ls[2] + ls[3];
    float tq = ls[4] + ls[5] + ls[6] + ls[7];
    float mean = ts * (1.f / DDIM);
    float var = tq * (1.f / DDIM) - mean * mean;
    float rstd = rsqrtf(var + 1e-6f);
    y[(size_t)row * DDIM + tid]       = __float2bfloat16(ldin(s, tid, m) * (v0 - mean) * rstd + ldin(b, tid, m));
    y[(size_t)row * DDIM + tid + 256] = __float2bfloat16(ldin(s, tid + 256, m) * (v1 - mean) * rstd + ldin(b, tid + 256, m));
}

// ================ pipelined MFMA GEMM ================
template<int EPI, int TN, int BK>
__global__ __launch_bounds__(256, 2)
void gemm_bt(const hb* __restrict__ A, const hb* __restrict__ Bt,
             const void* __restrict__ bp0, const void* __restrict__ bp1, const void* __restrict__ bp2,
             const void* __restrict__ res, void* __restrict__ C,
             int N, int K, int lda, int ldb, int ldc,
             const void* __restrict__ xd) {
    constexpr int WY = (TN == 128) ? 2 : 4;
    constexpr int WX = (TN == 128) ? 2 : 1;
    constexpr int FI = 128 / WY / 16;
    constexpr int FJ = TN / WX / 16;
    constexpr int NA = 128 * BK / (256 * 8);
    constexpr int NB = TN * BK / (256 * 8);
    constexpr int LDSW = BK + 8;
    const int fm = detect_fm(xd);
    __shared__ short As[128 * LDSW];
    __shared__ short Bs[TN * LDSW];
    const int tid = threadIdx.x, lane = tid & 63, wave = tid >> 6;
    const int wy = (TN == 128) ? (wave >> 1) : wave;
    const int wx = (TN == 128) ? (wave & 1) : 0;
    const int m0 = blockIdx.y * 128, n0 = blockIdx.x * TN;
    const int r0 = tid >> 3, c0 = (tid & 7) * 8;
    const int lm = lane & 15, lk = (lane >> 4) * 8;
    f4v acc[FI][FJ];
    #pragma unroll
    for (int i = 0; i < FI; ++i)
        #pragma unroll
        for (int j = 0; j < FJ; ++j) acc[i][j] = (f4v){0.f, 0.f, 0.f, 0.f};

    s8v an[NA], bn[NB];
    #pragma unroll
    for (int g = 0; g < NA; ++g) an[g] = *(const s8v*)(A + (size_t)(m0 + r0 + 32 * g) * lda + c0);
    #pragma unroll
    for (int g = 0; g < NB; ++g) bn[g] = *(const s8v*)(Bt + (size_t)(n0 + r0 + 32 * g) * ldb + c0);

    for (int k0 = 0; k0 < K; k0 += BK) {
        __syncthreads();
        #pragma unroll
        for (int g = 0; g < NA; ++g) *(s8v*)(As + (r0 + 32 * g) * LDSW + c0) = an[g];
        #pragma unroll
        for (int g = 0; g < NB; ++g) *(s8v*)(Bs + (r0 + 32 * g) * LDSW + c0) = bn[g];
        if (k0 + BK < K) {
            const int kn = k0 + BK;
            #pragma unroll
            for (int g = 0; g < NA; ++g) an[g] = *(const s8v*)(A + (size_t)(m0 + r0 + 32 * g) * lda + kn + c0);
            #pragma unroll
            for (int g = 0; g < NB; ++g) bn[g] = *(const s8v*)(Bt + (size_t)(n0 + r0 + 32 * g) * ldb + kn + c0);
        }
        __syncthreads();
        #pragma unroll
        for (int kc = 0; kc < BK; kc += 32) {
            s8v af[FI], bf[FJ];
            #pragma unroll
            for (int f = 0; f < FI; ++f)
                af[f] = *(const s8v*)(As + (wy * (128 / WY) + f * 16 + lm) * LDSW + kc + lk);
            #pragma unroll
            for (int f = 0; f < FJ; ++f)
                bf[f] = *(const s8v*)(Bs + (wx * (TN / WX) + f * 16 + lm) * LDSW + kc + lk);
            #pragma unroll
            for (int fi = 0; fi < FI; ++fi)
                #pragma unroll
                for (int fj = 0; fj < FJ; ++fj)
                    acc[fi][fj] = __builtin_amdgcn_mfma_f32_16x16x32_bf16(af[fi], bf[fj], acc[fi][fj], 0, 0, 0);
        }
    }

    const int embase = m0 + wy * (128 / WY) + (lane >> 4) * 4;
    const int enbase = n0 + wx * (TN / WX) + lm;
    #pragma unroll
    for (int fi = 0; fi < FI; ++fi) {
        #pragma unroll
        for (int fj = 0; fj < FJ; ++fj) {
            const int n = enbase + fj * 16;
            #pragma unroll
            for (int r = 0; r < 4; ++r) {
                const int m = embase + fi * 16 + r;
                float val = acc[fi][fj][r];
                size_t ci = (size_t)m * ldc + n;
                if (EPI == 0) {
                    const void* bp = (n < 512) ? bp0 : ((n < 1024) ? bp1 : bp2);
                    val += ldin(bp, n & 511, fm);
                    ((hb*)C)[ci] = __float2bfloat16(val);
                } else if (EPI == 1) {
                    val += ldin(bp0, n, fm) + ldin(res, (size_t)m * 512 + n, fm);
                    ((float*)C)[ci] = val;
                } else if (EPI == 2) {
                    val = gelu_f(val + ldin(bp0, n, fm));
                    ((hb*)C)[ci] = __float2bfloat16(val);
                } else {
                    val += ldin(bp0, n, fm) + ((const float*)res)[(size_t)m * 512 + n];
                    if (fm) ((float*)C)[ci] = val;
                    else ((hb*)C)[ci] = __float2bfloat16(val);
                }
            }
        }
    }
}

// ================ dist: fused hi/lo (2 accumulators), triangular, LDS-transposed mirror ================
__global__ __launch_bounds__(256, 2)
void dist_mfma(const hb* __restrict__ ph, const hb* __restrict__ pl,
               const float* __restrict__ p2, const void* __restrict__ cp,
               float* __restrict__ argb, const void* __restrict__ xd) {
    constexpr int BK = 32, LDSW = BK + 8;
    constexpr int KI = DDIM / BK;
    constexpr int TSH = 128 * LDSW;
    __shared__ float Tm[128 * 132];
    short* Sb = (short*)Tm;

    const int fm = detect_fm(xd);
    const float c = ld_scalar(cp, fm);
    const int bb = blockIdx.z;
    const float* p2b = p2 + bb * NTOK;
    const size_t rb = (size_t)bb * NTOK;
    float* out = argb + (size_t)bb * NTOK * NTOK;
    int t = blockIdx.x, bi = 0, rem = 16;
    while (t >= rem) { t -= rem; bi++; rem = 16 - bi; }
    const int bj = bi + t;
    const int i0 = bi * 128, j0 = bj * 128;
    const bool diag = (bi == bj);

    const int tid = threadIdx.x, lane = tid & 63, wave = tid >> 6;
    const int wy = wave >> 1, wx = wave & 1;
    const int r0 = tid >> 2, c0 = (tid & 3) * 8;
    const int lm = lane & 15, lk = (lane >> 4) * 8;

    const hb* src[4] = { ph + (rb + i0) * DDIM, pl + (rb + i0) * DDIM,
                         ph + (rb + j0) * DDIM, pl + (rb + j0) * DDIM };

    f4v acc_hh[4][4], acc_x[4][4];
    #pragma unroll
    for (int i = 0; i < 4; ++i)
        #pragma unroll
        for (int j = 0; j < 4; ++j) { acc_hh[i][j] = (f4v){0.f,0.f,0.f,0.f}; acc_x[i][j] = (f4v){0.f,0.f,0.f,0.f}; }

    s8v pf[4][2];
    #pragma unroll
    for (int tt = 0; tt < 4; ++tt)
        #pragma unroll
        for (int g = 0; g < 2; ++g)
            pf[tt][g] = *(const s8v*)(src[tt] + (size_t)(r0 + 64 * g) * DDIM + c0);

    for (int it = 0; it < KI; ++it) {
        __syncthreads();
        #pragma unroll
        for (int tt = 0; tt < 4; ++tt)
            #pragma unroll
            for (int g = 0; g < 2; ++g)
                *(s8v*)(Sb + tt * TSH + (r0 + 64 * g) * LDSW + c0) = pf[tt][g];
        if (it + 1 < KI) {
            const int kn = (it + 1) * BK;
            #pragma unroll
            for (int tt = 0; tt < 4; ++tt)
                #pragma unroll
                for (int g = 0; g < 2; ++g)
                    pf[tt][g] = *(const s8v*)(src[tt] + (size_t)(r0 + 64 * g) * DDIM + kn + c0);
        }
        __syncthreads();
        s8v ah[4], al[4], bh[4], bl[4];
        #pragma unroll
        for (int f = 0; f < 4; ++f) {
            ah[f] = *(const s8v*)(Sb + 0 * TSH + (wy * 64 + f * 16 + lm) * LDSW + lk);
            al[f] = *(const s8v*)(Sb + 1 * TSH + (wy * 64 + f * 16 + lm) * LDSW + lk);
            bh[f] = *(const s8v*)(Sb + 2 * TSH + (wx * 64 + f * 16 + lm) * LDSW + lk);
            bl[f] = *(const s8v*)(Sb + 3 * TSH + (wx * 64 + f * 16 + lm) * LDSW + lk);
        }
        #pragma unroll
        for (int fi = 0; fi < 4; ++fi)
            #pragma unroll
            for (int fj = 0; fj < 4; ++fj) {
                acc_hh[fi][fj] = __builtin_amdgcn_mfma_f32_16x16x32_bf16(ah[fi], bh[fj], acc_hh[fi][fj], 0, 0, 0);
                acc_x[fi][fj]  = __builtin_amdgcn_mfma_f32_16x16x32_bf16(ah[fi], bl[fj], acc_x[fi][fj], 0, 0, 0);
                acc_x[fi][fj]  = __builtin_amdgcn_mfma_f32_16x16x32_bf16(al[fi], bh[fj], acc_x[fi][fj], 0, 0, 0);
            }
    }

    __syncthreads();
    const int eibase = i0 + wy * 64 + (lane >> 4) * 4;
    const int ejbase = j0 + wx * 64 + lm;
    #pragma unroll
    for (int fi = 0; fi < 4; ++fi) {
        #pragma unroll
        for (int fj = 0; fj < 4; ++fj) {
            const int jj = ejbase + fj * 16;
            const float p2j = p2b[jj];
            #pragma unroll
            for (int r = 0; r < 4; ++r) {
                const int ii = eibase + fi * 16 + r;
                const float p2i = p2b[ii];
                const float xy = acc_hh[fi][fj][r] + acc_x[fi][fj][r];
                float diff = fmaxf(p2i + p2j - 2.f * xy, 0.f);
                float den = fmaxf((1.f - c * p2i) * (1.f - c * p2j), 1e-8f);
                float argv = 1.f + 2.f * c * diff / den;
                out[(size_t)ii * NTOK + jj] = argv;
                if (!diag) Tm[(jj - j0) * 132 + (ii - i0)] = argv;
            }
        }
    }
    if (!diag) {
        __syncthreads();
        #pragma unroll
        for (int k = 0; k < 16; ++k) {
            const int lin = k * 256 + tid;
            const int rowT = lin >> 5;
            const int c4 = (lin & 31) * 4;
            f4v v = *(const f4v*)(Tm + rowT * 132 + c4);
            *(f4v*)(out + (size_t)(j0 + rowT) * NTOK + i0 + c4) = v;
        }
    }
}

// ---------------- top-16 v4: one wave per row, 32 keys/lane, no merge ----------------
__global__ void topk_kernel(const float* __restrict__ argb, int* __restrict__ idxb,
                            float* __restrict__ argvb) {
    const int row = blockIdx.x * 4 + (threadIdx.x >> 6);     // 0..4095
    const int bb = row >> 11, r = row & (NTOK - 1);
    const float* arow = argb + (size_t)bb * NTOK * NTOK + (size_t)r * NTOK;
    const int lane = threadIdx.x & 63;
    ull k[32];
    #pragma unroll
    for (int i = 0; i < 8; ++i) {
        f4v v = *(const f4v*)(arow + lane * 4 + i * 256);
        #pragma unroll
        for (int e = 0; e < 4; ++e) {
            const unsigned idx = lane * 4 + e + i * 256;
            k[i * 4 + e] = ((ull)__float_as_uint(v[e]) << 32) | idx;
        }
    }
    ull res = ~0ull;
    for (int sel = 0; sel < KNN_K; ++sel) {
        ull t16[16];
        #pragma unroll
        for (int i = 0; i < 16; ++i) t16[i] = (k[2 * i] < k[2 * i + 1]) ? k[2 * i] : k[2 * i + 1];
        #pragma unroll
        for (int i = 0; i < 8; ++i) t16[i] = (t16[2 * i] < t16[2 * i + 1]) ? t16[2 * i] : t16[2 * i + 1];
        #pragma unroll
        for (int i = 0; i < 4; ++i) t16[i] = (t16[2 * i] < t16[2 * i + 1]) ? t16[2 * i] : t16[2 * i + 1];
        ull m01 = (t16[0] < t16[1]) ? t16[0] : t16[1];
        ull m23 = (t16[2] < t16[3]) ? t16[2] : t16[3];
        ull m = (m01 < m23) ? m01 : m23;
        #pragma unroll
        for (int mask = 1; mask < 64; mask <<= 1) {
            ull o = shfl_xor_u64(m, mask);
            m = (o < m) ? o : m;
        }
        const unsigned widx = (unsigned)m;
        const int regid = (int)(((widx >> 8) << 2) | (widx & 3));
        const bool mine = (int)((widx >> 2) & 63) == lane;
        #pragma unroll
        for (int rr = 0; rr < 32; ++rr)
            if (rr == regid && mine) k[rr] = ~0ull;
        if (lane == sel) res = m;
    }
    if (lane < KNN_K) {
        idxb[(size_t)row * KNN_K + lane] = (int)(unsigned)res;
        argvb[(size_t)row * KNN_K + lane] = __uint_as_float((unsigned)(res >> 32));
    }
}

// ---------------- fused attention: stat elimination + 16-lane groups ----------------
__global__ void attn_kernel(const void* __restrict__ pos,
                            const hb* __restrict__ qkvB, const int* __restrict__ idxb,
                            const float* __restrict__ argvb,
                            const float* __restrict__ p2, const float* __restrict__ spos,
                            const void* __restrict__ cp,
                            const void* __restrict__ geo_s, const void* __restrict__ geo_b,
                            const void* __restrict__ a_sc, const void* __restrict__ f_sc,
                            hb* __restrict__ attnO, const void* __restrict__ xd) {
    const int fm = detect_fm(xd);
    const int row = blockIdx.x;
    const int bb = row >> 11;
    const int tid = threadIdx.x, lane = tid & 63, wv = tid >> 6;
    const int l16 = lane & 15, grp = lane >> 4;
    const int kk = wv * 4 + grp;
    __shared__ float qgsL[DDIM], qL[DDIM];
    __shared__ float sc_s[KNN_K], wgt_s[KNN_K];
    __shared__ int nid_s[KNN_K];
    __shared__ float red3[12];

    const float c = ld_scalar(cp, fm);
    const float cs = fmaxf(c, 1e-20f);
    const float sc_c = sqrtf(fmaxf(c, 0.f));

    float qq = 0.f, qgs_sum = 0.f, qgb = 0.f;
    {
        const int d0 = tid * 2;
        float qp0 = ldin(pos, (size_t)row * DDIM + d0, fm);
        float qp1 = ldin(pos, (size_t)row * DDIM + d0 + 1, fm);
        float q0 = b2f(qkvB[(size_t)row * 1536 + d0]);
        float q1 = b2f(qkvB[(size_t)row * 1536 + d0 + 1]);
        float gs0 = ldin(geo_s, d0, fm), gs1 = ldin(geo_s, d0 + 1, fm);
        float gb0 = ldin(geo_b, d0, fm), gb1 = ldin(geo_b, d0 + 1, fm);
        float a0 = q0 * gs0, a1 = q1 * gs1;
        qgsL[d0] = a0; qgsL[d0 + 1] = a1;
        qL[d0] = q0; qL[d0 + 1] = q1;
        qq = a0 * qp0 + a1 * qp1;
        qgs_sum = a0 + a1;
        qgb = q0 * gb0 + q1 * gb1;
    }
    if (tid < KNN_K) nid_s[tid] = idxb[row * KNN_K + tid];
    #pragma unroll
    for (int off = 32; off; off >>= 1) {
        qq += __shfl_down(qq, off);
        qgs_sum += __shfl_down(qgs_sum, off);
        qgb += __shfl_down(qgb, off);
    }
    if (lane == 0) { red3[wv] = qq; red3[4 + wv] = qgs_sum; red3[8 + wv] = qgb; }
    __syncthreads();
    const float QQ  = red3[0] + red3[1] + red3[2] + red3[3];
    const float QGS = red3[4] + red3[5] + red3[6] + red3[7];
    const float QGB = red3[8] + red3[9] + red3[10] + red3[11];

    const int j = nid_s[kk];
    const size_t nro = (size_t)(bb * NTOK + j) * DDIM;
    const size_t nrk = (size_t)(bb * NTOK + j) * 1536 + 512;
    float qk = 0.f, feat = 0.f;
    if (fm) {
        #pragma unroll
        for (int i = 0; i < 8; ++i) {
            const int d = l16 * 4 + i * 64;
            f4v kp = *(const f4v*)((const float*)pos + nro + d);
            f4v qg = *(const f4v*)(qgsL + d);
            qk += qg[0] * kp[0] + qg[1] * kp[1] + qg[2] * kp[2] + qg[3] * kp[3];
        }
    } else {
        #pragma unroll
        for (int i = 0; i < 8; ++i) {
            const int d = l16 * 4 + i * 64;
            s4v kp4 = *(const s4v*)((const hb*)pos + nro + d);
            f4v qg = *(const f4v*)(qgsL + d);
            #pragma unroll
            for (int e = 0; e < 4; ++e) qk += qg[e] * bits2f(kp4[e]);
        }
    }
    #pragma unroll
    for (int i = 0; i < 4; ++i) {
        const int d = l16 * 8 + i * 128;
        s8v kv = *(const s8v*)(qkvB + nrk + d);
        f4v q0 = *(const f4v*)(qL + d);
        f4v q1 = *(const f4v*)(qL + d + 4);
        #pragma unroll
        for (int e = 0; e < 4; ++e)
            feat += q0[e] * bits2f(kv[e]) + q1[e] * bits2f(kv[e + 4]);
    }
    #pragma unroll
    for (int off = 8; off; off >>= 1) {
        qk += __shfl_down(qk, off, 16);
        feat += __shfl_down(feat, off, 16);
    }
    if (l16 == 0) {
        const float p2i = p2[row], p2j = p2[bb * NTOK + j];
        const float sposi = spos[row], sposj = spos[bb * NTOK + j];
        const float argv = argvb[row * KNN_K + kk];
        const float den_d = fmaxf((1.f - c * p2i) * (1.f - c * p2j), 1e-8f);
        const float diff = (argv - 1.f) * den_d / (2.f * cs);
        const float xy = 0.5f * (p2i + p2j - diff);
        const float x2 = p2i, y2 = p2j;
        const float Af = 1.f - 2.f * c * xy + c * y2;
        const float Bf = 1.f - c * x2;
        float den = fmaxf(1.f - 2.f * c * xy + c * c * x2 * y2, 1e-8f);
        const float rden = 1.f / den;
        float n2 = fmaxf(Af * Af * x2 - 2.f * Af * Bf * xy + Bf * Bf * y2, 0.f) * rden * rden;
        const float ynorm = fmaxf(sqrtf(n2), 1e-8f);
        const float t_over = sc_c * ynorm;
        const float targ = fminf(t_over, 1.f - 1e-7f);
        const float scale = (targ > 0.f) ? (atanhf(targ) / t_over) : 1.f;
        const float S1 = scale * rden * (Bf * sposj - Af * sposi);
        const float mean = S1 * (1.f / DDIM);
        const float sq = scale * scale * n2;
        const float var = sq * (1.f / DDIM) - mean * mean;
        const float rstd = rsqrtf(fmaxf(var, 0.f) + 1e-6f);
        const float G = scale * rden * (Bf * qk - Af * QQ);
        const float align = rstd * (G - mean * QGS) + QGB;
        sc_s[kk] = ld_scalar(f_sc, fm) * feat + ld_scalar(a_sc, fm) * align;
    }
    __syncthreads();
    if (tid < 16) {
        float v = sc_s[tid];
        float mx = v;
        #pragma unroll
        for (int off = 8; off; off >>= 1) mx = fmaxf(mx, __shfl_xor(mx, off, 16));
        float e = expf(v - mx);
        float s = e;
        #pragma unroll
        for (int off = 8; off; off >>= 1) s += __shfl_xor(s, off, 16);
        wgt_s[tid] = e / s;
    }
    __syncthreads();
    {
        const int d0 = tid * 2;
        float acc0 = 0.f, acc1 = 0.f;
        #pragma unroll
        for (int t = 0; t < KNN_K; ++t) {
            const hb* vp = qkvB + (size_t)(bb * NTOK + nid_s[t]) * 1536 + 1024 + d0;
            float w = wgt_s[t];
            acc0 += w * b2f(vp[0]);
            acc1 += w * b2f(vp[1]);
        }
        attnO[(size_t)row * DDIM + d0]     = __float2bfloat16(acc0);
        attnO[(size_t)row * DDIM + d0 + 1] = __float2bfloat16(acc1);
    }
}

extern "C" void kernel_launch(void* const* d_in, const int* in_sizes, int n_in,
                              void* d_out, int out_size, void* d_ws, size_t ws_size,
                              hipStream_t stream) {
    const void* x    = d_in[0];
    const void* posb = d_in[1];
    const void* cb   = d_in[2];
    const void* Wq   = d_in[3];
    const void* bq   = d_in[4];
    const void* Wk   = d_in[5];
    const void* bk   = d_in[6];
    const void* Wv   = d_in[7];
    const void* bv   = d_in[8];
    const void* Wo   = d_in[9];
    const void* bo   = d_in[10];
    const void* W1   = d_in[11];
    const void* b1   = d_in[12];
    const void* W2   = d_in[13];
    const void* b2   = d_in[14];
    const void* ln2s = d_in[17];
    const void* ln2b = d_in[18];
    const void* geos = d_in[19];
    const void* geob = d_in[20];
    const void* asc  = d_in[21];
    const void* fsc  = d_in[22];
    const void* ln1s = d_in[15];
    const void* ln1b = d_in[16];

    float* wsf = (float*)d_ws;
    size_t off = 0;
    hb* xnB   = (hb*)(wsf + off); off += 1048576;   // 4096x512 bf16; later hbuf (LN2 out)
    hb* qkvB  = (hb*)(wsf + off); off += 3145728;   // 4096x1536 bf16
    float* p2 = wsf + off;        off += 4096;
    float* spos = wsf + off;      off += 4096;
    int* idxb = (int*)(wsf + off); off += 65536;
    float* argvb = wsf + off;     off += 65536;
    float* x1 = wsf + off;        off += 2097152;   // f32 4096x512
    float* argb = wsf + off;                         // 2 x NTOK^2 f32
    hb* hh    = (hb*)argb;        off += 8388608;   // hh overlays argb (dead by FFN)
    hb* ph    = (hb*)(wsf + off); off += 1048576;   // later attnO
    hb* pl    = (hb*)(wsf + off); off += 1048576;
    hb* WqkvT = (hb*)(wsf + off); off += 393216;    // 1536x512 bf16
    hb* WoT   = (hb*)(wsf + off); off += 131072;    // 512x512 bf16
    hb* W1T   = (hb*)(wsf + off); off += 524288;    // 2048x512 bf16
    hb* W2T   = (hb*)(wsf + off); off += 524288;    // 512x2048 bf16
    hb* attnO = ph;
    hb* hbuf  = xnB;

    // 1. setup: all transposes + pos split + p2/spos + LN1
    setup_kernel<<<7168, 256, 0, stream>>>(posb, x, ln1s, ln1b, Wq, Wk, Wv, Wo, W1, W2,
                                           ph, pl, p2, spos, xnB, WqkvT, WoT, W1T, W2T);
    // 2. qkv GEMM
    gemm_bt<0, 128, 64><<<dim3(12, 32), 256, 0, stream>>>(xnB, WqkvT, bq, bk, bv, nullptr, qkvB,
                                                          1536, 512, 512, 512, 1536, x);
    // 3. distances (symmetric fused hi/lo, both batches)
    dist_mfma<<<dim3(136, 1, 2), 256, 0, stream>>>(ph, pl, p2, cb, argb, x);
    // 4. top-16 (1 wave/row)
    topk_kernel<<<1024, 256, 0, stream>>>(argb, idxb, argvb);
    // 5. fused geometric attention (overlays ph)
    attn_kernel<<<ROWS, 256, 0, stream>>>(posb, qkvB, idxb, argvb, p2, spos, cb,
                                          geos, geob, asc, fsc, attnO, x);
    // 6. x1 = x + attn @ Wo + bo  (f32)
    gemm_bt<1, 64, 64><<<dim3(8, 32), 256, 0, stream>>>(attnO, WoT, bo, nullptr, nullptr, x, x1,
                                                        512, 512, 512, 512, 512, x);
    // 7. LN2 -> bf16
    ln_kernel<<<ROWS, 256, 0, stream>>>(x1, ln2s, ln2b, hbuf, x);
    // 8. hh = gelu(h @ W1 + b1) -> bf16
    gemm_bt<2, 128, 64><<<dim3(16, 32), 256, 0, stream>>>(hbuf, W1T, b1, nullptr, nullptr, nullptr, hh,
                                                          2048, 512, 512, 512, 2048, x);
    // 9. out = x1 + hh @ W2 + b2
    gemm_bt<3, 64, 64><<<dim3(8, 32), 256, 0, stream>>>(hh, W2T, b2, nullptr, nullptr, x1, d_out,
                                                        512, 2048, 2048, 2048, 512, x);

    (void)in_sizes; (void)n_in; (void)out_size; (void)ws_size;
}